// Round 4
// baseline (3306.307 us; speedup 1.0000x reference)
//
#include <hip/hip_runtime.h>

#define KM 29
#define GTAB 4096

typedef __bf16 bf16_t;
typedef __bf16 bf16x8 __attribute__((ext_vector_type(8)));
typedef __bf16 bf16x4 __attribute__((ext_vector_type(4)));
typedef float  f32x4  __attribute__((ext_vector_type(4)));

__device__ __forceinline__ float silu_f(float x){ return x / (1.0f + __expf(-x)); }

__device__ __forceinline__ float wave_reduce_sum(float v){
  #pragma unroll
  for (int s = 1; s < 64; s <<= 1) v += __shfl_xor(v, s);
  return v;
}

// l-of-k with clamp for pad rows 29..31 (their data is zero)
__device__ __forceinline__ constexpr int LOF2(int k){
  return (k<1)?0 : (k<4)?1 : (k<9)?2 : (k<14)?3 : (k<19)?4 : (k<24)?5 : 6;
}

__device__ __forceinline__ f32x4 mfma16(bf16x8 a, bf16x8 b, f32x4 c){
  return __builtin_amdgcn_mfma_f32_16x16x32_bf16(a, b, c, 0, 0, 0);
}

__device__ __forceinline__ float env_f(float d){
  float xx = d*(1.0f/12.0f);
  float x2 = xx*xx, x4 = x2*x2, x5 = x4*xx;
  float env = 1.0f - 21.0f*x5 + 35.0f*x5*xx - 15.0f*x5*x2;
  return (xx < 1.0f) ? env : 0.0f;
}

// ---------------- CSR build ----------------
__global__ void k_count(const int* __restrict__ EI, int* __restrict__ cnt, int E){
  int e = blockIdx.x*256 + threadIdx.x;
  if (e < E) atomicAdd(&cnt[EI[E+e]], 1);
}

__global__ __launch_bounds__(1024) void k_scan(int* __restrict__ cnt, int* __restrict__ rowptr, int N){
  __shared__ int ts[1024];
  int t = threadIdx.x;
  int base = t*8;
  int loc[8]; int sum = 0;
  #pragma unroll
  for (int u = 0; u < 8; u++){ int idx = base+u; int v = (idx < N) ? cnt[idx] : 0; loc[u] = sum; sum += v; }
  ts[t] = sum; __syncthreads();
  for (int off = 1; off < 1024; off <<= 1){
    int v = (t >= off) ? ts[t-off] : 0;
    __syncthreads();
    ts[t] += v;
    __syncthreads();
  }
  int excl = ts[t] - sum;
  #pragma unroll
  for (int u = 0; u < 8; u++){
    int idx = base+u;
    if (idx < N){ int r = excl + loc[u]; rowptr[idx] = r; cnt[idx] = r; }
  }
  if (t == 1023) rowptr[N] = ts[1023];
}

__global__ void k_fill(const int* __restrict__ EI, int* __restrict__ cur, int* __restrict__ order, int E){
  int e = blockIdx.x*256 + threadIdx.x;
  if (e < E){ int pos = atomicAdd(&cur[EI[E+e]], 1); order[pos] = e; }
}

__global__ void k_sort(const int* __restrict__ rowptr, int* __restrict__ order, int N){
  int n = blockIdx.x*256 + threadIdx.x;
  if (n >= N) return;
  int rp = rowptr[n], re = rowptr[n+1];
  for (int a = rp+1; a < re; a++){
    int key = order[a]; int b = a-1;
    while (b >= rp && order[b] > key){ order[b+1] = order[b]; b--; }
    order[b+1] = key;
  }
}

// ---------------- weight transposes ----------------
// dst[(l*C + c)*R + r] = src[l*Lstr + r*C + c]
__global__ void k_tr(const float* __restrict__ src, bf16_t* __restrict__ dst,
                     int L, int R, int C, int Lstr){
  int idx = blockIdx.x*256 + threadIdx.x;
  int total = L*R*C;
  if (idx >= total) return;
  int l = idx / (R*C); int rem = idx - l*(R*C);
  int r = rem / C; int c = rem - r*C;
  dst[((size_t)l*C + c)*R + r] = (bf16_t)src[(size_t)l*Lstr + (size_t)r*C + c];
}

// Wmsg [4][256][64] -> combined [4][128 cols][128 k]; col<64 = P-half, col>=64 = Q-half
__global__ void k_tr2(const float* __restrict__ src, bf16_t* __restrict__ dst){
  int idx = blockIdx.x*256 + threadIdx.x;
  if (idx >= 4*128*128) return;
  int l = idx >> 14; int j = (idx >> 7) & 127; int c = idx & 127;
  float v = (j < 64) ? src[(size_t)l*16384 + c*64 + j]
                     : src[(size_t)l*16384 + 8192 + c*64 + (j-64)];
  dst[idx] = (bf16_t)v;
}

// ---------------- radial MLP table build (4096 grid points) ----------------
__global__ __launch_bounds__(256) void k_tab_embed(
    const float* __restrict__ We0, const float* __restrict__ be0,
    const float* __restrict__ We1, const float* __restrict__ be1,
    const float* __restrict__ Wr0, const float* __restrict__ Wr1, const float* __restrict__ Wrl,
    float* __restrict__ h2tab, float* __restrict__ radtab)
{
  __shared__ float sb[4][640];
  const int wid = threadIdx.x >> 6, lane = threadIdx.x & 63;
  const int e = blockIdx.x*4 + wid;
  if (e >= GTAB) return;
  const float d = e * (12.0f/(GTAB-1));
  const float DLT = 12.0f/599.0f;
  const float CO  = -0.5f/((2.0f*DLT)*(2.0f*DLT));
  int jc = (int)(d/DLT + 0.5f);
  int j0 = jc - 16; if (j0 < 0) j0 = 0; if (j0 > 600-32) j0 = 600-32;
  float diff = d - (float)(j0+lane)*DLT;
  float gval = __expf(CO*diff*diff);
  float p[10];
  #pragma unroll
  for (int u = 0; u < 10; u++) p[u] = 0.f;
  const int c2 = 2*lane;
  for (int jj = 0; jj < 32; jj++){
    float gj = __shfl(gval, jj);
    int row = j0 + jj;
    const float2 w0 = *(const float2*)(We0 + row*128 + c2);
    p[0] += gj*w0.x; p[1] += gj*w0.y;
    #pragma unroll
    for (int i = 0; i < 4; i++){
      const float2 wr = *(const float2*)(Wr0 + ((size_t)i*600 + row)*128 + c2);
      p[2+2*i] += gj*wr.x; p[3+2*i] += gj*wr.y;
    }
  }
  sb[wid][c2]   = silu_f(p[0] + be0[c2]);
  sb[wid][c2+1] = silu_f(p[1] + be0[c2+1]);
  #pragma unroll
  for (int i = 0; i < 4; i++){
    sb[wid][128 + 128*i + c2]   = silu_f(p[2+2*i]);
    sb[wid][128 + 128*i + c2+1] = silu_f(p[3+2*i]);
  }
  float a0 = 0.f, a1 = 0.f;
  for (int c = 0; c < 128; c++){
    float hv = sb[wid][c];
    const float2 w = *(const float2*)(We1 + c*128 + c2);
    a0 += hv*w.x; a1 += hv*w.y;
  }
  a0 = silu_f(a0 + be1[c2]); a1 = silu_f(a1 + be1[c2+1]);
  h2tab[(size_t)e*128 + c2]     = a0;
  h2tab[(size_t)e*128 + c2 + 1] = a1;
  #pragma unroll
  for (int i = 0; i < 4; i++){
    float r0 = 0.f, r1 = 0.f;
    const float* W1 = Wr1 + (size_t)i*128*128;
    for (int c = 0; c < 128; c++){
      float rv = sb[wid][128 + 128*i + c];
      const float2 w = *(const float2*)(W1 + c*128 + c2);
      r0 += rv*w.x; r1 += rv*w.y;
    }
    r0 = silu_f(r0); r1 = silu_f(r1);
    const float* Wl = Wrl + (size_t)i*128*7;
    float pl[7];
    #pragma unroll
    for (int l = 0; l < 7; l++) pl[l] = r0*Wl[c2*7+l] + r1*Wl[(c2+1)*7+l];
    #pragma unroll
    for (int l = 0; l < 7; l++) pl[l] = wave_reduce_sum(pl[l]);
    if (lane == 0){
      #pragma unroll
      for (int l = 0; l < 7; l++) radtab[(size_t)e*28 + i*7 + l] = pl[l];
    }
  }
}

// ---------------- x init: h2 sums (interp) + MFMA Weproj ----------------
__global__ __launch_bounds__(256) void k_init_x(
    const int* __restrict__ Z, const float* __restrict__ ed, const float* __restrict__ emb,
    const bf16_t* __restrict__ WeprojT, const float* __restrict__ h2tab,
    const int* __restrict__ rowptr, const int* __restrict__ order,
    float* __restrict__ X, int N)
{
  __shared__ bf16_t h2s[32*136];
  __shared__ int Zs[32];
  int n0 = blockIdx.x*32, t = threadIdx.x;
  int half = t >> 7, ch = t & 127;
  for (int pair = 0; pair < 16; pair++){
    int nn = pair*2 + half;
    int n = n0 + nn;
    float acc = 0.f;
    if (n < N){
      int rp = rowptr[n], deg = rowptr[n+1]-rp;
      for (int idx = 0; idx < deg; idx++){
        int e = order[rp+idx];
        float d = ed[e];
        float u = d * ((GTAB-1)/12.0f);
        int j = (int)u; if (j > GTAB-2) j = GTAB-2;
        float f = u - (float)j;
        float a = h2tab[(size_t)j*128 + ch], b = h2tab[(size_t)(j+1)*128 + ch];
        acc += a + f*(b-a);
      }
    }
    h2s[nn*136 + ch] = (bf16_t)acc;
  }
  if (t < 32) Zs[t] = (n0 + t < N) ? Z[n0+t] : 0;
  __syncthreads();
  int wid = t >> 6, lane = t & 63;
  int mtile = wid & 1;
  int row = mtile*16 + (lane & 15);
  int koff = (lane >> 4)*8;
  bf16x8 afr[4];
  #pragma unroll
  for (int kk = 0; kk < 4; kk++) afr[kk] = *(const bf16x8*)(h2s + row*136 + kk*32 + koff);
  for (int nt = (wid>>1); nt < 232; nt += 2){
    f32x4 acc = {0.f,0.f,0.f,0.f};
    int col = nt*16 + (lane & 15);
    #pragma unroll
    for (int kk = 0; kk < 4; kk++){
      bf16x8 b = *(const bf16x8*)(WeprojT + (size_t)col*128 + kk*32 + koff);
      acc = mfma16(afr[kk], b, acc);
    }
    #pragma unroll
    for (int r = 0; r < 4; r++){
      int r32 = mtile*16 + (lane>>4)*4 + r;
      int n = n0 + r32;
      if (n < N){
        float v = acc[r] * (1.0f/23.395238876342773f);
        if (col < 128) v += emb[(size_t)Zs[r32]*128 + col];
        X[(size_t)n*3712 + col] = v;
      }
    }
  }
}

// ---------------- per-layer: rms + combined [P|Q] GEMM + PV + qm + P0/Q0 ----------------
__global__ __launch_bounds__(256) void k_pqv(
    const float* __restrict__ X, const float* __restrict__ gamma1,
    const bf16_t* __restrict__ WmsgCT, const bf16_t* __restrict__ WvT,
    bf16_t* __restrict__ PVb, bf16_t* __restrict__ qmb,
    float* __restrict__ P0, float* __restrict__ Q0, int layer)
{
  __shared__ bf16_t ys16[32*136];
  __shared__ bf16_t pq16[32*136];
  int n = blockIdx.x, t = threadIdx.x;
  int wid = t >> 6, lane = t & 63;
  const float* g1 = gamma1 + layer*128;
  const float* xp = X + (size_t)n*3712;
  for (int k = wid; k < KM; k += 4){
    float x0 = xp[k*128 + lane], x1 = xp[k*128 + 64 + lane];
    float ss = wave_reduce_sum(x0*x0 + x1*x1);
    float sc = rsqrtf(ss*(1.0f/128.0f) + 1e-6f);
    ys16[k*136 + lane]      = (bf16_t)(x0*sc*g1[lane]);
    ys16[k*136 + 64 + lane] = (bf16_t)(x1*sc*g1[64+lane]);
  }
  // zero pad rows 29..31 of ys16
  for (int idx = t; idx < 3*136; idx += 256) ys16[29*136 + idx] = (bf16_t)0.f;
  __syncthreads();
  int mtile = wid >> 1;
  int row = mtile*16 + (lane & 15);
  int koff = (lane >> 4)*8;
  // GEMM-C: [32 x 128] = ys @ WmsgCT   (cols 0..63 = P, 64..127 = qm)
  {
    const bf16_t* Bc = WmsgCT + (size_t)layer*16384;
    f32x4 acc[4] = {{0,0,0,0},{0,0,0,0},{0,0,0,0},{0,0,0,0}};
    #pragma unroll
    for (int kk = 0; kk < 128; kk += 32){
      bf16x8 a = *(const bf16x8*)(ys16 + row*136 + kk + koff);
      #pragma unroll
      for (int u = 0; u < 4; u++){
        int col = ((wid&1)*4+u)*16 + (lane & 15);
        bf16x8 b = *(const bf16x8*)(Bc + (size_t)col*128 + kk + koff);
        acc[u] = mfma16(a, b, acc[u]);
      }
    }
    #pragma unroll
    for (int u = 0; u < 4; u++){
      int col = ((wid&1)*4+u)*16 + (lane & 15);
      #pragma unroll
      for (int r = 0; r < 4; r++){
        int r32 = mtile*16 + (lane>>4)*4 + r;
        pq16[r32*136 + col] = (bf16_t)acc[u][r];
      }
      if (mtile == 0 && (lane>>4) == 0){
        float v = acc[u][0];   // row 0
        if (col < 64) P0[(size_t)n*64 + col] = v;
        else          Q0[(size_t)n*64 + col - 64] = v;
      }
    }
  }
  __syncthreads();
  // PV GEMM: [32 x 128] = pq16[:, 0:64] @ WvT  -> PVb transposed [hv][k32]
  {
    const bf16_t* Bt = WvT + (size_t)layer*8192;
    int colt = (wid & 1)*4;
    f32x4 acc[4] = {{0,0,0,0},{0,0,0,0},{0,0,0,0},{0,0,0,0}};
    #pragma unroll
    for (int kk = 0; kk < 64; kk += 32){
      bf16x8 a = *(const bf16x8*)(pq16 + row*136 + kk + koff);
      #pragma unroll
      for (int u = 0; u < 4; u++){
        int col = (colt+u)*16 + (lane & 15);
        bf16x8 b = *(const bf16x8*)(Bt + (size_t)col*64 + kk + koff);
        acc[u] = mfma16(a, b, acc[u]);
      }
    }
    bf16_t* pvp = PVb + (size_t)n*4096;
    int r0i = mtile*16 + (lane>>4)*4;
    #pragma unroll
    for (int u = 0; u < 4; u++){
      int col = (colt+u)*16 + (lane & 15);
      bf16x4 pack;
      #pragma unroll
      for (int r = 0; r < 4; r++){
        int r32 = r0i + r;
        pack[r] = (r32 < KM) ? (bf16_t)acc[u][r] : (bf16_t)0.f;
      }
      *(bf16x4*)(pvp + col*32 + r0i) = pack;
    }
  }
  // qm store: pq16 cols 64..127 -> qmb [29][64] (coalesced)
  for (int idx = t; idx < KM*64; idx += 256){
    int k = idx >> 6, j = idx & 63;
    qmb[(size_t)n*1856 + idx] = pq16[k*136 + 64 + j];
  }
}

// ---------------- per-layer: edge logits + gate ----------------
__global__ __launch_bounds__(256) void k_edge_logits(
    const int* __restrict__ EI, const float* __restrict__ ed,
    const float* __restrict__ P0, const float* __restrict__ Q0,
    const float* __restrict__ radtab, const float* __restrict__ Wap, const float* __restrict__ wa,
    const float* __restrict__ Wg, float* __restrict__ logi, bf16_t* __restrict__ gate16,
    int E, int layer)
{
  __shared__ float m0s[16*64];
  __shared__ int   srcs[16], tgts[16];
  __shared__ float r0s[16];
  int t = threadIdx.x;
  int eb = blockIdx.x*16;
  if (t < 16){
    int e = eb + t;
    if (e < E){
      srcs[t] = EI[e]; tgts[t] = EI[E+e];
      float d = ed[e];
      float u = d * ((GTAB-1)/12.0f);
      int j = (int)u; if (j > GTAB-2) j = GTAB-2;
      float f = u - (float)j;
      float a = radtab[(size_t)j*28 + layer*7], b = radtab[(size_t)(j+1)*28 + layer*7];
      r0s[t] = a + f*(b-a);
    }
  }
  __syncthreads();
  #pragma unroll
  for (int u = 0; u < 4; u++){
    int idx = t + u*256;
    int i = idx >> 6, j = idx & 63;
    if (eb + i < E) m0s[idx] = (P0[(size_t)srcs[i]*64 + j] + Q0[(size_t)tgts[i]*64 + j]) * r0s[i];
  }
  __syncthreads();
  int wid = t >> 6, lane = t & 63;
  const float* Wa  = Wap + (size_t)layer*16384;
  const float* Wgp = Wg  + (size_t)layer*8192;
  const int o4 = 4*lane, c2 = 2*lane;
  float pa[4][4] = {};
  float gg[4][2] = {};
  for (int j = 0; j < 64; j++){
    const float4 w4  = *(const float4*)(Wa + j*256 + o4);
    const float2 wg2 = *(const float2*)(Wgp + j*128 + c2);
    #pragma unroll
    for (int q = 0; q < 4; q++){
      float mj = m0s[(wid*4+q)*64 + j];
      pa[q][0] += mj*w4.x; pa[q][1] += mj*w4.y; pa[q][2] += mj*w4.z; pa[q][3] += mj*w4.w;
      gg[q][0] += mj*wg2.x; gg[q][1] += mj*wg2.y;
    }
  }
  const float* wav = wa + layer*256;
  float wa0 = wav[o4], wa1 = wav[o4+1], wa2 = wav[o4+2], wa3 = wav[o4+3];
  #pragma unroll
  for (int q = 0; q < 4; q++){
    int e = eb + wid*4 + q;
    if (e >= E) continue;
    gate16[(size_t)e*128 + c2]     = (bf16_t)silu_f(gg[q][0]);
    gate16[(size_t)e*128 + c2 + 1] = (bf16_t)silu_f(gg[q][1]);
    float lg = silu_f(pa[q][0])*wa0 + silu_f(pa[q][1])*wa1 + silu_f(pa[q][2])*wa2 + silu_f(pa[q][3])*wa3;
    lg += __shfl_xor(lg, 1); lg += __shfl_xor(lg, 2); lg += __shfl_xor(lg, 4);
    if ((lane & 7) == 0) logi[(size_t)e*8 + (lane >> 3)] = lg;
  }
}

// ---------------- per-layer: softmax + gather (2 edge-groups) + QV + Wo + x add ----------------
__global__ __launch_bounds__(512) void k_attn(
    const int* __restrict__ EI, const int* __restrict__ rowptr, const int* __restrict__ order,
    const float* __restrict__ ed, const bf16_t* __restrict__ qmb,
    const bf16_t* __restrict__ WvT, const bf16_t* __restrict__ WoT,
    const bf16_t* __restrict__ PVb, const bf16_t* __restrict__ gate16,
    const float* __restrict__ logi, const float* __restrict__ radtab,
    float* __restrict__ X, int layer)
{
  __shared__ bf16_t qm16[32*72];
  __shared__ bf16_t qvs16[32*136];
  __shared__ bf16_t ag16[32*136];
  __shared__ float rl7[64*8];
  __shared__ float at8[64*8];
  __shared__ int   es[64], srcs[64];
  __shared__ float mh[8], iden[8];
  int n = blockIdx.x, t = threadIdx.x;
  int rp = rowptr[n], deg = rowptr[n+1]-rp;
  if (deg == 0) return;
  // qm -> LDS (+zero pad rows 29..31)
  for (int idx = t; idx < KM*64; idx += 512){
    int k = idx >> 6, j = idx & 63;
    qm16[k*72 + j] = qmb[(size_t)n*1856 + idx];
  }
  for (int idx = t; idx < 3*72; idx += 512) qm16[29*72 + idx] = (bf16_t)0.f;
  // softmax stats: 8 lanes per head
  if (t < 64){
    int h = t & 7, slot = t >> 3;
    float m = -3.0e38f;
    for (int idx = slot; idx < deg; idx += 8){
      int e = order[rp+idx];
      m = fmaxf(m, logi[(size_t)e*8 + h]);
    }
    m = fmaxf(m, __shfl_xor(m, 8));
    m = fmaxf(m, __shfl_xor(m, 16));
    m = fmaxf(m, __shfl_xor(m, 32));
    float den = 0.f;
    for (int idx = slot; idx < deg; idx += 8){
      int e = order[rp+idx];
      den += env_f(ed[e]) * __expf(logi[(size_t)e*8 + h] - m);
    }
    den += __shfl_xor(den, 8);
    den += __shfl_xor(den, 16);
    den += __shfl_xor(den, 32);
    if (t < 8){ mh[t] = m; iden[t] = 1.0f/(den + 1e-16f); }
  }
  __syncthreads();
  int wid = t >> 6, lane = t & 63;
  // QV GEMM: [32 x 128] = qm16 @ WvT  (8 waves)
  {
    const bf16_t* Bt = WvT + (size_t)layer*8192;
    int mtile = wid >> 2;
    int colt = (wid & 3)*2;
    int row = mtile*16 + (lane & 15);
    int koff = (lane >> 4)*8;
    f32x4 acc[2] = {{0,0,0,0},{0,0,0,0}};
    #pragma unroll
    for (int kk = 0; kk < 64; kk += 32){
      bf16x8 a = *(const bf16x8*)(qm16 + row*72 + kk + koff);
      #pragma unroll
      for (int u = 0; u < 2; u++){
        int col = (colt+u)*16 + (lane & 15);
        bf16x8 b = *(const bf16x8*)(Bt + (size_t)col*64 + kk + koff);
        acc[u] = mfma16(a, b, acc[u]);
      }
    }
    #pragma unroll
    for (int u = 0; u < 2; u++){
      int col = (colt+u)*16 + (lane & 15);
      #pragma unroll
      for (int r = 0; r < 4; r++){
        int r32 = mtile*16 + (lane>>4)*4 + r;
        qvs16[r32*136 + col] = (bf16_t)acc[u][r];
      }
    }
  }
  __syncthreads();
  // gather: eg (edge parity) x kg (k-half) x hv
  int eg = t >> 8, kg = (t >> 7) & 1, hv = t & 127, h = hv >> 4;
  float acc[16];
  #pragma unroll
  for (int j = 0; j < 16; j++) acc[j] = 0.f;
  float S[7];
  #pragma unroll
  for (int l = 0; l < 7; l++) S[l] = 0.f;
  for (int base = 0; base < deg; base += 64){
    int ne = min(64, deg - base);
    if (t < ne){ int e = order[rp + base + t]; es[t] = e; srcs[t] = EI[e]; }
    __syncthreads();
    if (t < ne*8){
      int i = t >> 3, q = t & 7;
      int e = es[i];
      float d = ed[e];
      at8[t] = env_f(d) * __expf(logi[(size_t)e*8 + q] - mh[q]) * iden[q];
      if (q < 7){
        float u = d * ((GTAB-1)/12.0f);
        int j = (int)u; if (j > GTAB-2) j = GTAB-2;
        float f = u - (float)j;
        float a = radtab[(size_t)j*28 + layer*7 + q], b = radtab[(size_t)(j+1)*28 + layer*7 + q];
        rl7[t] = a + f*(b-a);
      }
    }
    __syncthreads();
    for (int i = eg; i < ne; i += 2){
      const bf16x8* pv = (const bf16x8*)(PVb + (size_t)srcs[i]*4096 + hv*32 + kg*16);
      bf16x8 v0 = pv[0], v1 = pv[1];
      float w = (float)gate16[(size_t)es[i]*128 + hv] * at8[i*8 + h];
      float rw[7];
      #pragma unroll
      for (int l = 0; l < 7; l++){ rw[l] = rl7[i*8+l]*w; S[l] += rw[l]; }
      #pragma unroll
      for (int j = 0; j < 8; j++) acc[j]   += (float)v0[j]*rw[LOF2(kg*16+j)];
      #pragma unroll
      for (int j = 0; j < 8; j++) acc[8+j] += (float)v1[j]*rw[LOF2(kg*16+8+j)];
    }
    __syncthreads();
  }
  // QV * S
  #pragma unroll
  for (int j = 0; j < 16; j++){
    int k = kg*16 + j;
    acc[j] += (float)qvs16[k*136 + hv] * S[LOF2(k)];
  }
  // merge edge groups via ag16
  if (eg == 1){
    #pragma unroll
    for (int j = 0; j < 16; j++){
      int k = kg*16 + j;
      if (k < KM) ag16[k*136 + hv] = (bf16_t)acc[j];
    }
  }
  __syncthreads();
  if (eg == 0){
    #pragma unroll
    for (int j = 0; j < 16; j++){
      int k = kg*16 + j;
      if (k < KM) ag16[k*136 + hv] = (bf16_t)(acc[j] + (float)ag16[k*136 + hv]);
    }
  }
  __syncthreads();
  // out = ag16 @ WoT, += X  (8 waves)
  {
    const bf16_t* Bt = WoT + (size_t)layer*16384;
    int mtile = wid >> 2;
    int colt = (wid & 3)*2;
    int row = mtile*16 + (lane & 15);
    int koff = (lane >> 4)*8;
    f32x4 acc2[2] = {{0,0,0,0},{0,0,0,0}};
    #pragma unroll
    for (int kk = 0; kk < 128; kk += 32){
      bf16x8 a = *(const bf16x8*)(ag16 + row*136 + kk + koff);
      #pragma unroll
      for (int u = 0; u < 2; u++){
        int col = (colt+u)*16 + (lane & 15);
        bf16x8 b = *(const bf16x8*)(Bt + (size_t)col*128 + kk + koff);
        acc2[u] = mfma16(a, b, acc2[u]);
      }
    }
    float* xp = X + (size_t)n*3712;
    #pragma unroll
    for (int u = 0; u < 2; u++){
      int col = (colt+u)*16 + (lane & 15);
      #pragma unroll
      for (int r = 0; r < 4; r++){
        int r32 = mtile*16 + (lane>>4)*4 + r;
        if (r32 < KM) xp[r32*128 + col] += acc2[u][r];
      }
    }
  }
}

// ---------------- per-layer: gated FFN (MFMA) ----------------
__global__ __launch_bounds__(256) void k_ffn(
    float* __restrict__ X, const float* __restrict__ gamma2, const float* __restrict__ Wfg,
    const bf16_t* __restrict__ Wf1T, const bf16_t* __restrict__ Wf2T, int layer)
{
  __shared__ bf16_t ys16[32*136];
  __shared__ bf16_t hs16[32*136];
  __shared__ float gf[128];
  int n = blockIdx.x, t = threadIdx.x;
  int wid = t >> 6, lane = t & 63;
  float* xp = X + (size_t)n*3712;
  const float* g2 = gamma2 + layer*128;
  for (int k = wid; k < KM; k += 4){
    float x0 = xp[k*128+lane], x1 = xp[k*128+64+lane];
    float ss = wave_reduce_sum(x0*x0+x1*x1);
    float sc = rsqrtf(ss*(1.0f/128.0f)+1e-6f);
    ys16[k*136+lane]    = (bf16_t)(x0*sc*g2[lane]);
    ys16[k*136+64+lane] = (bf16_t)(x1*sc*g2[64+lane]);
  }
  __syncthreads();
  const float* Wfgp = Wfg + (size_t)layer*16384;
  if (t < 128){
    float acc = 0.f;
    for (int c = 0; c < 128; c++) acc += (float)ys16[c]*Wfgp[c*128 + t];
    gf[t] = silu_f(acc);
  }
  __syncthreads();
  int mtile = wid >> 1;
  int nt0 = (wid&1)*4;
  int row = mtile*16 + (lane&15);
  int koff = (lane>>4)*8;
  {
    const bf16_t* Bt = Wf1T + (size_t)layer*16384;
    f32x4 acc[4] = {{0,0,0,0},{0,0,0,0},{0,0,0,0},{0,0,0,0}};
    #pragma unroll
    for (int kk = 0; kk < 128; kk += 32){
      bf16x8 a = *(const bf16x8*)(ys16 + row*136 + kk + koff);
      #pragma unroll
      for (int u = 0; u < 4; u++){
        int col = (nt0+u)*16 + (lane&15);
        bf16x8 b = *(const bf16x8*)(Bt + (size_t)col*128 + kk + koff);
        acc[u] = mfma16(a, b, acc[u]);
      }
    }
    #pragma unroll
    for (int u = 0; u < 4; u++){
      int col = (nt0+u)*16 + (lane&15);
      float gfc = gf[col];
      #pragma unroll
      for (int r = 0; r < 4; r++){
        int r32 = mtile*16 + (lane>>4)*4 + r;
        hs16[r32*136 + col] = (bf16_t)(acc[u][r]*gfc);
      }
    }
  }
  __syncthreads();
  {
    const bf16_t* Bt = Wf2T + (size_t)layer*16384;
    f32x4 acc[4] = {{0,0,0,0},{0,0,0,0},{0,0,0,0},{0,0,0,0}};
    #pragma unroll
    for (int kk = 0; kk < 128; kk += 32){
      bf16x8 a = *(const bf16x8*)(hs16 + row*136 + kk + koff);
      #pragma unroll
      for (int u = 0; u < 4; u++){
        int col = (nt0+u)*16 + (lane&15);
        bf16x8 b = *(const bf16x8*)(Bt + (size_t)col*128 + kk + koff);
        acc[u] = mfma16(a, b, acc[u]);
      }
    }
    #pragma unroll
    for (int u = 0; u < 4; u++){
      int col = (nt0+u)*16 + (lane&15);
      #pragma unroll
      for (int r = 0; r < 4; r++){
        int r32 = mtile*16 + (lane>>4)*4 + r;
        if (r32 < KM) xp[r32*128 + col] += acc[u][r];
      }
    }
  }
}

// ---------------- output head ----------------
__global__ __launch_bounds__(256) void k_head(
    const float* __restrict__ X, const float* __restrict__ Wh1, const float* __restrict__ Wh2,
    float* __restrict__ partial, int N)
{
  __shared__ float wsum[4];
  int t = threadIdx.x;
  int half = t >> 7;
  int n = blockIdx.x*2 + half;
  int f = t & 127;
  float sv = 0.f;
  if (n < N){
    const float* xp = X + (size_t)n*3712;
    float acc = 0.f;
    for (int c = 0; c < 128; c++) acc += xp[c]*Wh1[c*128 + f];
    sv = silu_f(acc)*Wh2[f];
  }
  sv = wave_reduce_sum(sv);
  if ((t & 63) == 0) wsum[t >> 6] = sv;
  __syncthreads();
  if (t == 0) partial[blockIdx.x] = wsum[0] + wsum[1] + wsum[2] + wsum[3];
}

__global__ __launch_bounds__(256) void k_reduce(const float* __restrict__ partial, float* __restrict__ out, int P){
  __shared__ float sh[256];
  int t = threadIdx.x;
  float s = 0.f;
  for (int i = t; i < P; i += 256) s += partial[i];
  sh[t] = s; __syncthreads();
  for (int off = 128; off > 0; off >>= 1){
    if (t < off) sh[t] += sh[t+off];
    __syncthreads();
  }
  if (t == 0) out[0] = sh[0] / 77.81317f;
}

extern "C" void kernel_launch(void* const* d_in, const int* in_sizes, int n_in,
                              void* d_out, int out_size, void* d_ws, size_t ws_size,
                              hipStream_t stream)
{
  const int*   Z      = (const int*)d_in[0];
  const int*   EI     = (const int*)d_in[1];
  const float* ed     = (const float*)d_in[2];
  const float* emb    = (const float*)d_in[3];
  const float* We0    = (const float*)d_in[4];
  const float* be0    = (const float*)d_in[5];
  const float* We1    = (const float*)d_in[6];
  const float* be1    = (const float*)d_in[7];
  const float* Weproj = (const float*)d_in[8];
  const float* gamma1 = (const float*)d_in[9];
  const float* gamma2 = (const float*)d_in[10];
  const float* Wr0    = (const float*)d_in[11];
  const float* Wr1    = (const float*)d_in[12];
  const float* Wrl    = (const float*)d_in[13];
  const float* Wmsg   = (const float*)d_in[14];
  const float* Wap    = (const float*)d_in[15];
  const float* wa     = (const float*)d_in[16];
  const float* Wg     = (const float*)d_in[17];
  const float* Wv     = (const float*)d_in[18];
  const float* Wo     = (const float*)d_in[19];
  const float* Wf1    = (const float*)d_in[20];
  const float* Wfg    = (const float*)d_in[21];
  const float* Wf2    = (const float*)d_in[22];
  const float* Wh1    = (const float*)d_in[23];
  const float* Wh2    = (const float*)d_in[24];

  const int N = in_sizes[0];
  const int E = in_sizes[2];

  float* ws = (float*)d_ws;
  size_t o = 0;
  auto alloc = [&](size_t nf){ float* p = ws + o; o += (nf + 7) & ~(size_t)7; return p; };

  float* X      = alloc((size_t)N*3712);
  float* P0     = alloc((size_t)N*64);
  float* Q0     = alloc((size_t)N*64);
  float* logi   = alloc((size_t)E*8);
  float* part   = alloc((size_t)((N+1)/2) + 8);
  float* radtab = alloc((size_t)GTAB*28);
  bf16_t* qmb   = (bf16_t*)alloc((size_t)N*928);       // N*1856 bf16; h2tab aliases here
  float* h2tab  = (float*)qmb;                          // GTAB*128 f32 = 2.1MB < qmb 11.1MB; disjoint lifetimes
  bf16_t* PVb   = (bf16_t*)alloc((size_t)N*2048);      // N*4096 bf16 ([hv][k-pad32])
  bf16_t* gate16= (bf16_t*)alloc((size_t)E*64);        // E*128 bf16
  bf16_t* arena = (bf16_t*)alloc(385024);              // 770048 bf16
  int* rowptr = (int*)alloc((size_t)N+8);
  int* curs   = (int*)alloc((size_t)N);
  int* order  = (int*)alloc((size_t)E);
  // total ~198.7 MB for N=6000, E=120000 (R2 passed at 199.5 MB)

  bf16_t* WmsgCT  = arena;            // [4][128][128]
  bf16_t* WvT     = arena + 65536;    // [4][128][64]
  bf16_t* WoT     = arena + 98304;    // [4][128][128]
  bf16_t* Wf1T    = arena + 163840;
  bf16_t* Wf2T    = arena + 229376;
  bf16_t* WeprojT = arena + 294912;   // [3712][128]

  // CSR by target
  hipMemsetAsync(curs, 0, sizeof(int)*N, stream);
  k_count<<<(E+255)/256, 256, 0, stream>>>(EI, curs, E);
  k_scan<<<1, 1024, 0, stream>>>(curs, rowptr, N);
  k_fill<<<(E+255)/256, 256, 0, stream>>>(EI, curs, order, E);
  k_sort<<<(N+255)/256, 256, 0, stream>>>(rowptr, order, N);

  // weight transposes -> bf16 arenas
  k_tr2<<<256, 256, 0, stream>>>(Wmsg, WmsgCT);
  k_tr<<<128, 256, 0, stream>>>(Wv,   WvT,  4, 64, 128, 8192);
  k_tr<<<256, 256, 0, stream>>>(Wo,   WoT,  4, 128, 128, 16384);
  k_tr<<<256, 256, 0, stream>>>(Wf1,  Wf1T, 4, 128, 128, 16384);
  k_tr<<<256, 256, 0, stream>>>(Wf2,  Wf2T, 4, 128, 128, 16384);
  k_tr<<<1856, 256, 0, stream>>>(Weproj, WeprojT, 1, 128, 3712, 0);

  // radial tables + x init (h2tab lives in qmb space until first k_pqv)
  k_tab_embed<<<GTAB/4, 256, 0, stream>>>(We0, be0, We1, be1, Wr0, Wr1, Wrl, h2tab, radtab);
  k_init_x<<<(N+31)/32, 256, 0, stream>>>(Z, ed, emb, WeprojT, h2tab, rowptr, order, X, N);

  for (int i = 0; i < 4; i++){
    k_pqv<<<N, 256, 0, stream>>>(X, gamma1, WmsgCT, WvT, PVb, qmb, P0, Q0, i);
    k_edge_logits<<<(E+15)/16, 256, 0, stream>>>(EI, ed, P0, Q0, radtab, Wap, wa, Wg, logi, gate16, E, i);
    k_attn<<<N, 512, 0, stream>>>(EI, rowptr, order, ed, qmb, WvT, WoT, PVb, gate16, logi, radtab, X, i);
    k_ffn<<<N, 256, 0, stream>>>(X, gamma2, Wfg, Wf1T, Wf2T, i);
  }

  int PB = (N+1)/2;
  k_head<<<PB, 256, 0, stream>>>(X, Wh1, Wh2, part, N);
  k_reduce<<<1, 256, 0, stream>>>(part, (float*)d_out, PB);
}

// Round 5
// 2806.634 us; speedup vs baseline: 1.1780x; 1.1780x over previous
//
#include <hip/hip_runtime.h>

#define KM 29
#define GTAB 4096

typedef __bf16 bf16_t;
typedef __bf16 bf16x8 __attribute__((ext_vector_type(8)));
typedef __bf16 bf16x4 __attribute__((ext_vector_type(4)));
typedef float  f32x4  __attribute__((ext_vector_type(4)));

__device__ __forceinline__ float silu_f(float x){ return x / (1.0f + __expf(-x)); }

__device__ __forceinline__ float wave_reduce_sum(float v){
  #pragma unroll
  for (int s = 1; s < 64; s <<= 1) v += __shfl_xor(v, s);
  return v;
}

// l-of-k with clamp for pad rows 29..31 (their data is zero)
__device__ __forceinline__ constexpr int LOF2(int k){
  return (k<1)?0 : (k<4)?1 : (k<9)?2 : (k<14)?3 : (k<19)?4 : (k<24)?5 : 6;
}

__device__ __forceinline__ f32x4 mfma16(bf16x8 a, bf16x8 b, f32x4 c){
  return __builtin_amdgcn_mfma_f32_16x16x32_bf16(a, b, c, 0, 0, 0);
}

__device__ __forceinline__ float env_f(float d){
  float xx = d*(1.0f/12.0f);
  float x2 = xx*xx, x4 = x2*x2, x5 = x4*xx;
  float env = 1.0f - 21.0f*x5 + 35.0f*x5*xx - 15.0f*x5*x2;
  return (xx < 1.0f) ? env : 0.0f;
}

// ---------------- CSR build ----------------
__global__ void k_count(const int* __restrict__ EI, int* __restrict__ cnt, int E){
  int e = blockIdx.x*256 + threadIdx.x;
  if (e < E) atomicAdd(&cnt[EI[E+e]], 1);
}

__global__ __launch_bounds__(1024) void k_scan(int* __restrict__ cnt, int* __restrict__ rowptr, int N){
  __shared__ int ts[1024];
  int t = threadIdx.x;
  int base = t*8;
  int loc[8]; int sum = 0;
  #pragma unroll
  for (int u = 0; u < 8; u++){ int idx = base+u; int v = (idx < N) ? cnt[idx] : 0; loc[u] = sum; sum += v; }
  ts[t] = sum; __syncthreads();
  for (int off = 1; off < 1024; off <<= 1){
    int v = (t >= off) ? ts[t-off] : 0;
    __syncthreads();
    ts[t] += v;
    __syncthreads();
  }
  int excl = ts[t] - sum;
  #pragma unroll
  for (int u = 0; u < 8; u++){
    int idx = base+u;
    if (idx < N){ int r = excl + loc[u]; rowptr[idx] = r; cnt[idx] = r; }
  }
  if (t == 1023) rowptr[N] = ts[1023];
}

__global__ void k_fill(const int* __restrict__ EI, int* __restrict__ cur, int* __restrict__ order, int E){
  int e = blockIdx.x*256 + threadIdx.x;
  if (e < E){ int pos = atomicAdd(&cur[EI[E+e]], 1); order[pos] = e; }
}

__global__ void k_sort(const int* __restrict__ rowptr, int* __restrict__ order, int N){
  int n = blockIdx.x*256 + threadIdx.x;
  if (n >= N) return;
  int rp = rowptr[n], re = rowptr[n+1];
  for (int a = rp+1; a < re; a++){
    int key = order[a]; int b = a-1;
    while (b >= rp && order[b] > key){ order[b+1] = order[b]; b--; }
    order[b+1] = key;
  }
}

// ---------------- weight transposes ----------------
__global__ void k_tr(const float* __restrict__ src, bf16_t* __restrict__ dst,
                     int L, int R, int C, int Lstr){
  int idx = blockIdx.x*256 + threadIdx.x;
  int total = L*R*C;
  if (idx >= total) return;
  int l = idx / (R*C); int rem = idx - l*(R*C);
  int r = rem / C; int c = rem - r*C;
  dst[((size_t)l*C + c)*R + r] = (bf16_t)src[(size_t)l*Lstr + (size_t)r*C + c];
}

// Wmsg [4][256][64] -> combined [4][128 cols][128 k]; col<64 = P-half, col>=64 = Q-half
__global__ void k_tr2(const float* __restrict__ src, bf16_t* __restrict__ dst){
  int idx = blockIdx.x*256 + threadIdx.x;
  if (idx >= 4*128*128) return;
  int l = idx >> 14; int j = (idx >> 7) & 127; int c = idx & 127;
  float v = (j < 64) ? src[(size_t)l*16384 + c*64 + j]
                     : src[(size_t)l*16384 + 8192 + c*64 + (j-64)];
  dst[idx] = (bf16_t)v;
}

// ---------------- radial MLP table build ----------------
__global__ __launch_bounds__(256) void k_tab_embed(
    const float* __restrict__ We0, const float* __restrict__ be0,
    const float* __restrict__ We1, const float* __restrict__ be1,
    const float* __restrict__ Wr0, const float* __restrict__ Wr1, const float* __restrict__ Wrl,
    float* __restrict__ h2tab, float* __restrict__ radtab)
{
  __shared__ float sb[4][640];
  const int wid = threadIdx.x >> 6, lane = threadIdx.x & 63;
  const int e = blockIdx.x*4 + wid;
  if (e >= GTAB) return;
  const float d = e * (12.0f/(GTAB-1));
  const float DLT = 12.0f/599.0f;
  const float CO  = -0.5f/((2.0f*DLT)*(2.0f*DLT));
  int jc = (int)(d/DLT + 0.5f);
  int j0 = jc - 16; if (j0 < 0) j0 = 0; if (j0 > 600-32) j0 = 600-32;
  float diff = d - (float)(j0+lane)*DLT;
  float gval = __expf(CO*diff*diff);
  float p[10];
  #pragma unroll
  for (int u = 0; u < 10; u++) p[u] = 0.f;
  const int c2 = 2*lane;
  for (int jj = 0; jj < 32; jj++){
    float gj = __shfl(gval, jj);
    int row = j0 + jj;
    const float2 w0 = *(const float2*)(We0 + row*128 + c2);
    p[0] += gj*w0.x; p[1] += gj*w0.y;
    #pragma unroll
    for (int i = 0; i < 4; i++){
      const float2 wr = *(const float2*)(Wr0 + ((size_t)i*600 + row)*128 + c2);
      p[2+2*i] += gj*wr.x; p[3+2*i] += gj*wr.y;
    }
  }
  sb[wid][c2]   = silu_f(p[0] + be0[c2]);
  sb[wid][c2+1] = silu_f(p[1] + be0[c2+1]);
  #pragma unroll
  for (int i = 0; i < 4; i++){
    sb[wid][128 + 128*i + c2]   = silu_f(p[2+2*i]);
    sb[wid][128 + 128*i + c2+1] = silu_f(p[3+2*i]);
  }
  float a0 = 0.f, a1 = 0.f;
  for (int c = 0; c < 128; c++){
    float hv = sb[wid][c];
    const float2 w = *(const float2*)(We1 + c*128 + c2);
    a0 += hv*w.x; a1 += hv*w.y;
  }
  a0 = silu_f(a0 + be1[c2]); a1 = silu_f(a1 + be1[c2+1]);
  h2tab[(size_t)e*128 + c2]     = a0;
  h2tab[(size_t)e*128 + c2 + 1] = a1;
  #pragma unroll
  for (int i = 0; i < 4; i++){
    float r0 = 0.f, r1 = 0.f;
    const float* W1 = Wr1 + (size_t)i*128*128;
    for (int c = 0; c < 128; c++){
      float rv = sb[wid][128 + 128*i + c];
      const float2 w = *(const float2*)(W1 + c*128 + c2);
      r0 += rv*w.x; r1 += rv*w.y;
    }
    r0 = silu_f(r0); r1 = silu_f(r1);
    const float* Wl = Wrl + (size_t)i*128*7;
    float pl[7];
    #pragma unroll
    for (int l = 0; l < 7; l++) pl[l] = r0*Wl[c2*7+l] + r1*Wl[(c2+1)*7+l];
    #pragma unroll
    for (int l = 0; l < 7; l++) pl[l] = wave_reduce_sum(pl[l]);
    if (lane == 0){
      #pragma unroll
      for (int l = 0; l < 7; l++) radtab[(size_t)e*28 + i*7 + l] = pl[l];
    }
  }
}

// ---------------- x init ----------------
__global__ __launch_bounds__(256) void k_init_x(
    const int* __restrict__ Z, const float* __restrict__ ed, const float* __restrict__ emb,
    const bf16_t* __restrict__ WeprojT, const float* __restrict__ h2tab,
    const int* __restrict__ rowptr, const int* __restrict__ order,
    float* __restrict__ X, int N)
{
  __shared__ bf16_t h2s[32*136];
  __shared__ int Zs[32];
  int n0 = blockIdx.x*32, t = threadIdx.x;
  int half = t >> 7, ch = t & 127;
  for (int pair = 0; pair < 16; pair++){
    int nn = pair*2 + half;
    int n = n0 + nn;
    float acc = 0.f;
    if (n < N){
      int rp = rowptr[n], deg = rowptr[n+1]-rp;
      for (int idx = 0; idx < deg; idx++){
        int e = order[rp+idx];
        float d = ed[e];
        float u = d * ((GTAB-1)/12.0f);
        int j = (int)u; if (j > GTAB-2) j = GTAB-2;
        float f = u - (float)j;
        float a = h2tab[(size_t)j*128 + ch], b = h2tab[(size_t)(j+1)*128 + ch];
        acc += a + f*(b-a);
      }
    }
    h2s[nn*136 + ch] = (bf16_t)acc;
  }
  if (t < 32) Zs[t] = (n0 + t < N) ? Z[n0+t] : 0;
  __syncthreads();
  int wid = t >> 6, lane = t & 63;
  int mtile = wid & 1;
  int row = mtile*16 + (lane & 15);
  int koff = (lane >> 4)*8;
  bf16x8 afr[4];
  #pragma unroll
  for (int kk = 0; kk < 4; kk++) afr[kk] = *(const bf16x8*)(h2s + row*136 + kk*32 + koff);
  for (int nt = (wid>>1); nt < 232; nt += 2){
    f32x4 acc = {0.f,0.f,0.f,0.f};
    int col = nt*16 + (lane & 15);
    #pragma unroll
    for (int kk = 0; kk < 4; kk++){
      bf16x8 b = *(const bf16x8*)(WeprojT + (size_t)col*128 + kk*32 + koff);
      acc = mfma16(afr[kk], b, acc);
    }
    #pragma unroll
    for (int r = 0; r < 4; r++){
      int r32 = mtile*16 + (lane>>4)*4 + r;
      int n = n0 + r32;
      if (n < N){
        float v = acc[r] * (1.0f/23.395238876342773f);
        if (col < 128) v += emb[(size_t)Zs[r32]*128 + col];
        X[(size_t)n*3712 + col] = v;
      }
    }
  }
}

// ---------------- per-layer: rms + combined [P|Q] GEMM + PV + qm + P0/Q0 ----------------
__global__ __launch_bounds__(256) void k_pqv(
    const float* __restrict__ X, const float* __restrict__ gamma1,
    const bf16_t* __restrict__ WmsgCT, const bf16_t* __restrict__ WvT,
    bf16_t* __restrict__ PVb, bf16_t* __restrict__ qmb,
    float* __restrict__ P0, float* __restrict__ Q0, int layer)
{
  __shared__ bf16_t ys16[32*136];
  __shared__ bf16_t pq16[32*136];
  int n = blockIdx.x, t = threadIdx.x;
  int wid = t >> 6, lane = t & 63;
  const float* g1 = gamma1 + layer*128;
  const float* xp = X + (size_t)n*3712;
  for (int k = wid; k < KM; k += 4){
    float x0 = xp[k*128 + lane], x1 = xp[k*128 + 64 + lane];
    float ss = wave_reduce_sum(x0*x0 + x1*x1);
    float sc = rsqrtf(ss*(1.0f/128.0f) + 1e-6f);
    ys16[k*136 + lane]      = (bf16_t)(x0*sc*g1[lane]);
    ys16[k*136 + 64 + lane] = (bf16_t)(x1*sc*g1[64+lane]);
  }
  for (int idx = t; idx < 3*136; idx += 256) ys16[29*136 + idx] = (bf16_t)0.f;
  __syncthreads();
  int mtile = wid >> 1;
  int row = mtile*16 + (lane & 15);
  int koff = (lane >> 4)*8;
  {
    const bf16_t* Bc = WmsgCT + (size_t)layer*16384;
    f32x4 acc[4] = {{0,0,0,0},{0,0,0,0},{0,0,0,0},{0,0,0,0}};
    #pragma unroll
    for (int kk = 0; kk < 128; kk += 32){
      bf16x8 a = *(const bf16x8*)(ys16 + row*136 + kk + koff);
      #pragma unroll
      for (int u = 0; u < 4; u++){
        int col = ((wid&1)*4+u)*16 + (lane & 15);
        bf16x8 b = *(const bf16x8*)(Bc + (size_t)col*128 + kk + koff);
        acc[u] = mfma16(a, b, acc[u]);
      }
    }
    #pragma unroll
    for (int u = 0; u < 4; u++){
      int col = ((wid&1)*4+u)*16 + (lane & 15);
      #pragma unroll
      for (int r = 0; r < 4; r++){
        int r32 = mtile*16 + (lane>>4)*4 + r;
        pq16[r32*136 + col] = (bf16_t)acc[u][r];
      }
      if (mtile == 0 && (lane>>4) == 0){
        float v = acc[u][0];
        if (col < 64) P0[(size_t)n*64 + col] = v;
        else          Q0[(size_t)n*64 + col - 64] = v;
      }
    }
  }
  __syncthreads();
  {
    const bf16_t* Bt = WvT + (size_t)layer*8192;
    int colt = (wid & 1)*4;
    f32x4 acc[4] = {{0,0,0,0},{0,0,0,0},{0,0,0,0},{0,0,0,0}};
    #pragma unroll
    for (int kk = 0; kk < 64; kk += 32){
      bf16x8 a = *(const bf16x8*)(pq16 + row*136 + kk + koff);
      #pragma unroll
      for (int u = 0; u < 4; u++){
        int col = (colt+u)*16 + (lane & 15);
        bf16x8 b = *(const bf16x8*)(Bt + (size_t)col*64 + kk + koff);
        acc[u] = mfma16(a, b, acc[u]);
      }
    }
    bf16_t* pvp = PVb + (size_t)n*4096;
    int r0i = mtile*16 + (lane>>4)*4;
    #pragma unroll
    for (int u = 0; u < 4; u++){
      int col = (colt+u)*16 + (lane & 15);
      bf16x4 pack;
      #pragma unroll
      for (int r = 0; r < 4; r++){
        int r32 = r0i + r;
        pack[r] = (r32 < KM) ? (bf16_t)acc[u][r] : (bf16_t)0.f;
      }
      *(bf16x4*)(pvp + col*32 + r0i) = pack;
    }
  }
  for (int idx = t; idx < KM*64; idx += 256){
    int k = idx >> 6, j = idx & 63;
    qmb[(size_t)n*1856 + idx] = pq16[k*136 + 64 + j];
  }
}

// ---------------- per-layer: edge logits + gate ----------------
__global__ __launch_bounds__(256) void k_edge_logits(
    const int* __restrict__ EI, const float* __restrict__ ed,
    const float* __restrict__ P0, const float* __restrict__ Q0,
    const float* __restrict__ radtab, const float* __restrict__ Wap, const float* __restrict__ wa,
    const float* __restrict__ Wg, float* __restrict__ logi, bf16_t* __restrict__ gate16,
    int E, int layer)
{
  __shared__ float m0s[16*64];
  __shared__ int   srcs[16], tgts[16];
  __shared__ float r0s[16];
  int t = threadIdx.x;
  int eb = blockIdx.x*16;
  if (t < 16){
    int e = eb + t;
    if (e < E){
      srcs[t] = EI[e]; tgts[t] = EI[E+e];
      float d = ed[e];
      float u = d * ((GTAB-1)/12.0f);
      int j = (int)u; if (j > GTAB-2) j = GTAB-2;
      float f = u - (float)j;
      float a = radtab[(size_t)j*28 + layer*7], b = radtab[(size_t)(j+1)*28 + layer*7];
      r0s[t] = a + f*(b-a);
    }
  }
  __syncthreads();
  #pragma unroll
  for (int u = 0; u < 4; u++){
    int idx = t + u*256;
    int i = idx >> 6, j = idx & 63;
    if (eb + i < E) m0s[idx] = (P0[(size_t)srcs[i]*64 + j] + Q0[(size_t)tgts[i]*64 + j]) * r0s[i];
  }
  __syncthreads();
  int wid = t >> 6, lane = t & 63;
  const float* Wa  = Wap + (size_t)layer*16384;
  const float* Wgp = Wg  + (size_t)layer*8192;
  const int o4 = 4*lane, c2 = 2*lane;
  float pa[4][4] = {};
  float gg[4][2] = {};
  for (int j = 0; j < 64; j++){
    const float4 w4  = *(const float4*)(Wa + j*256 + o4);
    const float2 wg2 = *(const float2*)(Wgp + j*128 + c2);
    #pragma unroll
    for (int q = 0; q < 4; q++){
      float mj = m0s[(wid*4+q)*64 + j];
      pa[q][0] += mj*w4.x; pa[q][1] += mj*w4.y; pa[q][2] += mj*w4.z; pa[q][3] += mj*w4.w;
      gg[q][0] += mj*wg2.x; gg[q][1] += mj*wg2.y;
    }
  }
  const float* wav = wa + layer*256;
  float wa0 = wav[o4], wa1 = wav[o4+1], wa2 = wav[o4+2], wa3 = wav[o4+3];
  #pragma unroll
  for (int q = 0; q < 4; q++){
    int e = eb + wid*4 + q;
    if (e >= E) continue;
    gate16[(size_t)e*128 + c2]     = (bf16_t)silu_f(gg[q][0]);
    gate16[(size_t)e*128 + c2 + 1] = (bf16_t)silu_f(gg[q][1]);
    float lg = silu_f(pa[q][0])*wa0 + silu_f(pa[q][1])*wa1 + silu_f(pa[q][2])*wa2 + silu_f(pa[q][3])*wa3;
    lg += __shfl_xor(lg, 1); lg += __shfl_xor(lg, 2); lg += __shfl_xor(lg, 4);
    if ((lane & 7) == 0) logi[(size_t)e*8 + (lane >> 3)] = lg;
  }
}

// ---------------- fused per-layer: attn (softmax+gather+QV+Wo) + FFN; x in LDS ----------------
__global__ __launch_bounds__(512, 4) void k_attn_ffn(
    const int* __restrict__ EI, const int* __restrict__ rowptr, const int* __restrict__ order,
    const float* __restrict__ ed, const bf16_t* __restrict__ qmb,
    const bf16_t* __restrict__ WvT, const bf16_t* __restrict__ WoT,
    const bf16_t* __restrict__ PVb, const bf16_t* __restrict__ gate16,
    const float* __restrict__ logi, const float* __restrict__ radtab,
    const float* __restrict__ gamma2, const float* __restrict__ Wfg,
    const bf16_t* __restrict__ Wf1T, const bf16_t* __restrict__ Wf2T,
    float* __restrict__ X, int layer)
{
  __shared__ float  xs[3712];        // x residual, fp32, persistent
  __shared__ bf16_t ysag[32*136];    // attn: ag16 (Wo input); ffn: ys16
  __shared__ bf16_t hsqv[32*136];    // attn: qvs16; ffn: hs16
  __shared__ char   uA[4608];        // qm16, then {at8, rl7, es, srcs}
  __shared__ float  agf[4096];       // attn: fp32 merge; ffn: gfp/gf
  __shared__ float  mh[8], iden[8];

  bf16_t* qm16 = (bf16_t*)uA;
  float*  at8  = (float*)uA;
  float*  rl7  = (float*)(uA + 2048);
  int*    es   = (int*)(uA + 4096);
  int*    srcs = (int*)(uA + 4352);

  int n = blockIdx.x, t = threadIdx.x;
  int wid = t >> 6, lane = t & 63;
  int rp = rowptr[n], deg = rowptr[n+1] - rp;

  // load x into LDS
  for (int idx = t; idx < 3712; idx += 512) xs[idx] = X[(size_t)n*3712 + idx];

  if (deg > 0){
    // qm -> LDS (+pads)
    for (int idx = t; idx < KM*64; idx += 512){
      int k = idx >> 6, j = idx & 63;
      qm16[k*72 + j] = qmb[(size_t)n*1856 + idx];
    }
    for (int idx = t; idx < 3*72; idx += 512) qm16[29*72 + idx] = (bf16_t)0.f;
    // softmax stats (8 lanes per head)
    if (t < 64){
      int hh = t & 7, slot = t >> 3;
      float m = -3.0e38f;
      for (int idx = slot; idx < deg; idx += 8){
        int e = order[rp+idx];
        m = fmaxf(m, logi[(size_t)e*8 + hh]);
      }
      m = fmaxf(m, __shfl_xor(m, 8));
      m = fmaxf(m, __shfl_xor(m, 16));
      m = fmaxf(m, __shfl_xor(m, 32));
      float den = 0.f;
      for (int idx = slot; idx < deg; idx += 8){
        int e = order[rp+idx];
        den += env_f(ed[e]) * __expf(logi[(size_t)e*8 + hh] - m);
      }
      den += __shfl_xor(den, 8);
      den += __shfl_xor(den, 16);
      den += __shfl_xor(den, 32);
      if (t < 8){ mh[t] = m; iden[t] = 1.0f/(den + 1e-16f); }
    }
    __syncthreads();
    // QV GEMM: hsqv = qm16 @ WvT (K=64, 8 waves)
    {
      const bf16_t* Bt = WvT + (size_t)layer*8192;
      int mtile = wid >> 2, colt = (wid & 3)*2;
      int row = mtile*16 + (lane & 15);
      int koff = (lane >> 4)*8;
      f32x4 a2[2] = {{0,0,0,0},{0,0,0,0}};
      #pragma unroll
      for (int kk = 0; kk < 64; kk += 32){
        bf16x8 a = *(const bf16x8*)(qm16 + row*72 + kk + koff);
        #pragma unroll
        for (int u = 0; u < 2; u++){
          int col = (colt+u)*16 + (lane & 15);
          bf16x8 b = *(const bf16x8*)(Bt + (size_t)col*64 + kk + koff);
          a2[u] = mfma16(a, b, a2[u]);
        }
      }
      #pragma unroll
      for (int u = 0; u < 2; u++){
        int col = (colt+u)*16 + (lane & 15);
        #pragma unroll
        for (int r = 0; r < 4; r++){
          int r32 = mtile*16 + (lane>>4)*4 + r;
          hsqv[r32*136 + col] = (bf16_t)a2[u][r];
        }
      }
    }
    __syncthreads();   // qvs ready; qm dead -> uA reused by at8/rl7/es/srcs
    // gather: eg in {0..3} x hv in {0..127}; each thread owns all 32 k
    int eg = t >> 7, hv = t & 127, h = hv >> 4;
    float acc[32];
    #pragma unroll
    for (int j = 0; j < 32; j++) acc[j] = 0.f;
    float S[7];
    #pragma unroll
    for (int l = 0; l < 7; l++) S[l] = 0.f;
    for (int base = 0; base < deg; base += 64){
      int ne = min(64, deg - base);
      if (t < ne){ int e = order[rp + base + t]; es[t] = e; srcs[t] = EI[e]; }
      __syncthreads();
      if (t < ne*8){
        int i = t >> 3, q = t & 7;
        int e = es[i];
        float d = ed[e];
        at8[t] = env_f(d) * __expf(logi[(size_t)e*8 + q] - mh[q]) * iden[q];
        if (q < 7){
          float u = d * ((GTAB-1)/12.0f);
          int j = (int)u; if (j > GTAB-2) j = GTAB-2;
          float f = u - (float)j;
          float a = radtab[(size_t)j*28 + layer*7 + q], b = radtab[(size_t)(j+1)*28 + layer*7 + q];
          rl7[t] = a + f*(b-a);
        }
      }
      __syncthreads();
      // 2-deep register-prefetched edge loop
      bf16x8 va0, va1, va2, va3; float gcur = 0.f;
      int i = eg;
      if (i < ne){
        const bf16x8* p = (const bf16x8*)(PVb + (size_t)srcs[i]*4096 + hv*32);
        va0 = p[0]; va1 = p[1]; va2 = p[2]; va3 = p[3];
        gcur = (float)gate16[(size_t)es[i]*128 + hv];
      }
      while (i < ne){
        int in = i + 4;
        bf16x8 vb0, vb1, vb2, vb3; float gnext = 0.f;
        if (in < ne){
          const bf16x8* p = (const bf16x8*)(PVb + (size_t)srcs[in]*4096 + hv*32);
          vb0 = p[0]; vb1 = p[1]; vb2 = p[2]; vb3 = p[3];
          gnext = (float)gate16[(size_t)es[in]*128 + hv];
        }
        float w = gcur * at8[i*8 + h];
        float rw[7];
        #pragma unroll
        for (int l = 0; l < 7; l++){ rw[l] = rl7[i*8 + l]*w; S[l] += rw[l]; }
        #pragma unroll
        for (int j = 0; j < 8; j++) acc[j]    += (float)va0[j]*rw[LOF2(j)];
        #pragma unroll
        for (int j = 0; j < 8; j++) acc[8+j]  += (float)va1[j]*rw[LOF2(8+j)];
        #pragma unroll
        for (int j = 0; j < 8; j++) acc[16+j] += (float)va2[j]*rw[LOF2(16+j)];
        #pragma unroll
        for (int j = 0; j < 8; j++) acc[24+j] += (float)va3[j]*rw[LOF2(24+j)];
        va0 = vb0; va1 = vb1; va2 = vb2; va3 = vb3;
        gcur = gnext;
        i = in;
      }
      __syncthreads();
    }
    // QV * S (per-group partial S sums correctly across merge)
    #pragma unroll
    for (int j = 0; j < 32; j++)
      acc[j] += (float)hsqv[j*136 + hv] * S[LOF2(j)];
    // merge 4 groups in fp32 LDS
    for (int g = 0; g < 4; g++){
      if (eg == g){
        #pragma unroll
        for (int j = 0; j < 32; j++){
          if (g == 0) agf[j*128 + hv] = acc[j];
          else        agf[j*128 + hv] += acc[j];
        }
      }
      __syncthreads();
    }
    // convert to bf16 for Wo MFMA
    for (int idx = t; idx < 32*128; idx += 512){
      int k = idx >> 7, c = idx & 127;
      ysag[k*136 + c] = (bf16_t)agf[idx];
    }
    __syncthreads();
    // Wo GEMM: xs += ag @ WoT (K=128, 8 waves)
    {
      const bf16_t* Bt = WoT + (size_t)layer*16384;
      int mtile = wid >> 2, colt = (wid & 3)*2;
      int row = mtile*16 + (lane & 15);
      int koff = (lane >> 4)*8;
      f32x4 a2[2] = {{0,0,0,0},{0,0,0,0}};
      #pragma unroll
      for (int kk = 0; kk < 128; kk += 32){
        bf16x8 a = *(const bf16x8*)(ysag + row*136 + kk + koff);
        #pragma unroll
        for (int u = 0; u < 2; u++){
          int col = (colt+u)*16 + (lane & 15);
          bf16x8 b = *(const bf16x8*)(Bt + (size_t)col*128 + kk + koff);
          a2[u] = mfma16(a, b, a2[u]);
        }
      }
      #pragma unroll
      for (int u = 0; u < 2; u++){
        int col = (colt+u)*16 + (lane & 15);
        #pragma unroll
        for (int r = 0; r < 4; r++){
          int r32 = mtile*16 + (lane>>4)*4 + r;
          if (r32 < KM) xs[r32*128 + col] += a2[u][r];
        }
      }
    }
  }
  __syncthreads();
  // ---------- FFN phase ----------
  const float* g2 = gamma2 + layer*128;
  for (int k = wid; k < KM; k += 8){
    float x0 = xs[k*128 + lane], x1 = xs[k*128 + 64 + lane];
    float ss = wave_reduce_sum(x0*x0 + x1*x1);
    float sc = rsqrtf(ss*(1.0f/128.0f) + 1e-6f);
    ysag[k*136 + lane]      = (bf16_t)(x0*sc*g2[lane]);
    ysag[k*136 + 64 + lane] = (bf16_t)(x1*sc*g2[64+lane]);
  }
  for (int idx = t; idx < 3*136; idx += 512) ysag[29*136 + idx] = (bf16_t)0.f;
  __syncthreads();
  // gate: 4 partials x 128
  {
    int part = t >> 7, f = t & 127;
    const float* Wfgp = Wfg + (size_t)layer*16384;
    float p = 0.f;
    for (int c = part*32; c < part*32 + 32; c++) p += (float)ysag[c] * Wfgp[c*128 + f];
    agf[part*128 + f] = p;
  }
  __syncthreads();
  if (t < 128) agf[512 + t] = silu_f(agf[t] + agf[128+t] + agf[256+t] + agf[384+t]);
  __syncthreads();
  // Wf1: hs = (ys @ Wf1T) * gf
  {
    const bf16_t* Bt = Wf1T + (size_t)layer*16384;
    int mtile = wid >> 2, colt = (wid & 3)*2;
    int row = mtile*16 + (lane & 15);
    int koff = (lane >> 4)*8;
    f32x4 a2[2] = {{0,0,0,0},{0,0,0,0}};
    #pragma unroll
    for (int kk = 0; kk < 128; kk += 32){
      bf16x8 a = *(const bf16x8*)(ysag + row*136 + kk + koff);
      #pragma unroll
      for (int u = 0; u < 2; u++){
        int col = (colt+u)*16 + (lane & 15);
        bf16x8 b = *(const bf16x8*)(Bt + (size_t)col*128 + kk + koff);
        a2[u] = mfma16(a, b, a2[u]);
      }
    }
    #pragma unroll
    for (int u = 0; u < 2; u++){
      int col = (colt+u)*16 + (lane & 15);
      float gfc = agf[512 + col];
      #pragma unroll
      for (int r = 0; r < 4; r++){
        int r32 = mtile*16 + (lane>>4)*4 + r;
        hsqv[r32*136 + col] = (bf16_t)(a2[u][r]*gfc);
      }
    }
  }
  __syncthreads();
  // Wf2: xs += hs @ Wf2T
  {
    const bf16_t* Bt = Wf2T + (size_t)layer*16384;
    int mtile = wid >> 2, colt = (wid & 3)*2;
    int row = mtile*16 + (lane & 15);
    int koff = (lane >> 4)*8;
    f32x4 a2[2] = {{0,0,0,0},{0,0,0,0}};
    #pragma unroll
    for (int kk = 0; kk < 128; kk += 32){
      bf16x8 a = *(const bf16x8*)(hsqv + row*136 + kk + koff);
      #pragma unroll
      for (int u = 0; u < 2; u++){
        int col = (colt+u)*16 + (lane & 15);
        bf16x8 b = *(const bf16x8*)(Bt + (size_t)col*128 + kk + koff);
        a2[u] = mfma16(a, b, a2[u]);
      }
    }
    #pragma unroll
    for (int u = 0; u < 2; u++){
      int col = (colt+u)*16 + (lane & 15);
      #pragma unroll
      for (int r = 0; r < 4; r++){
        int r32 = mtile*16 + (lane>>4)*4 + r;
        if (r32 < KM) xs[r32*128 + col] += a2[u][r];
      }
    }
  }
  __syncthreads();
  // store x back
  for (int idx = t; idx < 3712; idx += 512) X[(size_t)n*3712 + idx] = xs[idx];
}

// ---------------- output head ----------------
__global__ __launch_bounds__(256) void k_head(
    const float* __restrict__ X, const float* __restrict__ Wh1, const float* __restrict__ Wh2,
    float* __restrict__ partial, int N)
{
  __shared__ float wsum[4];
  int t = threadIdx.x;
  int half = t >> 7;
  int n = blockIdx.x*2 + half;
  int f = t & 127;
  float sv = 0.f;
  if (n < N){
    const float* xp = X + (size_t)n*3712;
    float acc = 0.f;
    for (int c = 0; c < 128; c++) acc += xp[c]*Wh1[c*128 + f];
    sv = silu_f(acc)*Wh2[f];
  }
  sv = wave_reduce_sum(sv);
  if ((t & 63) == 0) wsum[t >> 6] = sv;
  __syncthreads();
  if (t == 0) partial[blockIdx.x] = wsum[0] + wsum[1] + wsum[2] + wsum[3];
}

__global__ __launch_bounds__(256) void k_reduce(const float* __restrict__ partial, float* __restrict__ out, int P){
  __shared__ float sh[256];
  int t = threadIdx.x;
  float s = 0.f;
  for (int i = t; i < P; i += 256) s += partial[i];
  sh[t] = s; __syncthreads();
  for (int off = 128; off > 0; off >>= 1){
    if (t < off) sh[t] += sh[t+off];
    __syncthreads();
  }
  if (t == 0) out[0] = sh[0] / 77.81317f;
}

extern "C" void kernel_launch(void* const* d_in, const int* in_sizes, int n_in,
                              void* d_out, int out_size, void* d_ws, size_t ws_size,
                              hipStream_t stream)
{
  const int*   Z      = (const int*)d_in[0];
  const int*   EI     = (const int*)d_in[1];
  const float* ed     = (const float*)d_in[2];
  const float* emb    = (const float*)d_in[3];
  const float* We0    = (const float*)d_in[4];
  const float* be0    = (const float*)d_in[5];
  const float* We1    = (const float*)d_in[6];
  const float* be1    = (const float*)d_in[7];
  const float* Weproj = (const float*)d_in[8];
  const float* gamma1 = (const float*)d_in[9];
  const float* gamma2 = (const float*)d_in[10];
  const float* Wr0    = (const float*)d_in[11];
  const float* Wr1    = (const float*)d_in[12];
  const float* Wrl    = (const float*)d_in[13];
  const float* Wmsg   = (const float*)d_in[14];
  const float* Wap    = (const float*)d_in[15];
  const float* wa     = (const float*)d_in[16];
  const float* Wg     = (const float*)d_in[17];
  const float* Wv     = (const float*)d_in[18];
  const float* Wo     = (const float*)d_in[19];
  const float* Wf1    = (const float*)d_in[20];
  const float* Wfg    = (const float*)d_in[21];
  const float* Wf2    = (const float*)d_in[22];
  const float* Wh1    = (const float*)d_in[23];
  const float* Wh2    = (const float*)d_in[24];

  const int N = in_sizes[0];
  const int E = in_sizes[2];

  float* ws = (float*)d_ws;
  size_t o = 0;
  auto alloc = [&](size_t nf){ float* p = ws + o; o += (nf + 7) & ~(size_t)7; return p; };

  float* X      = alloc((size_t)N*3712);
  float* P0     = alloc((size_t)N*64);
  float* Q0     = alloc((size_t)N*64);
  float* logi   = alloc((size_t)E*8);
  float* part   = alloc((size_t)((N+1)/2) + 8);
  float* radtab = alloc((size_t)GTAB*28);
  bf16_t* qmb   = (bf16_t*)alloc((size_t)N*928);       // N*1856 bf16; h2tab aliases here
  float* h2tab  = (float*)qmb;                          // disjoint lifetimes
  bf16_t* PVb   = (bf16_t*)alloc((size_t)N*2048);      // N*4096 bf16 ([hv][k-pad32])
  bf16_t* gate16= (bf16_t*)alloc((size_t)E*64);        // E*128 bf16
  bf16_t* arena = (bf16_t*)alloc(385024);              // 770048 bf16
  int* rowptr = (int*)alloc((size_t)N+8);
  int* curs   = (int*)alloc((size_t)N);
  int* order  = (int*)alloc((size_t)E);

  bf16_t* WmsgCT  = arena;            // [4][128][128]
  bf16_t* WvT     = arena + 65536;    // [4][128][64]
  bf16_t* WoT     = arena + 98304;    // [4][128][128]
  bf16_t* Wf1T    = arena + 163840;
  bf16_t* Wf2T    = arena + 229376;
  bf16_t* WeprojT = arena + 294912;   // [3712][128]

  // CSR by target
  hipMemsetAsync(curs, 0, sizeof(int)*N, stream);
  k_count<<<(E+255)/256, 256, 0, stream>>>(EI, curs, E);
  k_scan<<<1, 1024, 0, stream>>>(curs, rowptr, N);
  k_fill<<<(E+255)/256, 256, 0, stream>>>(EI, curs, order, E);
  k_sort<<<(N+255)/256, 256, 0, stream>>>(rowptr, order, N);

  // weight transposes -> bf16 arenas
  k_tr2<<<256, 256, 0, stream>>>(Wmsg, WmsgCT);
  k_tr<<<128, 256, 0, stream>>>(Wv,   WvT,  4, 64, 128, 8192);
  k_tr<<<256, 256, 0, stream>>>(Wo,   WoT,  4, 128, 128, 16384);
  k_tr<<<256, 256, 0, stream>>>(Wf1,  Wf1T, 4, 128, 128, 16384);
  k_tr<<<256, 256, 0, stream>>>(Wf2,  Wf2T, 4, 128, 128, 16384);
  k_tr<<<1856, 256, 0, stream>>>(Weproj, WeprojT, 1, 128, 3712, 0);

  // radial tables + x init
  k_tab_embed<<<GTAB/4, 256, 0, stream>>>(We0, be0, We1, be1, Wr0, Wr1, Wrl, h2tab, radtab);
  k_init_x<<<(N+31)/32, 256, 0, stream>>>(Z, ed, emb, WeprojT, h2tab, rowptr, order, X, N);

  for (int i = 0; i < 4; i++){
    k_pqv<<<N, 256, 0, stream>>>(X, gamma1, WmsgCT, WvT, PVb, qmb, P0, Q0, i);
    k_edge_logits<<<(E+15)/16, 256, 0, stream>>>(EI, ed, P0, Q0, radtab, Wap, wa, Wg, logi, gate16, E, i);
    k_attn_ffn<<<N, 512, 0, stream>>>(EI, rowptr, order, ed, qmb, WvT, WoT, PVb, gate16,
                                      logi, radtab, gamma2, Wfg, Wf1T, Wf2T, X, i);
  }

  int PB = (N+1)/2;
  k_head<<<PB, 256, 0, stream>>>(X, Wh1, Wh2, part, N);
  k_reduce<<<1, 256, 0, stream>>>(part, (float*)d_out, PB);
}

// Round 6
// 2526.547 us; speedup vs baseline: 1.3086x; 1.1109x over previous
//
#include <hip/hip_runtime.h>

#define KM 29
#define GTAB 4096

typedef __bf16 bf16_t;
typedef __bf16 bf16x8 __attribute__((ext_vector_type(8)));
typedef __bf16 bf16x4 __attribute__((ext_vector_type(4)));
typedef float  f32x4  __attribute__((ext_vector_type(4)));

__device__ __forceinline__ float silu_f(float x){ return x / (1.0f + __expf(-x)); }

__device__ __forceinline__ float wave_reduce_sum(float v){
  #pragma unroll
  for (int s = 1; s < 64; s <<= 1) v += __shfl_xor(v, s);
  return v;
}

// l-of-k with clamp for pad rows 29..31 (their data is zero)
__device__ __forceinline__ constexpr int LOF2(int k){
  return (k<1)?0 : (k<4)?1 : (k<9)?2 : (k<14)?3 : (k<19)?4 : (k<24)?5 : 6;
}

__device__ __forceinline__ f32x4 mfma16(bf16x8 a, bf16x8 b, f32x4 c){
  return __builtin_amdgcn_mfma_f32_16x16x32_bf16(a, b, c, 0, 0, 0);
}

__device__ __forceinline__ float env_f(float d){
  float xx = d*(1.0f/12.0f);
  float x2 = xx*xx, x4 = x2*x2, x5 = x4*xx;
  float env = 1.0f - 21.0f*x5 + 35.0f*x5*xx - 15.0f*x5*x2;
  return (xx < 1.0f) ? env : 0.0f;
}

// ---------------- CSR build ----------------
__global__ void k_count(const int* __restrict__ EI, int* __restrict__ cnt, int E){
  int e = blockIdx.x*256 + threadIdx.x;
  if (e < E) atomicAdd(&cnt[EI[E+e]], 1);
}

__global__ __launch_bounds__(1024) void k_scan(int* __restrict__ cnt, int* __restrict__ rowptr, int N){
  __shared__ int ts[1024];
  int t = threadIdx.x;
  int base = t*8;
  int loc[8]; int sum = 0;
  #pragma unroll
  for (int u = 0; u < 8; u++){ int idx = base+u; int v = (idx < N) ? cnt[idx] : 0; loc[u] = sum; sum += v; }
  ts[t] = sum; __syncthreads();
  for (int off = 1; off < 1024; off <<= 1){
    int v = (t >= off) ? ts[t-off] : 0;
    __syncthreads();
    ts[t] += v;
    __syncthreads();
  }
  int excl = ts[t] - sum;
  #pragma unroll
  for (int u = 0; u < 8; u++){
    int idx = base+u;
    if (idx < N){ int r = excl + loc[u]; rowptr[idx] = r; cnt[idx] = r; }
  }
  if (t == 1023) rowptr[N] = ts[1023];
}

__global__ void k_fill(const int* __restrict__ EI, int* __restrict__ cur, int* __restrict__ order, int E){
  int e = blockIdx.x*256 + threadIdx.x;
  if (e < E){ int pos = atomicAdd(&cur[EI[E+e]], 1); order[pos] = e; }
}

__global__ void k_sort(const int* __restrict__ rowptr, int* __restrict__ order, int N){
  int n = blockIdx.x*256 + threadIdx.x;
  if (n >= N) return;
  int rp = rowptr[n], re = rowptr[n+1];
  for (int a = rp+1; a < re; a++){
    int key = order[a]; int b = a-1;
    while (b >= rp && order[b] > key){ order[b+1] = order[b]; b--; }
    order[b+1] = key;
  }
}

// ---------------- weight transposes ----------------
__global__ void k_tr(const float* __restrict__ src, bf16_t* __restrict__ dst,
                     int L, int R, int C, int Lstr){
  int idx = blockIdx.x*256 + threadIdx.x;
  int total = L*R*C;
  if (idx >= total) return;
  int l = idx / (R*C); int rem = idx - l*(R*C);
  int r = rem / C; int c = rem - r*C;
  dst[((size_t)l*C + c)*R + r] = (bf16_t)src[(size_t)l*Lstr + (size_t)r*C + c];
}

// Wmsg [4][256][64] -> combined [4][128 cols][128 k]; col<64 = P-half, col>=64 = Q-half
__global__ void k_tr2(const float* __restrict__ src, bf16_t* __restrict__ dst){
  int idx = blockIdx.x*256 + threadIdx.x;
  if (idx >= 4*128*128) return;
  int l = idx >> 14; int j = (idx >> 7) & 127; int c = idx & 127;
  float v = (j < 64) ? src[(size_t)l*16384 + c*64 + j]
                     : src[(size_t)l*16384 + 8192 + c*64 + (j-64)];
  dst[idx] = (bf16_t)v;
}

// ---------------- radial MLP table build ----------------
__global__ __launch_bounds__(256) void k_tab_embed(
    const float* __restrict__ We0, const float* __restrict__ be0,
    const float* __restrict__ We1, const float* __restrict__ be1,
    const float* __restrict__ Wr0, const float* __restrict__ Wr1, const float* __restrict__ Wrl,
    float* __restrict__ h2tab, float* __restrict__ radtab)
{
  __shared__ float sb[4][640];
  const int wid = threadIdx.x >> 6, lane = threadIdx.x & 63;
  const int e = blockIdx.x*4 + wid;
  if (e >= GTAB) return;
  const float d = e * (12.0f/(GTAB-1));
  const float DLT = 12.0f/599.0f;
  const float CO  = -0.5f/((2.0f*DLT)*(2.0f*DLT));
  int jc = (int)(d/DLT + 0.5f);
  int j0 = jc - 16; if (j0 < 0) j0 = 0; if (j0 > 600-32) j0 = 600-32;
  float diff = d - (float)(j0+lane)*DLT;
  float gval = __expf(CO*diff*diff);
  float p[10];
  #pragma unroll
  for (int u = 0; u < 10; u++) p[u] = 0.f;
  const int c2 = 2*lane;
  for (int jj = 0; jj < 32; jj++){
    float gj = __shfl(gval, jj);
    int row = j0 + jj;
    const float2 w0 = *(const float2*)(We0 + row*128 + c2);
    p[0] += gj*w0.x; p[1] += gj*w0.y;
    #pragma unroll
    for (int i = 0; i < 4; i++){
      const float2 wr = *(const float2*)(Wr0 + ((size_t)i*600 + row)*128 + c2);
      p[2+2*i] += gj*wr.x; p[3+2*i] += gj*wr.y;
    }
  }
  sb[wid][c2]   = silu_f(p[0] + be0[c2]);
  sb[wid][c2+1] = silu_f(p[1] + be0[c2+1]);
  #pragma unroll
  for (int i = 0; i < 4; i++){
    sb[wid][128 + 128*i + c2]   = silu_f(p[2+2*i]);
    sb[wid][128 + 128*i + c2+1] = silu_f(p[3+2*i]);
  }
  float a0 = 0.f, a1 = 0.f;
  for (int c = 0; c < 128; c++){
    float hv = sb[wid][c];
    const float2 w = *(const float2*)(We1 + c*128 + c2);
    a0 += hv*w.x; a1 += hv*w.y;
  }
  a0 = silu_f(a0 + be1[c2]); a1 = silu_f(a1 + be1[c2+1]);
  h2tab[(size_t)e*128 + c2]     = a0;
  h2tab[(size_t)e*128 + c2 + 1] = a1;
  #pragma unroll
  for (int i = 0; i < 4; i++){
    float r0 = 0.f, r1 = 0.f;
    const float* W1 = Wr1 + (size_t)i*128*128;
    for (int c = 0; c < 128; c++){
      float rv = sb[wid][128 + 128*i + c];
      const float2 w = *(const float2*)(W1 + c*128 + c2);
      r0 += rv*w.x; r1 += rv*w.y;
    }
    r0 = silu_f(r0); r1 = silu_f(r1);
    const float* Wl = Wrl + (size_t)i*128*7;
    float pl[7];
    #pragma unroll
    for (int l = 0; l < 7; l++) pl[l] = r0*Wl[c2*7+l] + r1*Wl[(c2+1)*7+l];
    #pragma unroll
    for (int l = 0; l < 7; l++) pl[l] = wave_reduce_sum(pl[l]);
    if (lane == 0){
      #pragma unroll
      for (int l = 0; l < 7; l++) radtab[(size_t)e*28 + i*7 + l] = pl[l];
    }
  }
}

// ---------------- per-edge h2 interp (edge-parallel) ----------------
__global__ void k_h2e(const float* __restrict__ ed, const float* __restrict__ h2tab,
                      bf16_t* __restrict__ h2e, int E){
  int idx = blockIdx.x*256 + threadIdx.x;
  if (idx >= E*128) return;
  int e = idx >> 7, ch = idx & 127;
  float d = ed[e];
  float u = d * ((GTAB-1)/12.0f);
  int j = (int)u; if (j > GTAB-2) j = GTAB-2;
  float f = u - (float)j;
  float a = h2tab[(size_t)j*128 + ch], b = h2tab[(size_t)(j+1)*128 + ch];
  h2e[idx] = (bf16_t)(a + f*(b-a));
}

// ---------------- x init ----------------
__global__ __launch_bounds__(256) void k_init_x(
    const int* __restrict__ Z, const float* __restrict__ emb,
    const bf16_t* __restrict__ WeprojT, const bf16_t* __restrict__ h2e,
    const int* __restrict__ rowptr, const int* __restrict__ order,
    float* __restrict__ X, int N)
{
  __shared__ bf16_t h2s[32*136];
  __shared__ int Zs[32];
  int n0 = blockIdx.x*32, t = threadIdx.x;
  int half = t >> 7, ch = t & 127;
  for (int pair = 0; pair < 16; pair++){
    int nn = pair*2 + half;
    int n = n0 + nn;
    float acc = 0.f;
    if (n < N){
      int rp = rowptr[n], deg = rowptr[n+1]-rp;
      for (int idx = 0; idx < deg; idx++){
        int e = order[rp+idx];
        acc += (float)h2e[(size_t)e*128 + ch];
      }
    }
    h2s[nn*136 + ch] = (bf16_t)acc;
  }
  if (t < 32) Zs[t] = (n0 + t < N) ? Z[n0+t] : 0;
  __syncthreads();
  int wid = t >> 6, lane = t & 63;
  int mtile = wid & 1;
  int row = mtile*16 + (lane & 15);
  int koff = (lane >> 4)*8;
  bf16x8 afr[4];
  #pragma unroll
  for (int kk = 0; kk < 4; kk++) afr[kk] = *(const bf16x8*)(h2s + row*136 + kk*32 + koff);
  for (int nt = (wid>>1); nt < 232; nt += 2){
    f32x4 acc = {0.f,0.f,0.f,0.f};
    int col = nt*16 + (lane & 15);
    #pragma unroll
    for (int kk = 0; kk < 4; kk++){
      bf16x8 b = *(const bf16x8*)(WeprojT + (size_t)col*128 + kk*32 + koff);
      acc = mfma16(afr[kk], b, acc);
    }
    #pragma unroll
    for (int r = 0; r < 4; r++){
      int r32 = mtile*16 + (lane>>4)*4 + r;
      int n = n0 + r32;
      if (n < N){
        float v = acc[r] * (1.0f/23.395238876342773f);
        if (col < 128) v += emb[(size_t)Zs[r32]*128 + col];
        X[(size_t)n*3712 + col] = v;
      }
    }
  }
}

// ---------------- per-layer: rms + combined [P|Q] GEMM + PV + qm + P0/Q0 (512 thr) ----------------
__global__ __launch_bounds__(512) void k_pqv(
    const float* __restrict__ X, const float* __restrict__ gamma1,
    const bf16_t* __restrict__ WmsgCT, const bf16_t* __restrict__ WvT,
    bf16_t* __restrict__ PVb, bf16_t* __restrict__ qmb,
    float* __restrict__ P0, float* __restrict__ Q0, int layer)
{
  __shared__ bf16_t ys16[32*136];
  __shared__ bf16_t pq16[32*136];
  int n = blockIdx.x, t = threadIdx.x;
  int wid = t >> 6, lane = t & 63;
  const float* g1 = gamma1 + layer*128;
  const float* xp = X + (size_t)n*3712;
  for (int k = wid; k < KM; k += 8){
    float x0 = xp[k*128 + lane], x1 = xp[k*128 + 64 + lane];
    float ss = wave_reduce_sum(x0*x0 + x1*x1);
    float sc = rsqrtf(ss*(1.0f/128.0f) + 1e-6f);
    ys16[k*136 + lane]      = (bf16_t)(x0*sc*g1[lane]);
    ys16[k*136 + 64 + lane] = (bf16_t)(x1*sc*g1[64+lane]);
  }
  for (int idx = t; idx < 3*136; idx += 512) ys16[29*136 + idx] = (bf16_t)0.f;
  __syncthreads();
  int mtile = wid >> 2;
  int row = mtile*16 + (lane & 15);
  int koff = (lane >> 4)*8;
  // GEMM-C: [32 x 128] = ys @ WmsgCT (8 waves, 2 cols each)
  {
    const bf16_t* Bc = WmsgCT + (size_t)layer*16384;
    f32x4 acc[2] = {{0,0,0,0},{0,0,0,0}};
    #pragma unroll
    for (int kk = 0; kk < 128; kk += 32){
      bf16x8 a = *(const bf16x8*)(ys16 + row*136 + kk + koff);
      #pragma unroll
      for (int u = 0; u < 2; u++){
        int col = ((wid&3)*2+u)*16 + (lane & 15);
        bf16x8 b = *(const bf16x8*)(Bc + (size_t)col*128 + kk + koff);
        acc[u] = mfma16(a, b, acc[u]);
      }
    }
    #pragma unroll
    for (int u = 0; u < 2; u++){
      int col = ((wid&3)*2+u)*16 + (lane & 15);
      #pragma unroll
      for (int r = 0; r < 4; r++){
        int r32 = mtile*16 + (lane>>4)*4 + r;
        pq16[r32*136 + col] = (bf16_t)acc[u][r];
      }
      if (mtile == 0 && (lane>>4) == 0){
        float v = acc[u][0];
        if (col < 64) P0[(size_t)n*64 + col] = v;
        else          Q0[(size_t)n*64 + col - 64] = v;
      }
    }
  }
  __syncthreads();
  // PV GEMM: [32 x 128] = pq16[:, 0:64] @ WvT -> PVb [hv][k32]
  {
    const bf16_t* Bt = WvT + (size_t)layer*8192;
    f32x4 acc[2] = {{0,0,0,0},{0,0,0,0}};
    #pragma unroll
    for (int kk = 0; kk < 64; kk += 32){
      bf16x8 a = *(const bf16x8*)(pq16 + row*136 + kk + koff);
      #pragma unroll
      for (int u = 0; u < 2; u++){
        int col = ((wid&3)*2+u)*16 + (lane & 15);
        bf16x8 b = *(const bf16x8*)(Bt + (size_t)col*64 + kk + koff);
        acc[u] = mfma16(a, b, acc[u]);
      }
    }
    bf16_t* pvp = PVb + (size_t)n*4096;
    int r0i = mtile*16 + (lane>>4)*4;
    #pragma unroll
    for (int u = 0; u < 2; u++){
      int col = ((wid&3)*2+u)*16 + (lane & 15);
      bf16x4 pack;
      #pragma unroll
      for (int r = 0; r < 4; r++){
        int r32 = r0i + r;
        pack[r] = (r32 < KM) ? (bf16_t)acc[u][r] : (bf16_t)0.f;
      }
      *(bf16x4*)(pvp + col*32 + r0i) = pack;
    }
  }
  for (int idx = t; idx < KM*64; idx += 512){
    int k = idx >> 6, j = idx & 63;
    qmb[(size_t)n*1856 + idx] = pq16[k*136 + 64 + j];
  }
}

// ---------------- per-layer: edge logits + gate (MFMA) ----------------
__global__ __launch_bounds__(256) void k_edge_logits(
    const int* __restrict__ EI, const float* __restrict__ ed,
    const float* __restrict__ P0, const float* __restrict__ Q0,
    const float* __restrict__ radtab, const bf16_t* __restrict__ WapT, const float* __restrict__ wa,
    const bf16_t* __restrict__ WgT, float* __restrict__ logi, bf16_t* __restrict__ gate16,
    int E, int layer)
{
  __shared__ bf16_t m0s[16*72];
  __shared__ int   srcs[16], tgts[16];
  __shared__ float r0s[16];
  int t = threadIdx.x;
  int eb = blockIdx.x*16;
  if (t < 16){
    int e = eb + t;
    if (e < E){
      srcs[t] = EI[e]; tgts[t] = EI[E+e];
      float d = ed[e];
      float u = d * ((GTAB-1)/12.0f);
      int j = (int)u; if (j > GTAB-2) j = GTAB-2;
      float f = u - (float)j;
      float a = radtab[(size_t)j*28 + layer*7], b = radtab[(size_t)(j+1)*28 + layer*7];
      r0s[t] = a + f*(b-a);
    } else { srcs[t] = 0; tgts[t] = 0; r0s[t] = 0.f; }
  }
  __syncthreads();
  #pragma unroll
  for (int u = 0; u < 4; u++){
    int idx = t + u*256;
    int i = idx >> 6, j = idx & 63;
    m0s[i*72 + j] = (bf16_t)((P0[(size_t)srcs[i]*64 + j] + Q0[(size_t)tgts[i]*64 + j]) * r0s[i]);
  }
  __syncthreads();
  int wid = t >> 6, lane = t & 63;
  int l15 = lane & 15, lg = lane >> 4;   // row group
  int koff = lg*8;
  bf16x8 a0 = *(const bf16x8*)(m0s + l15*72 + koff);
  bf16x8 a1 = *(const bf16x8*)(m0s + l15*72 + 32 + koff);
  // ap: 4 col-tiles per wave (cols 64*wid .. 64*wid+63) -> heads 2*wid, 2*wid+1
  const bf16_t* Ba = WapT + (size_t)layer*16384;
  const bf16_t* Bg = WgT  + (size_t)layer*8192;
  const float* wav = wa + layer*256;
  f32x4 accA[4], accG[2];
  #pragma unroll
  for (int u = 0; u < 4; u++){
    int col = 64*wid + u*16 + l15;
    f32x4 acc = {0,0,0,0};
    acc = mfma16(a0, *(const bf16x8*)(Ba + (size_t)col*64 + koff), acc);
    acc = mfma16(a1, *(const bf16x8*)(Ba + (size_t)col*64 + 32 + koff), acc);
    accA[u] = acc;
  }
  #pragma unroll
  for (int u = 0; u < 2; u++){
    int col = 32*wid + u*16 + l15;
    f32x4 acc = {0,0,0,0};
    acc = mfma16(a0, *(const bf16x8*)(Bg + (size_t)col*64 + koff), acc);
    acc = mfma16(a1, *(const bf16x8*)(Bg + (size_t)col*64 + 32 + koff), acc);
    accG[u] = acc;
  }
  // gate writes
  #pragma unroll
  for (int u = 0; u < 2; u++){
    int col = 32*wid + u*16 + l15;
    #pragma unroll
    for (int r = 0; r < 4; r++){
      int e = eb + lg*4 + r;
      if (e < E) gate16[(size_t)e*128 + col] = (bf16_t)silu_f(accG[u][r]);
    }
  }
  // logits: per head (2 tiles each), silu*wa then 16-lane reduce
  #pragma unroll
  for (int hpair = 0; hpair < 2; hpair++){
    int c0 = 64*wid + hpair*32 + l15;
    float w0 = wav[c0], w1 = wav[c0+16];
    float s[4];
    #pragma unroll
    for (int r = 0; r < 4; r++)
      s[r] = silu_f(accA[2*hpair][r])*w0 + silu_f(accA[2*hpair+1][r])*w1;
    #pragma unroll
    for (int r = 0; r < 4; r++){
      s[r] += __shfl_xor(s[r], 1);
      s[r] += __shfl_xor(s[r], 2);
      s[r] += __shfl_xor(s[r], 4);
      s[r] += __shfl_xor(s[r], 8);
    }
    if (l15 == 0){
      #pragma unroll
      for (int r = 0; r < 4; r++){
        int e = eb + lg*4 + r;
        if (e < E) logi[(size_t)e*8 + 2*wid + hpair] = s[r];
      }
    }
  }
}

// ---------------- fused per-layer: attn (softmax+gather+QV+Wo) + FFN; x in LDS ----------------
__global__ __launch_bounds__(512, 4) void k_attn_ffn(
    const int* __restrict__ EI, const int* __restrict__ rowptr, const int* __restrict__ order,
    const float* __restrict__ ed, const bf16_t* __restrict__ qmb,
    const bf16_t* __restrict__ WvT, const bf16_t* __restrict__ WoT,
    const bf16_t* __restrict__ PVb, const bf16_t* __restrict__ gate16,
    const float* __restrict__ logi, const float* __restrict__ radtab,
    const float* __restrict__ gamma2, const float* __restrict__ Wfg,
    const bf16_t* __restrict__ Wf1T, const bf16_t* __restrict__ Wf2T,
    float* __restrict__ X, int layer)
{
  __shared__ float  xs[3712];        // x residual, fp32, persistent
  __shared__ bf16_t ysag[32*136];    // attn: merge buf A + Wo input; ffn: ys16
  __shared__ bf16_t hsqv[32*136];    // attn: qvs16, then merge buf B; ffn: hs16
  __shared__ char   uA[4608];        // qm16 -> {at8, rl7, es, srcs} -> ffn gate partials
  __shared__ float  mh[8], iden[8];

  bf16_t* qm16 = (bf16_t*)uA;
  float*  at8  = (float*)uA;
  float*  rl7  = (float*)(uA + 2048);
  int*    es   = (int*)(uA + 4096);
  int*    srcs = (int*)(uA + 4352);
  float*  pf   = (float*)uA;         // ffn gate partials (640 f32)

  int n = blockIdx.x, t = threadIdx.x;
  int wid = t >> 6, lane = t & 63;
  int rp = rowptr[n], deg = rowptr[n+1] - rp;

  // load x into LDS
  for (int idx = t; idx < 3712; idx += 512) xs[idx] = X[(size_t)n*3712 + idx];

  if (deg > 0){
    // qm -> LDS (+pads)
    for (int idx = t; idx < KM*64; idx += 512){
      int k = idx >> 6, j = idx & 63;
      qm16[k*72 + j] = qmb[(size_t)n*1856 + idx];
    }
    for (int idx = t; idx < 3*72; idx += 512) qm16[29*72 + idx] = (bf16_t)0.f;
    // softmax stats (8 lanes per head), overlapped w/ qm write of other waves
    if (t < 64){
      int hh = t & 7, slot = t >> 3;
      float m = -3.0e38f;
      for (int idx = slot; idx < deg; idx += 8){
        int e = order[rp+idx];
        m = fmaxf(m, logi[(size_t)e*8 + hh]);
      }
      m = fmaxf(m, __shfl_xor(m, 8));
      m = fmaxf(m, __shfl_xor(m, 16));
      m = fmaxf(m, __shfl_xor(m, 32));
      float den = 0.f;
      for (int idx = slot; idx < deg; idx += 8){
        int e = order[rp+idx];
        den += env_f(ed[e]) * __expf(logi[(size_t)e*8 + hh] - m);
      }
      den += __shfl_xor(den, 8);
      den += __shfl_xor(den, 16);
      den += __shfl_xor(den, 32);
      if (t < 8){ mh[t] = m; iden[t] = 1.0f/(den + 1e-16f); }
    }
    __syncthreads();
    // QV GEMM: hsqv = qm16 @ WvT (K=64, 8 waves)
    {
      const bf16_t* Bt = WvT + (size_t)layer*8192;
      int mtile = wid >> 2, colt = (wid & 3)*2;
      int row = mtile*16 + (lane & 15);
      int koff = (lane >> 4)*8;
      f32x4 a2[2] = {{0,0,0,0},{0,0,0,0}};
      #pragma unroll
      for (int kk = 0; kk < 64; kk += 32){
        bf16x8 a = *(const bf16x8*)(qm16 + row*72 + kk + koff);
        #pragma unroll
        for (int u = 0; u < 2; u++){
          int col = (colt+u)*16 + (lane & 15);
          bf16x8 b = *(const bf16x8*)(Bt + (size_t)col*64 + kk + koff);
          a2[u] = mfma16(a, b, a2[u]);
        }
      }
      #pragma unroll
      for (int u = 0; u < 2; u++){
        int col = (colt+u)*16 + (lane & 15);
        #pragma unroll
        for (int r = 0; r < 4; r++){
          int r32 = mtile*16 + (lane>>4)*4 + r;
          hsqv[r32*136 + col] = (bf16_t)a2[u][r];
        }
      }
    }
    __syncthreads();   // qvs ready; qm dead -> uA reused by at8/rl7/es/srcs
    // gather: eg in {0..3} x hv in {0..127}; each thread owns all 32 k
    int eg = t >> 7, hv = t & 127, h = hv >> 4;
    float acc[32];
    #pragma unroll
    for (int j = 0; j < 32; j++) acc[j] = 0.f;
    float S[7];
    #pragma unroll
    for (int l = 0; l < 7; l++) S[l] = 0.f;
    for (int base = 0; base < deg; base += 64){
      int ne = min(64, deg - base);
      if (t < ne){ int e = order[rp + base + t]; es[t] = e; srcs[t] = EI[e]; }
      __syncthreads();
      if (t < ne*8){
        int i = t >> 3, q = t & 7;
        int e = es[i];
        float d = ed[e];
        at8[t] = env_f(d) * __expf(logi[(size_t)e*8 + q] - mh[q]) * iden[q];
        if (q < 7){
          float u = d * ((GTAB-1)/12.0f);
          int j = (int)u; if (j > GTAB-2) j = GTAB-2;
          float f = u - (float)j;
          float a = radtab[(size_t)j*28 + layer*7 + q], b = radtab[(size_t)(j+1)*28 + layer*7 + q];
          rl7[t] = a + f*(b-a);
        }
      }
      __syncthreads();
      // 2-deep register-prefetched edge loop
      bf16x8 va0, va1, va2, va3; float gcur = 0.f;
      int i = eg;
      if (i < ne){
        const bf16x8* p = (const bf16x8*)(PVb + (size_t)srcs[i]*4096 + hv*32);
        va0 = p[0]; va1 = p[1]; va2 = p[2]; va3 = p[3];
        gcur = (float)gate16[(size_t)es[i]*128 + hv];
      }
      while (i < ne){
        int in = i + 4;
        bf16x8 vb0, vb1, vb2, vb3; float gnext = 0.f;
        if (in < ne){
          const bf16x8* p = (const bf16x8*)(PVb + (size_t)srcs[in]*4096 + hv*32);
          vb0 = p[0]; vb1 = p[1]; vb2 = p[2]; vb3 = p[3];
          gnext = (float)gate16[(size_t)es[in]*128 + hv];
        }
        float w = gcur * at8[i*8 + h];
        float rw[7];
        #pragma unroll
        for (int l = 0; l < 7; l++){ rw[l] = rl7[i*8 + l]*w; S[l] += rw[l]; }
        #pragma unroll
        for (int j = 0; j < 8; j++) acc[j]    += (float)va0[j]*rw[LOF2(j)];
        #pragma unroll
        for (int j = 0; j < 8; j++) acc[8+j]  += (float)va1[j]*rw[LOF2(8+j)];
        #pragma unroll
        for (int j = 0; j < 8; j++) acc[16+j] += (float)va2[j]*rw[LOF2(16+j)];
        #pragma unroll
        for (int j = 0; j < 8; j++) acc[24+j] += (float)va3[j]*rw[LOF2(24+j)];
        va0 = vb0; va1 = vb1; va2 = vb2; va3 = vb3;
        gcur = gnext;
        i = in;
      }
      __syncthreads();
    }
    // QV * S (per-group partial S sums correctly across merge); reads hsqv (qvs)
    #pragma unroll
    for (int j = 0; j < 32; j++)
      acc[j] += (float)hsqv[j*136 + hv] * S[LOF2(j)];
    __syncthreads();   // all qvs reads done before hsqv overwritten
    // bf16 merge: g0->ysag, g1->hsqv; g2+=ysag, g3+=hsqv; combine
    if (eg == 0){
      #pragma unroll
      for (int j = 0; j < 32; j++) ysag[j*136 + hv] = (bf16_t)acc[j];
    } else if (eg == 1){
      #pragma unroll
      for (int j = 0; j < 32; j++) hsqv[j*136 + hv] = (bf16_t)acc[j];
    }
    __syncthreads();
    if (eg == 2){
      #pragma unroll
      for (int j = 0; j < 32; j++) ysag[j*136 + hv] = (bf16_t)((float)ysag[j*136 + hv] + acc[j]);
    } else if (eg == 3){
      #pragma unroll
      for (int j = 0; j < 32; j++) hsqv[j*136 + hv] = (bf16_t)((float)hsqv[j*136 + hv] + acc[j]);
    }
    __syncthreads();
    for (int idx = t; idx < 32*128; idx += 512){
      int k = idx >> 7, c = idx & 127;
      ysag[k*136 + c] = (bf16_t)((float)ysag[k*136 + c] + (float)hsqv[k*136 + c]);
    }
    __syncthreads();
    // Wo GEMM: xs += ag @ WoT (K=128, 8 waves)
    {
      const bf16_t* Bt = WoT + (size_t)layer*16384;
      int mtile = wid >> 2, colt = (wid & 3)*2;
      int row = mtile*16 + (lane & 15);
      int koff = (lane >> 4)*8;
      f32x4 a2[2] = {{0,0,0,0},{0,0,0,0}};
      #pragma unroll
      for (int kk = 0; kk < 128; kk += 32){
        bf16x8 a = *(const bf16x8*)(ysag + row*136 + kk + koff);
        #pragma unroll
        for (int u = 0; u < 2; u++){
          int col = (colt+u)*16 + (lane & 15);
          bf16x8 b = *(const bf16x8*)(Bt + (size_t)col*128 + kk + koff);
          a2[u] = mfma16(a, b, a2[u]);
        }
      }
      #pragma unroll
      for (int u = 0; u < 2; u++){
        int col = (colt+u)*16 + (lane & 15);
        #pragma unroll
        for (int r = 0; r < 4; r++){
          int r32 = mtile*16 + (lane>>4)*4 + r;
          if (r32 < KM) xs[r32*128 + col] += a2[u][r];
        }
      }
    }
  }
  __syncthreads();
  // ---------- FFN phase ----------
  const float* g2 = gamma2 + layer*128;
  for (int k = wid; k < KM; k += 8){
    float x0 = xs[k*128 + lane], x1 = xs[k*128 + 64 + lane];
    float ss = wave_reduce_sum(x0*x0 + x1*x1);
    float sc = rsqrtf(ss*(1.0f/128.0f) + 1e-6f);
    ysag[k*136 + lane]      = (bf16_t)(x0*sc*g2[lane]);
    ysag[k*136 + 64 + lane] = (bf16_t)(x1*sc*g2[64+lane]);
  }
  for (int idx = t; idx < 3*136; idx += 512) ysag[29*136 + idx] = (bf16_t)0.f;
  __syncthreads();
  // gate: 4 partials x 128 into pf (uA)
  {
    int part = t >> 7, f = t & 127;
    const float* Wfgp = Wfg + (size_t)layer*16384;
    float p = 0.f;
    for (int c = part*32; c < part*32 + 32; c++) p += (float)ysag[c] * Wfgp[c*128 + f];
    pf[part*128 + f] = p;
  }
  __syncthreads();
  if (t < 128) pf[512 + t] = silu_f(pf[t] + pf[128+t] + pf[256+t] + pf[384+t]);
  __syncthreads();
  // Wf1: hs = (ys @ Wf1T) * gf
  {
    const bf16_t* Bt = Wf1T + (size_t)layer*16384;
    int mtile = wid >> 2, colt = (wid & 3)*2;
    int row = mtile*16 + (lane & 15);
    int koff = (lane >> 4)*8;
    f32x4 a2[2] = {{0,0,0,0},{0,0,0,0}};
    #pragma unroll
    for (int kk = 0; kk < 128; kk += 32){
      bf16x8 a = *(const bf16x8*)(ysag + row*136 + kk + koff);
      #pragma unroll
      for (int u = 0; u < 2; u++){
        int col = (colt+u)*16 + (lane & 15);
        bf16x8 b = *(const bf16x8*)(Bt + (size_t)col*128 + kk + koff);
        a2[u] = mfma16(a, b, a2[u]);
      }
    }
    #pragma unroll
    for (int u = 0; u < 2; u++){
      int col = (colt+u)*16 + (lane & 15);
      float gfc = pf[512 + col];
      #pragma unroll
      for (int r = 0; r < 4; r++){
        int r32 = mtile*16 + (lane>>4)*4 + r;
        hsqv[r32*136 + col] = (bf16_t)(a2[u][r]*gfc);
      }
    }
  }
  __syncthreads();
  // Wf2: xs += hs @ Wf2T
  {
    const bf16_t* Bt = Wf2T + (size_t)layer*16384;
    int mtile = wid >> 2, colt = (wid & 3)*2;
    int row = mtile*16 + (lane & 15);
    int koff = (lane >> 4)*8;
    f32x4 a2[2] = {{0,0,0,0},{0,0,0,0}};
    #pragma unroll
    for (int kk = 0; kk < 128; kk += 32){
      bf16x8 a = *(const bf16x8*)(hsqv + row*136 + kk + koff);
      #pragma unroll
      for (int u = 0; u < 2; u++){
        int col = (colt+u)*16 + (lane & 15);
        bf16x8 b = *(const bf16x8*)(Bt + (size_t)col*128 + kk + koff);
        a2[u] = mfma16(a, b, a2[u]);
      }
    }
    #pragma unroll
    for (int u = 0; u < 2; u++){
      int col = (colt+u)*16 + (lane & 15);
      #pragma unroll
      for (int r = 0; r < 4; r++){
        int r32 = mtile*16 + (lane>>4)*4 + r;
        if (r32 < KM) xs[r32*128 + col] += a2[u][r];
      }
    }
  }
  __syncthreads();
  // store x back
  for (int idx = t; idx < 3712; idx += 512) X[(size_t)n*3712 + idx] = xs[idx];
}

// ---------------- output head ----------------
__global__ __launch_bounds__(256) void k_head(
    const float* __restrict__ X, const float* __restrict__ Wh1, const float* __restrict__ Wh2,
    float* __restrict__ partial, int N)
{
  __shared__ float wsum[4];
  int t = threadIdx.x;
  int half = t >> 7;
  int n = blockIdx.x*2 + half;
  int f = t & 127;
  float sv = 0.f;
  if (n < N){
    const float* xp = X + (size_t)n*3712;
    float acc = 0.f;
    for (int c = 0; c < 128; c++) acc += xp[c]*Wh1[c*128 + f];
    sv = silu_f(acc)*Wh2[f];
  }
  sv = wave_reduce_sum(sv);
  if ((t & 63) == 0) wsum[t >> 6] = sv;
  __syncthreads();
  if (t == 0) partial[blockIdx.x] = wsum[0] + wsum[1] + wsum[2] + wsum[3];
}

__global__ __launch_bounds__(256) void k_reduce(const float* __restrict__ partial, float* __restrict__ out, int P){
  __shared__ float sh[256];
  int t = threadIdx.x;
  float s = 0.f;
  for (int i = t; i < P; i += 256) s += partial[i];
  sh[t] = s; __syncthreads();
  for (int off = 128; off > 0; off >>= 1){
    if (t < off) sh[t] += sh[t+off];
    __syncthreads();
  }
  if (t == 0) out[0] = sh[0] / 77.81317f;
}

extern "C" void kernel_launch(void* const* d_in, const int* in_sizes, int n_in,
                              void* d_out, int out_size, void* d_ws, size_t ws_size,
                              hipStream_t stream)
{
  const int*   Z      = (const int*)d_in[0];
  const int*   EI     = (const int*)d_in[1];
  const float* ed     = (const float*)d_in[2];
  const float* emb    = (const float*)d_in[3];
  const float* We0    = (const float*)d_in[4];
  const float* be0    = (const float*)d_in[5];
  const float* We1    = (const float*)d_in[6];
  const float* be1    = (const float*)d_in[7];
  const float* Weproj = (const float*)d_in[8];
  const float* gamma1 = (const float*)d_in[9];
  const float* gamma2 = (const float*)d_in[10];
  const float* Wr0    = (const float*)d_in[11];
  const float* Wr1    = (const float*)d_in[12];
  const float* Wrl    = (const float*)d_in[13];
  const float* Wmsg   = (const float*)d_in[14];
  const float* Wap    = (const float*)d_in[15];
  const float* wa     = (const float*)d_in[16];
  const float* Wg     = (const float*)d_in[17];
  const float* Wv     = (const float*)d_in[18];
  const float* Wo     = (const float*)d_in[19];
  const float* Wf1    = (const float*)d_in[20];
  const float* Wfg    = (const float*)d_in[21];
  const float* Wf2    = (const float*)d_in[22];
  const float* Wh1    = (const float*)d_in[23];
  const float* Wh2    = (const float*)d_in[24];

  const int N = in_sizes[0];
  const int E = in_sizes[2];

  float* ws = (float*)d_ws;
  size_t o = 0;
  auto alloc = [&](size_t nf){ float* p = ws + o; o += (nf + 7) & ~(size_t)7; return p; };

  float* X      = alloc((size_t)N*3712);
  float* P0     = alloc((size_t)N*64);
  float* Q0     = alloc((size_t)N*64);
  float* logi   = alloc((size_t)E*8);
  float* part   = alloc((size_t)((N+1)/2) + 8);
  float* radtab = alloc((size_t)GTAB*28);
  bf16_t* qmb   = (bf16_t*)alloc((size_t)N*928);       // N*1856 bf16; h2tab aliases here
  float* h2tab  = (float*)qmb;                          // disjoint lifetimes
  bf16_t* PVb   = (bf16_t*)alloc((size_t)N*2048);      // N*4096 bf16 ([hv][k-pad32])
  bf16_t* gate16= (bf16_t*)alloc((size_t)E*64);        // E*128 bf16; h2e aliases pre-layers
  bf16_t* arena = (bf16_t*)alloc(434176);              // 868352 bf16
  int* rowptr = (int*)alloc((size_t)N+8);
  int* curs   = (int*)alloc((size_t)N);
  int* order  = (int*)alloc((size_t)E);

  bf16_t* WmsgCT  = arena;            // [4][128][128]
  bf16_t* WvT     = arena + 65536;    // [4][128][64]
  bf16_t* WoT     = arena + 98304;    // [4][128][128]
  bf16_t* Wf1T    = arena + 163840;   // [4][128][128]
  bf16_t* Wf2T    = arena + 229376;   // [4][128][128]
  bf16_t* WapT    = arena + 294912;   // [4][256][64]
  bf16_t* WgT     = arena + 360448;   // [4][128][64]
  bf16_t* WeprojT = arena + 393216;   // [3712][128]

  bf16_t* h2e = gate16;   // alias: dead before layer-0 logits writes gate16

  // CSR by target
  hipMemsetAsync(curs, 0, sizeof(int)*N, stream);
  k_count<<<(E+255)/256, 256, 0, stream>>>(EI, curs, E);
  k_scan<<<1, 1024, 0, stream>>>(curs, rowptr, N);
  k_fill<<<(E+255)/256, 256, 0, stream>>>(EI, curs, order, E);
  k_sort<<<(N+255)/256, 256, 0, stream>>>(rowptr, order, N);

  // weight transposes -> bf16 arenas
  k_tr2<<<256, 256, 0, stream>>>(Wmsg, WmsgCT);
  k_tr<<<128, 256, 0, stream>>>(Wv,   WvT,  4, 64, 128, 8192);
  k_tr<<<256, 256, 0, stream>>>(Wo,   WoT,  4, 128, 128, 16384);
  k_tr<<<256, 256, 0, stream>>>(Wf1,  Wf1T, 4, 128, 128, 16384);
  k_tr<<<256, 256, 0, stream>>>(Wf2,  Wf2T, 4, 128, 128, 16384);
  k_tr<<<256, 256, 0, stream>>>(Wap,  WapT, 4, 64, 256, 16384);
  k_tr<<<128, 256, 0, stream>>>(Wg,   WgT,  4, 64, 128, 8192);
  k_tr<<<1856, 256, 0, stream>>>(Weproj, WeprojT, 1, 128, 3712, 0);

  // radial tables + per-edge h2 + x init
  k_tab_embed<<<GTAB/4, 256, 0, stream>>>(We0, be0, We1, be1, Wr0, Wr1, Wrl, h2tab, radtab);
  k_h2e<<<(E*128+255)/256, 256, 0, stream>>>(ed, h2tab, h2e, E);
  k_init_x<<<(N+31)/32, 256, 0, stream>>>(Z, emb, WeprojT, h2e, rowptr, order, X, N);

  for (int i = 0; i < 4; i++){
    k_pqv<<<N, 512, 0, stream>>>(X, gamma1, WmsgCT, WvT, PVb, qmb, P0, Q0, i);
    k_edge_logits<<<(E+15)/16, 256, 0, stream>>>(EI, ed, P0, Q0, radtab, WapT, wa, WgT, logi, gate16, E, i);
    k_attn_ffn<<<N, 512, 0, stream>>>(EI, rowptr, order, ed, qmb, WvT, WoT, PVb, gate16,
                                      logi, radtab, gamma2, Wfg, Wf1T, Wf2T, X, i);
  }

  int PB = (N+1)/2;
  k_head<<<PB, 256, 0, stream>>>(X, Wh1, Wh2, part, N);
  k_reduce<<<1, 256, 0, stream>>>(part, (float*)d_out, PB);
}

// Round 7
// 2409.111 us; speedup vs baseline: 1.3724x; 1.0487x over previous
//
#include <hip/hip_runtime.h>

#define KM 29
#define GTAB 4096

typedef __bf16 bf16_t;
typedef __bf16 bf16x8 __attribute__((ext_vector_type(8)));
typedef __bf16 bf16x4 __attribute__((ext_vector_type(4)));
typedef float  f32x4  __attribute__((ext_vector_type(4)));
typedef float  f32x2  __attribute__((ext_vector_type(2)));

__device__ __forceinline__ float silu_f(float x){ return x / (1.0f + __expf(-x)); }

__device__ __forceinline__ float wave_reduce_sum(float v){
  #pragma unroll
  for (int s = 1; s < 64; s <<= 1) v += __shfl_xor(v, s);
  return v;
}

// l-of-k with clamp for pad rows 29..31 (their data is zero)
__device__ __forceinline__ constexpr int LOF2(int k){
  return (k<1)?0 : (k<4)?1 : (k<9)?2 : (k<14)?3 : (k<19)?4 : (k<24)?5 : 6;
}

__device__ __forceinline__ f32x4 mfma16(bf16x8 a, bf16x8 b, f32x4 c){
  return __builtin_amdgcn_mfma_f32_16x16x32_bf16(a, b, c, 0, 0, 0);
}

__device__ __forceinline__ float env_f(float d){
  float xx = d*(1.0f/12.0f);
  float x2 = xx*xx, x4 = x2*x2, x5 = x4*xx;
  float env = 1.0f - 21.0f*x5 + 35.0f*x5*xx - 15.0f*x5*x2;
  return (xx < 1.0f) ? env : 0.0f;
}

// ---------------- CSR build ----------------
__global__ void k_count(const int* __restrict__ EI, int* __restrict__ cnt, int E){
  int e = blockIdx.x*256 + threadIdx.x;
  if (e < E) atomicAdd(&cnt[EI[E+e]], 1);
}

__global__ __launch_bounds__(1024) void k_scan(int* __restrict__ cnt, int* __restrict__ rowptr, int N){
  __shared__ int ts[1024];
  int t = threadIdx.x;
  int base = t*8;
  int loc[8]; int sum = 0;
  #pragma unroll
  for (int u = 0; u < 8; u++){ int idx = base+u; int v = (idx < N) ? cnt[idx] : 0; loc[u] = sum; sum += v; }
  ts[t] = sum; __syncthreads();
  for (int off = 1; off < 1024; off <<= 1){
    int v = (t >= off) ? ts[t-off] : 0;
    __syncthreads();
    ts[t] += v;
    __syncthreads();
  }
  int excl = ts[t] - sum;
  #pragma unroll
  for (int u = 0; u < 8; u++){
    int idx = base+u;
    if (idx < N){ int r = excl + loc[u]; rowptr[idx] = r; cnt[idx] = r; }
  }
  if (t == 1023) rowptr[N] = ts[1023];
}

__global__ void k_fill(const int* __restrict__ EI, int* __restrict__ cur, int* __restrict__ order, int E){
  int e = blockIdx.x*256 + threadIdx.x;
  if (e < E){ int pos = atomicAdd(&cur[EI[E+e]], 1); order[pos] = e; }
}

__global__ void k_sort(const int* __restrict__ rowptr, int* __restrict__ order, int N){
  int n = blockIdx.x*256 + threadIdx.x;
  if (n >= N) return;
  int rp = rowptr[n], re = rowptr[n+1];
  for (int a = rp+1; a < re; a++){
    int key = order[a]; int b = a-1;
    while (b >= rp && order[b] > key){ order[b+1] = order[b]; b--; }
    order[b+1] = key;
  }
}

// ---------------- weight transposes ----------------
__global__ void k_tr(const float* __restrict__ src, bf16_t* __restrict__ dst,
                     int L, int R, int C, int Lstr){
  int idx = blockIdx.x*256 + threadIdx.x;
  int total = L*R*C;
  if (idx >= total) return;
  int l = idx / (R*C); int rem = idx - l*(R*C);
  int r = rem / C; int c = rem - r*C;
  dst[((size_t)l*C + c)*R + r] = (bf16_t)src[(size_t)l*Lstr + (size_t)r*C + c];
}

// Wmsg [4][256][64] -> combined [4][128 cols][128 k]; col<64 = P-half, col>=64 = Q-half
__global__ void k_tr2(const float* __restrict__ src, bf16_t* __restrict__ dst){
  int idx = blockIdx.x*256 + threadIdx.x;
  if (idx >= 4*128*128) return;
  int l = idx >> 14; int j = (idx >> 7) & 127; int c = idx & 127;
  float v = (j < 64) ? src[(size_t)l*16384 + c*64 + j]
                     : src[(size_t)l*16384 + 8192 + c*64 + (j-64)];
  dst[idx] = (bf16_t)v;
}

// ---------------- radial MLP table build ----------------
__global__ __launch_bounds__(256) void k_tab_embed(
    const float* __restrict__ We0, const float* __restrict__ be0,
    const float* __restrict__ We1, const float* __restrict__ be1,
    const float* __restrict__ Wr0, const float* __restrict__ Wr1, const float* __restrict__ Wrl,
    float* __restrict__ h2tab, float* __restrict__ radtab)
{
  __shared__ float sb[4][640];
  const int wid = threadIdx.x >> 6, lane = threadIdx.x & 63;
  const int e = blockIdx.x*4 + wid;
  if (e >= GTAB) return;
  const float d = e * (12.0f/(GTAB-1));
  const float DLT = 12.0f/599.0f;
  const float CO  = -0.5f/((2.0f*DLT)*(2.0f*DLT));
  int jc = (int)(d/DLT + 0.5f);
  int j0 = jc - 16; if (j0 < 0) j0 = 0; if (j0 > 600-32) j0 = 600-32;
  float diff = d - (float)(j0+lane)*DLT;
  float gval = __expf(CO*diff*diff);
  float p[10];
  #pragma unroll
  for (int u = 0; u < 10; u++) p[u] = 0.f;
  const int c2 = 2*lane;
  for (int jj = 0; jj < 32; jj++){
    float gj = __shfl(gval, jj);
    int row = j0 + jj;
    const float2 w0 = *(const float2*)(We0 + row*128 + c2);
    p[0] += gj*w0.x; p[1] += gj*w0.y;
    #pragma unroll
    for (int i = 0; i < 4; i++){
      const float2 wr = *(const float2*)(Wr0 + ((size_t)i*600 + row)*128 + c2);
      p[2+2*i] += gj*wr.x; p[3+2*i] += gj*wr.y;
    }
  }
  sb[wid][c2]   = silu_f(p[0] + be0[c2]);
  sb[wid][c2+1] = silu_f(p[1] + be0[c2+1]);
  #pragma unroll
  for (int i = 0; i < 4; i++){
    sb[wid][128 + 128*i + c2]   = silu_f(p[2+2*i]);
    sb[wid][128 + 128*i + c2+1] = silu_f(p[3+2*i]);
  }
  float a0 = 0.f, a1 = 0.f;
  for (int c = 0; c < 128; c++){
    float hv = sb[wid][c];
    const float2 w = *(const float2*)(We1 + c*128 + c2);
    a0 += hv*w.x; a1 += hv*w.y;
  }
  a0 = silu_f(a0 + be1[c2]); a1 = silu_f(a1 + be1[c2+1]);
  h2tab[(size_t)e*128 + c2]     = a0;
  h2tab[(size_t)e*128 + c2 + 1] = a1;
  #pragma unroll
  for (int i = 0; i < 4; i++){
    float r0 = 0.f, r1 = 0.f;
    const float* W1 = Wr1 + (size_t)i*128*128;
    for (int c = 0; c < 128; c++){
      float rv = sb[wid][128 + 128*i + c];
      const float2 w = *(const float2*)(W1 + c*128 + c2);
      r0 += rv*w.x; r1 += rv*w.y;
    }
    r0 = silu_f(r0); r1 = silu_f(r1);
    const float* Wl = Wrl + (size_t)i*128*7;
    float pl[7];
    #pragma unroll
    for (int l = 0; l < 7; l++) pl[l] = r0*Wl[c2*7+l] + r1*Wl[(c2+1)*7+l];
    #pragma unroll
    for (int l = 0; l < 7; l++) pl[l] = wave_reduce_sum(pl[l]);
    if (lane == 0){
      #pragma unroll
      for (int l = 0; l < 7; l++) radtab[(size_t)e*28 + i*7 + l] = pl[l];
    }
  }
}

// ---------------- per-edge h2 interp (edge-parallel) ----------------
__global__ void k_h2e(const float* __restrict__ ed, const float* __restrict__ h2tab,
                      bf16_t* __restrict__ h2e, int E){
  int idx = blockIdx.x*256 + threadIdx.x;
  if (idx >= E*128) return;
  int e = idx >> 7, ch = idx & 127;
  float d = ed[e];
  float u = d * ((GTAB-1)/12.0f);
  int j = (int)u; if (j > GTAB-2) j = GTAB-2;
  float f = u - (float)j;
  float a = h2tab[(size_t)j*128 + ch], b = h2tab[(size_t)(j+1)*128 + ch];
  h2e[idx] = (bf16_t)(a + f*(b-a));
}

// ---------------- x init ----------------
__global__ __launch_bounds__(256) void k_init_x(
    const int* __restrict__ Z, const float* __restrict__ emb,
    const bf16_t* __restrict__ WeprojT, const bf16_t* __restrict__ h2e,
    const int* __restrict__ rowptr, const int* __restrict__ order,
    float* __restrict__ X, int N)
{
  __shared__ bf16_t h2s[32*136];
  __shared__ int Zs[32];
  int n0 = blockIdx.x*32, t = threadIdx.x;
  int half = t >> 7, ch = t & 127;
  for (int pair = 0; pair < 16; pair++){
    int nn = pair*2 + half;
    int n = n0 + nn;
    float acc = 0.f;
    if (n < N){
      int rp = rowptr[n], deg = rowptr[n+1]-rp;
      for (int idx = 0; idx < deg; idx++){
        int e = order[rp+idx];
        acc += (float)h2e[(size_t)e*128 + ch];
      }
    }
    h2s[nn*136 + ch] = (bf16_t)acc;
  }
  if (t < 32) Zs[t] = (n0 + t < N) ? Z[n0+t] : 0;
  __syncthreads();
  int wid = t >> 6, lane = t & 63;
  int mtile = wid & 1;
  int row = mtile*16 + (lane & 15);
  int koff = (lane >> 4)*8;
  bf16x8 afr[4];
  #pragma unroll
  for (int kk = 0; kk < 4; kk++) afr[kk] = *(const bf16x8*)(h2s + row*136 + kk*32 + koff);
  for (int nt = (wid>>1); nt < 232; nt += 2){
    f32x4 acc = {0.f,0.f,0.f,0.f};
    int col = nt*16 + (lane & 15);
    #pragma unroll
    for (int kk = 0; kk < 4; kk++){
      bf16x8 b = *(const bf16x8*)(WeprojT + (size_t)col*128 + kk*32 + koff);
      acc = mfma16(afr[kk], b, acc);
    }
    #pragma unroll
    for (int r = 0; r < 4; r++){
      int r32 = mtile*16 + (lane>>4)*4 + r;
      int n = n0 + r32;
      if (n < N){
        float v = acc[r] * (1.0f/23.395238876342773f);
        if (col < 128) v += emb[(size_t)Zs[r32]*128 + col];
        X[(size_t)n*3712 + col] = v;
      }
    }
  }
}

// ---------------- per-layer: rms + combined [P|Q] GEMM + PV(fp8) + qm + P0/Q0 ----------------
__global__ __launch_bounds__(512) void k_pqv(
    const float* __restrict__ X, const float* __restrict__ gamma1,
    const bf16_t* __restrict__ WmsgCT, const bf16_t* __restrict__ WvT,
    unsigned char* __restrict__ PV8, bf16_t* __restrict__ qmb,
    float* __restrict__ P0, float* __restrict__ Q0, int layer)
{
  __shared__ bf16_t ys16[32*136];
  __shared__ bf16_t pq16[32*136];
  int n = blockIdx.x, t = threadIdx.x;
  int wid = t >> 6, lane = t & 63;
  const float* g1 = gamma1 + layer*128;
  const float* xp = X + (size_t)n*3712;
  for (int k = wid; k < KM; k += 8){
    float x0 = xp[k*128 + lane], x1 = xp[k*128 + 64 + lane];
    float ss = wave_reduce_sum(x0*x0 + x1*x1);
    float sc = rsqrtf(ss*(1.0f/128.0f) + 1e-6f);
    ys16[k*136 + lane]      = (bf16_t)(x0*sc*g1[lane]);
    ys16[k*136 + 64 + lane] = (bf16_t)(x1*sc*g1[64+lane]);
  }
  for (int idx = t; idx < 3*136; idx += 512) ys16[29*136 + idx] = (bf16_t)0.f;
  __syncthreads();
  int mtile = wid >> 2;
  int row = mtile*16 + (lane & 15);
  int koff = (lane >> 4)*8;
  // GEMM-C: [32 x 128] = ys @ WmsgCT (8 waves, 2 cols each)
  {
    const bf16_t* Bc = WmsgCT + (size_t)layer*16384;
    f32x4 acc[2] = {{0,0,0,0},{0,0,0,0}};
    #pragma unroll
    for (int kk = 0; kk < 128; kk += 32){
      bf16x8 a = *(const bf16x8*)(ys16 + row*136 + kk + koff);
      #pragma unroll
      for (int u = 0; u < 2; u++){
        int col = ((wid&3)*2+u)*16 + (lane & 15);
        bf16x8 b = *(const bf16x8*)(Bc + (size_t)col*128 + kk + koff);
        acc[u] = mfma16(a, b, acc[u]);
      }
    }
    #pragma unroll
    for (int u = 0; u < 2; u++){
      int col = ((wid&3)*2+u)*16 + (lane & 15);
      #pragma unroll
      for (int r = 0; r < 4; r++){
        int r32 = mtile*16 + (lane>>4)*4 + r;
        pq16[r32*136 + col] = (bf16_t)acc[u][r];
      }
      if (mtile == 0 && (lane>>4) == 0){
        float v = acc[u][0];
        if (col < 64) P0[(size_t)n*64 + col] = v;
        else          Q0[(size_t)n*64 + col - 64] = v;
      }
    }
  }
  __syncthreads();
  // PV GEMM: [32 x 128] = pq16[:, 0:64] @ WvT -> PV8 [hv][k32] fp8 e4m3
  {
    const bf16_t* Bt = WvT + (size_t)layer*8192;
    f32x4 acc[2] = {{0,0,0,0},{0,0,0,0}};
    #pragma unroll
    for (int kk = 0; kk < 64; kk += 32){
      bf16x8 a = *(const bf16x8*)(pq16 + row*136 + kk + koff);
      #pragma unroll
      for (int u = 0; u < 2; u++){
        int col = ((wid&3)*2+u)*16 + (lane & 15);
        bf16x8 b = *(const bf16x8*)(Bt + (size_t)col*64 + kk + koff);
        acc[u] = mfma16(a, b, acc[u]);
      }
    }
    unsigned char* pvp = PV8 + (size_t)n*4096;
    int r0i = mtile*16 + (lane>>4)*4;
    #pragma unroll
    for (int u = 0; u < 2; u++){
      int col = ((wid&3)*2+u)*16 + (lane & 15);
      float pk[4];
      #pragma unroll
      for (int r = 0; r < 4; r++){
        int r32 = r0i + r;
        pk[r] = (r32 < KM) ? acc[u][r] : 0.f;
      }
      int dw = __builtin_amdgcn_cvt_pk_fp8_f32(pk[0], pk[1], 0, false);
      dw = __builtin_amdgcn_cvt_pk_fp8_f32(pk[2], pk[3], dw, true);
      *(unsigned int*)(pvp + col*32 + r0i) = (unsigned int)dw;
    }
  }
  for (int idx = t; idx < KM*64; idx += 512){
    int k = idx >> 6, j = idx & 63;
    qmb[(size_t)n*1856 + idx] = pq16[k*136 + 64 + j];
  }
}

// ---------------- per-layer: edge logits + gate (MFMA) ----------------
__global__ __launch_bounds__(256) void k_edge_logits(
    const int* __restrict__ EI, const float* __restrict__ ed,
    const float* __restrict__ P0, const float* __restrict__ Q0,
    const float* __restrict__ radtab, const bf16_t* __restrict__ WapT, const float* __restrict__ wa,
    const bf16_t* __restrict__ WgT, float* __restrict__ logi, bf16_t* __restrict__ gate16,
    int E, int layer)
{
  __shared__ bf16_t m0s[16*72];
  __shared__ int   srcs[16], tgts[16];
  __shared__ float r0s[16];
  int t = threadIdx.x;
  int eb = blockIdx.x*16;
  if (t < 16){
    int e = eb + t;
    if (e < E){
      srcs[t] = EI[e]; tgts[t] = EI[E+e];
      float d = ed[e];
      float u = d * ((GTAB-1)/12.0f);
      int j = (int)u; if (j > GTAB-2) j = GTAB-2;
      float f = u - (float)j;
      float a = radtab[(size_t)j*28 + layer*7], b = radtab[(size_t)(j+1)*28 + layer*7];
      r0s[t] = a + f*(b-a);
    } else { srcs[t] = 0; tgts[t] = 0; r0s[t] = 0.f; }
  }
  __syncthreads();
  #pragma unroll
  for (int u = 0; u < 4; u++){
    int idx = t + u*256;
    int i = idx >> 6, j = idx & 63;
    m0s[i*72 + j] = (bf16_t)((P0[(size_t)srcs[i]*64 + j] + Q0[(size_t)tgts[i]*64 + j]) * r0s[i]);
  }
  __syncthreads();
  int wid = t >> 6, lane = t & 63;
  int l15 = lane & 15, lg = lane >> 4;   // row group
  int koff = lg*8;
  bf16x8 a0 = *(const bf16x8*)(m0s + l15*72 + koff);
  bf16x8 a1 = *(const bf16x8*)(m0s + l15*72 + 32 + koff);
  const bf16_t* Ba = WapT + (size_t)layer*16384;
  const bf16_t* Bg = WgT  + (size_t)layer*8192;
  const float* wav = wa + layer*256;
  f32x4 accA[4], accG[2];
  #pragma unroll
  for (int u = 0; u < 4; u++){
    int col = 64*wid + u*16 + l15;
    f32x4 acc = {0,0,0,0};
    acc = mfma16(a0, *(const bf16x8*)(Ba + (size_t)col*64 + koff), acc);
    acc = mfma16(a1, *(const bf16x8*)(Ba + (size_t)col*64 + 32 + koff), acc);
    accA[u] = acc;
  }
  #pragma unroll
  for (int u = 0; u < 2; u++){
    int col = 32*wid + u*16 + l15;
    f32x4 acc = {0,0,0,0};
    acc = mfma16(a0, *(const bf16x8*)(Bg + (size_t)col*64 + koff), acc);
    acc = mfma16(a1, *(const bf16x8*)(Bg + (size_t)col*64 + 32 + koff), acc);
    accG[u] = acc;
  }
  #pragma unroll
  for (int u = 0; u < 2; u++){
    int col = 32*wid + u*16 + l15;
    #pragma unroll
    for (int r = 0; r < 4; r++){
      int e = eb + lg*4 + r;
      if (e < E) gate16[(size_t)e*128 + col] = (bf16_t)silu_f(accG[u][r]);
    }
  }
  #pragma unroll
  for (int hpair = 0; hpair < 2; hpair++){
    int c0 = 64*wid + hpair*32 + l15;
    float w0 = wav[c0], w1 = wav[c0+16];
    float s[4];
    #pragma unroll
    for (int r = 0; r < 4; r++)
      s[r] = silu_f(accA[2*hpair][r])*w0 + silu_f(accA[2*hpair+1][r])*w1;
    #pragma unroll
    for (int r = 0; r < 4; r++){
      s[r] += __shfl_xor(s[r], 1);
      s[r] += __shfl_xor(s[r], 2);
      s[r] += __shfl_xor(s[r], 4);
      s[r] += __shfl_xor(s[r], 8);
    }
    if (l15 == 0){
      #pragma unroll
      for (int r = 0; r < 4; r++){
        int e = eb + lg*4 + r;
        if (e < E) logi[(size_t)e*8 + 2*wid + hpair] = s[r];
      }
    }
  }
}

// fp8 dword -> 4 fp32 FMA into acc
#define FMA_DW(dw, kb) { \
  f32x2 lo_ = __builtin_amdgcn_cvt_pk_f32_fp8((dw), false); \
  f32x2 hi_ = __builtin_amdgcn_cvt_pk_f32_fp8((dw), true); \
  acc[(kb)]   += lo_.x * rw[LOF2((kb))]; \
  acc[(kb)+1] += lo_.y * rw[LOF2((kb)+1)]; \
  acc[(kb)+2] += hi_.x * rw[LOF2((kb)+2)]; \
  acc[(kb)+3] += hi_.y * rw[LOF2((kb)+3)]; }

// ---------------- fused per-layer: attn (softmax+gather+QV+Wo) + FFN; x in LDS ----------------
__global__ __launch_bounds__(512, 4) void k_attn_ffn(
    const int* __restrict__ EI, const int* __restrict__ rowptr, const int* __restrict__ order,
    const float* __restrict__ ed, const bf16_t* __restrict__ qmb,
    const bf16_t* __restrict__ WvT, const bf16_t* __restrict__ WoT,
    const unsigned char* __restrict__ PV8, const bf16_t* __restrict__ gate16,
    const float* __restrict__ logi, const float* __restrict__ radtab,
    const float* __restrict__ gamma2, const float* __restrict__ Wfg,
    const bf16_t* __restrict__ Wf1T, const bf16_t* __restrict__ Wf2T,
    float* __restrict__ X, int layer)
{
  __shared__ float  xs[3712];        // x residual, fp32, persistent
  __shared__ bf16_t ysag[32*136];    // attn: merge buf A + Wo input; ffn: ys16
  __shared__ bf16_t hsqv[32*136];    // attn: qvs16, then merge buf B; ffn: hs16
  __shared__ char   uA[4608];        // qm16 -> {at8, rl7, es, srcs} -> ffn gate partials
  __shared__ float  mh[8], iden[8];

  bf16_t* qm16 = (bf16_t*)uA;
  float*  at8  = (float*)uA;
  float*  rl7  = (float*)(uA + 2048);
  int*    es   = (int*)(uA + 4096);
  int*    srcs = (int*)(uA + 4352);
  float*  pf   = (float*)uA;         // ffn gate partials (640 f32)

  int n = blockIdx.x, t = threadIdx.x;
  int wid = t >> 6, lane = t & 63;
  int rp = rowptr[n], deg = rowptr[n+1] - rp;

  // load x into LDS
  for (int idx = t; idx < 3712; idx += 512) xs[idx] = X[(size_t)n*3712 + idx];

  if (deg > 0){
    // qm -> LDS (+pads)
    for (int idx = t; idx < KM*64; idx += 512){
      int k = idx >> 6, j = idx & 63;
      qm16[k*72 + j] = qmb[(size_t)n*1856 + idx];
    }
    for (int idx = t; idx < 3*72; idx += 512) qm16[29*72 + idx] = (bf16_t)0.f;
    // softmax stats (8 lanes per head)
    if (t < 64){
      int hh = t & 7, slot = t >> 3;
      float m = -3.0e38f;
      for (int idx = slot; idx < deg; idx += 8){
        int e = order[rp+idx];
        m = fmaxf(m, logi[(size_t)e*8 + hh]);
      }
      m = fmaxf(m, __shfl_xor(m, 8));
      m = fmaxf(m, __shfl_xor(m, 16));
      m = fmaxf(m, __shfl_xor(m, 32));
      float den = 0.f;
      for (int idx = slot; idx < deg; idx += 8){
        int e = order[rp+idx];
        den += env_f(ed[e]) * __expf(logi[(size_t)e*8 + hh] - m);
      }
      den += __shfl_xor(den, 8);
      den += __shfl_xor(den, 16);
      den += __shfl_xor(den, 32);
      if (t < 8){ mh[t] = m; iden[t] = 1.0f/(den + 1e-16f); }
    }
    __syncthreads();
    // QV GEMM: hsqv = qm16 @ WvT (K=64, 8 waves)
    {
      const bf16_t* Bt = WvT + (size_t)layer*8192;
      int mtile = wid >> 2, colt = (wid & 3)*2;
      int row = mtile*16 + (lane & 15);
      int koff = (lane >> 4)*8;
      f32x4 a2[2] = {{0,0,0,0},{0,0,0,0}};
      #pragma unroll
      for (int kk = 0; kk < 64; kk += 32){
        bf16x8 a = *(const bf16x8*)(qm16 + row*72 + kk + koff);
        #pragma unroll
        for (int u = 0; u < 2; u++){
          int col = (colt+u)*16 + (lane & 15);
          bf16x8 b = *(const bf16x8*)(Bt + (size_t)col*64 + kk + koff);
          a2[u] = mfma16(a, b, a2[u]);
        }
      }
      #pragma unroll
      for (int u = 0; u < 2; u++){
        int col = (colt+u)*16 + (lane & 15);
        #pragma unroll
        for (int r = 0; r < 4; r++){
          int r32 = mtile*16 + (lane>>4)*4 + r;
          hsqv[r32*136 + col] = (bf16_t)a2[u][r];
        }
      }
    }
    __syncthreads();   // qvs ready; qm dead -> uA reused by at8/rl7/es/srcs
    // gather: eg in {0..3} x hv in {0..127}; fp8 PV, 2-deep register prefetch
    int eg = t >> 7, hv = t & 127, h = hv >> 4;
    float acc[32];
    #pragma unroll
    for (int j = 0; j < 32; j++) acc[j] = 0.f;
    float S[7];
    #pragma unroll
    for (int l = 0; l < 7; l++) S[l] = 0.f;
    for (int base = 0; base < deg; base += 64){
      int ne = min(64, deg - base);
      if (t < ne){ int e = order[rp + base + t]; es[t] = e; srcs[t] = EI[e]; }
      __syncthreads();
      if (t < ne*8){
        int i = t >> 3, q = t & 7;
        int e = es[i];
        float d = ed[e];
        at8[t] = env_f(d) * __expf(logi[(size_t)e*8 + q] - mh[q]) * iden[q];
        if (q < 7){
          float u = d * ((GTAB-1)/12.0f);
          int j = (int)u; if (j > GTAB-2) j = GTAB-2;
          float f = u - (float)j;
          float a = radtab[(size_t)j*28 + layer*7 + q], b = radtab[(size_t)(j+1)*28 + layer*7 + q];
          rl7[t] = a + f*(b-a);
        }
      }
      __syncthreads();
      uint4 A0 = {0,0,0,0}, A1 = {0,0,0,0}, B0 = {0,0,0,0}, B1 = {0,0,0,0};
      float gA = 0.f, gB = 0.f;
      int i = eg;
      if (i < ne){
        const uint4* p = (const uint4*)(PV8 + (size_t)srcs[i]*4096 + hv*32);
        A0 = p[0]; A1 = p[1];
        gA = (float)gate16[(size_t)es[i]*128 + hv];
      }
      if (i + 4 < ne){
        const uint4* p = (const uint4*)(PV8 + (size_t)srcs[i+4]*4096 + hv*32);
        B0 = p[0]; B1 = p[1];
        gB = (float)gate16[(size_t)es[i+4]*128 + hv];
      }
      while (i < ne){
        int i2 = i + 8;
        uint4 C0 = {0,0,0,0}, C1 = {0,0,0,0}; float gC = 0.f;
        if (i2 < ne){
          const uint4* p = (const uint4*)(PV8 + (size_t)srcs[i2]*4096 + hv*32);
          C0 = p[0]; C1 = p[1];
          gC = (float)gate16[(size_t)es[i2]*128 + hv];
        }
        float w = gA * at8[i*8 + h];
        float rw[7];
        #pragma unroll
        for (int l = 0; l < 7; l++){ rw[l] = rl7[i*8 + l]*w; S[l] += rw[l]; }
        FMA_DW(A0.x, 0)  FMA_DW(A0.y, 4)  FMA_DW(A0.z, 8)  FMA_DW(A0.w, 12)
        FMA_DW(A1.x, 16) FMA_DW(A1.y, 20) FMA_DW(A1.z, 24) FMA_DW(A1.w, 28)
        A0 = B0; A1 = B1; gA = gB;
        B0 = C0; B1 = C1; gB = gC;
        i += 4;
      }
      __syncthreads();
    }
    // QV * S (per-group partial S sums correctly across merge); reads hsqv (qvs)
    #pragma unroll
    for (int j = 0; j < 32; j++)
      acc[j] += (float)hsqv[j*136 + hv] * S[LOF2(j)];
    __syncthreads();   // all qvs reads done before hsqv overwritten
    // bf16 merge: g0->ysag, g1->hsqv; g2+=ysag, g3+=hsqv; combine
    if (eg == 0){
      #pragma unroll
      for (int j = 0; j < 32; j++) ysag[j*136 + hv] = (bf16_t)acc[j];
    } else if (eg == 1){
      #pragma unroll
      for (int j = 0; j < 32; j++) hsqv[j*136 + hv] = (bf16_t)acc[j];
    }
    __syncthreads();
    if (eg == 2){
      #pragma unroll
      for (int j = 0; j < 32; j++) ysag[j*136 + hv] = (bf16_t)((float)ysag[j*136 + hv] + acc[j]);
    } else if (eg == 3){
      #pragma unroll
      for (int j = 0; j < 32; j++) hsqv[j*136 + hv] = (bf16_t)((float)hsqv[j*136 + hv] + acc[j]);
    }
    __syncthreads();
    for (int idx = t; idx < 32*128; idx += 512){
      int k = idx >> 7, c = idx & 127;
      ysag[k*136 + c] = (bf16_t)((float)ysag[k*136 + c] + (float)hsqv[k*136 + c]);
    }
    __syncthreads();
    // Wo GEMM: xs += ag @ WoT (K=128, 8 waves)
    {
      const bf16_t* Bt = WoT + (size_t)layer*16384;
      int mtile = wid >> 2, colt = (wid & 3)*2;
      int row = mtile*16 + (lane & 15);
      int koff = (lane >> 4)*8;
      f32x4 a2[2] = {{0,0,0,0},{0,0,0,0}};
      #pragma unroll
      for (int kk = 0; kk < 128; kk += 32){
        bf16x8 a = *(const bf16x8*)(ysag + row*136 + kk + koff);
        #pragma unroll
        for (int u = 0; u < 2; u++){
          int col = (colt+u)*16 + (lane & 15);
          bf16x8 b = *(const bf16x8*)(Bt + (size_t)col*128 + kk + koff);
          a2[u] = mfma16(a, b, a2[u]);
        }
      }
      #pragma unroll
      for (int u = 0; u < 2; u++){
        int col = (colt+u)*16 + (lane & 15);
        #pragma unroll
        for (int r = 0; r < 4; r++){
          int r32 = mtile*16 + (lane>>4)*4 + r;
          if (r32 < KM) xs[r32*128 + col] += a2[u][r];
        }
      }
    }
  }
  __syncthreads();
  // ---------- FFN phase ----------
  const float* g2 = gamma2 + layer*128;
  for (int k = wid; k < KM; k += 8){
    float x0 = xs[k*128 + lane], x1 = xs[k*128 + 64 + lane];
    float ss = wave_reduce_sum(x0*x0 + x1*x1);
    float sc = rsqrtf(ss*(1.0f/128.0f) + 1e-6f);
    ysag[k*136 + lane]      = (bf16_t)(x0*sc*g2[lane]);
    ysag[k*136 + 64 + lane] = (bf16_t)(x1*sc*g2[64+lane]);
  }
  for (int idx = t; idx < 3*136; idx += 512) ysag[29*136 + idx] = (bf16_t)0.f;
  __syncthreads();
  // gate: 4 partials x 128 into pf (uA)
  {
    int part = t >> 7, f = t & 127;
    const float* Wfgp = Wfg + (size_t)layer*16384;
    float p = 0.f;
    for (int c = part*32; c < part*32 + 32; c++) p += (float)ysag[c] * Wfgp[c*128 + f];
    pf[part*128 + f] = p;
  }
  __syncthreads();
  if (t < 128) pf[512 + t] = silu_f(pf[t] + pf[128+t] + pf[256+t] + pf[384+t]);
  __syncthreads();
  // Wf1: hs = (ys @ Wf1T) * gf
  {
    const bf16_t* Bt = Wf1T + (size_t)layer*16384;
    int mtile = wid >> 2, colt = (wid & 3)*2;
    int row = mtile*16 + (lane & 15);
    int koff = (lane >> 4)*8;
    f32x4 a2[2] = {{0,0,0,0},{0,0,0,0}};
    #pragma unroll
    for (int kk = 0; kk < 128; kk += 32){
      bf16x8 a = *(const bf16x8*)(ysag + row*136 + kk + koff);
      #pragma unroll
      for (int u = 0; u < 2; u++){
        int col = (colt+u)*16 + (lane & 15);
        bf16x8 b = *(const bf16x8*)(Bt + (size_t)col*128 + kk + koff);
        a2[u] = mfma16(a, b, a2[u]);
      }
    }
    #pragma unroll
    for (int u = 0; u < 2; u++){
      int col = (colt+u)*16 + (lane & 15);
      float gfc = pf[512 + col];
      #pragma unroll
      for (int r = 0; r < 4; r++){
        int r32 = mtile*16 + (lane>>4)*4 + r;
        hsqv[r32*136 + col] = (bf16_t)(a2[u][r]*gfc);
      }
    }
  }
  __syncthreads();
  // Wf2: xs += hs @ Wf2T
  {
    const bf16_t* Bt = Wf2T + (size_t)layer*16384;
    int mtile = wid >> 2, colt = (wid & 3)*2;
    int row = mtile*16 + (lane & 15);
    int koff = (lane >> 4)*8;
    f32x4 a2[2] = {{0,0,0,0},{0,0,0,0}};
    #pragma unroll
    for (int kk = 0; kk < 128; kk += 32){
      bf16x8 a = *(const bf16x8*)(hsqv + row*136 + kk + koff);
      #pragma unroll
      for (int u = 0; u < 2; u++){
        int col = (colt+u)*16 + (lane & 15);
        bf16x8 b = *(const bf16x8*)(Bt + (size_t)col*128 + kk + koff);
        a2[u] = mfma16(a, b, a2[u]);
      }
    }
    #pragma unroll
    for (int u = 0; u < 2; u++){
      int col = (colt+u)*16 + (lane & 15);
      #pragma unroll
      for (int r = 0; r < 4; r++){
        int r32 = mtile*16 + (lane>>4)*4 + r;
        if (r32 < KM) xs[r32*128 + col] += a2[u][r];
      }
    }
  }
  __syncthreads();
  // store x back
  for (int idx = t; idx < 3712; idx += 512) X[(size_t)n*3712 + idx] = xs[idx];
}

// ---------------- output head ----------------
__global__ __launch_bounds__(256) void k_head(
    const float* __restrict__ X, const float* __restrict__ Wh1, const float* __restrict__ Wh2,
    float* __restrict__ partial, int N)
{
  __shared__ float wsum[4];
  int t = threadIdx.x;
  int half = t >> 7;
  int n = blockIdx.x*2 + half;
  int f = t & 127;
  float sv = 0.f;
  if (n < N){
    const float* xp = X + (size_t)n*3712;
    float acc = 0.f;
    for (int c = 0; c < 128; c++) acc += xp[c]*Wh1[c*128 + f];
    sv = silu_f(acc)*Wh2[f];
  }
  sv = wave_reduce_sum(sv);
  if ((t & 63) == 0) wsum[t >> 6] = sv;
  __syncthreads();
  if (t == 0) partial[blockIdx.x] = wsum[0] + wsum[1] + wsum[2] + wsum[3];
}

__global__ __launch_bounds__(256) void k_reduce(const float* __restrict__ partial, float* __restrict__ out, int P){
  __shared__ float sh[256];
  int t = threadIdx.x;
  float s = 0.f;
  for (int i = t; i < P; i += 256) s += partial[i];
  sh[t] = s; __syncthreads();
  for (int off = 128; off > 0; off >>= 1){
    if (t < off) sh[t] += sh[t+off];
    __syncthreads();
  }
  if (t == 0) out[0] = sh[0] / 77.81317f;
}

extern "C" void kernel_launch(void* const* d_in, const int* in_sizes, int n_in,
                              void* d_out, int out_size, void* d_ws, size_t ws_size,
                              hipStream_t stream)
{
  const int*   Z      = (const int*)d_in[0];
  const int*   EI     = (const int*)d_in[1];
  const float* ed     = (const float*)d_in[2];
  const float* emb    = (const float*)d_in[3];
  const float* We0    = (const float*)d_in[4];
  const float* be0    = (const float*)d_in[5];
  const float* We1    = (const float*)d_in[6];
  const float* be1    = (const float*)d_in[7];
  const float* Weproj = (const float*)d_in[8];
  const float* gamma1 = (const float*)d_in[9];
  const float* gamma2 = (const float*)d_in[10];
  const float* Wr0    = (const float*)d_in[11];
  const float* Wr1    = (const float*)d_in[12];
  const float* Wrl    = (const float*)d_in[13];
  const float* Wmsg   = (const float*)d_in[14];
  const float* Wap    = (const float*)d_in[15];
  const float* wa     = (const float*)d_in[16];
  const float* Wg     = (const float*)d_in[17];
  const float* Wv     = (const float*)d_in[18];
  const float* Wo     = (const float*)d_in[19];
  const float* Wf1    = (const float*)d_in[20];
  const float* Wfg    = (const float*)d_in[21];
  const float* Wf2    = (const float*)d_in[22];
  const float* Wh1    = (const float*)d_in[23];
  const float* Wh2    = (const float*)d_in[24];

  const int N = in_sizes[0];
  const int E = in_sizes[2];

  float* ws = (float*)d_ws;
  size_t o = 0;
  auto alloc = [&](size_t nf){ float* p = ws + o; o += (nf + 7) & ~(size_t)7; return p; };

  float* X      = alloc((size_t)N*3712);
  float* P0     = alloc((size_t)N*64);
  float* Q0     = alloc((size_t)N*64);
  float* logi   = alloc((size_t)E*8);
  float* part   = alloc((size_t)((N+1)/2) + 8);
  float* radtab = alloc((size_t)GTAB*28);
  bf16_t* qmb   = (bf16_t*)alloc((size_t)N*928);       // N*1856 bf16; h2tab aliases here
  float* h2tab  = (float*)qmb;                          // disjoint lifetimes
  unsigned char* PV8 = (unsigned char*)alloc((size_t)N*1024);  // N*4096 fp8 ([hv][k32])
  bf16_t* gate16= (bf16_t*)alloc((size_t)E*64);        // E*128 bf16; h2e aliases pre-layers
  bf16_t* arena = (bf16_t*)alloc(434176);              // 868352 bf16
  int* rowptr = (int*)alloc((size_t)N+8);
  int* curs   = (int*)alloc((size_t)N);
  int* order  = (int*)alloc((size_t)E);

  bf16_t* WmsgCT  = arena;            // [4][128][128]
  bf16_t* WvT     = arena + 65536;    // [4][128][64]
  bf16_t* WoT     = arena + 98304;    // [4][128][128]
  bf16_t* Wf1T    = arena + 163840;   // [4][128][128]
  bf16_t* Wf2T    = arena + 229376;   // [4][128][128]
  bf16_t* WapT    = arena + 294912;   // [4][256][64]
  bf16_t* WgT     = arena + 360448;   // [4][128][64]
  bf16_t* WeprojT = arena + 393216;   // [3712][128]

  bf16_t* h2e = gate16;   // alias: dead before layer-0 logits writes gate16

  // CSR by target
  hipMemsetAsync(curs, 0, sizeof(int)*N, stream);
  k_count<<<(E+255)/256, 256, 0, stream>>>(EI, curs, E);
  k_scan<<<1, 1024, 0, stream>>>(curs, rowptr, N);
  k_fill<<<(E+255)/256, 256, 0, stream>>>(EI, curs, order, E);
  k_sort<<<(N+255)/256, 256, 0, stream>>>(rowptr, order, N);

  // weight transposes -> bf16 arenas
  k_tr2<<<256, 256, 0, stream>>>(Wmsg, WmsgCT);
  k_tr<<<128, 256, 0, stream>>>(Wv,   WvT,  4, 64, 128, 8192);
  k_tr<<<256, 256, 0, stream>>>(Wo,   WoT,  4, 128, 128, 16384);
  k_tr<<<256, 256, 0, stream>>>(Wf1,  Wf1T, 4, 128, 128, 16384);
  k_tr<<<256, 256, 0, stream>>>(Wf2,  Wf2T, 4, 128, 128, 16384);
  k_tr<<<256, 256, 0, stream>>>(Wap,  WapT, 4, 64, 256, 16384);
  k_tr<<<128, 256, 0, stream>>>(Wg,   WgT,  4, 64, 128, 8192);
  k_tr<<<1856, 256, 0, stream>>>(Weproj, WeprojT, 1, 128, 3712, 0);

  // radial tables + per-edge h2 + x init
  k_tab_embed<<<GTAB/4, 256, 0, stream>>>(We0, be0, We1, be1, Wr0, Wr1, Wrl, h2tab, radtab);
  k_h2e<<<(E*128+255)/256, 256, 0, stream>>>(ed, h2tab, h2e, E);
  k_init_x<<<(N+31)/32, 256, 0, stream>>>(Z, emb, WeprojT, h2e, rowptr, order, X, N);

  for (int i = 0; i < 4; i++){
    k_pqv<<<N, 512, 0, stream>>>(X, gamma1, WmsgCT, WvT, PV8, qmb, P0, Q0, i);
    k_edge_logits<<<(E+15)/16, 256, 0, stream>>>(EI, ed, P0, Q0, radtab, WapT, wa, WgT, logi, gate16, E, i);
    k_attn_ffn<<<N, 512, 0, stream>>>(EI, rowptr, order, ed, qmb, WvT, WoT, PV8, gate16,
                                      logi, radtab, gamma2, Wfg, Wf1T, Wf2T, X, i);
  }

  int PB = (N+1)/2;
  k_head<<<PB, 256, 0, stream>>>(X, Wh1, Wh2, part, N);
  k_reduce<<<1, 256, 0, stream>>>(part, (float*)d_out, PB);
}

// Round 8
// 2339.988 us; speedup vs baseline: 1.4130x; 1.0295x over previous
//
#include <hip/hip_runtime.h>

#define KM 29
#define GTAB 2048

typedef __bf16 bf16_t;
typedef __bf16 bf16x8 __attribute__((ext_vector_type(8)));
typedef __bf16 bf16x4 __attribute__((ext_vector_type(4)));
typedef __bf16 bf16x2 __attribute__((ext_vector_type(2)));
typedef float  f32x4  __attribute__((ext_vector_type(4)));
typedef float  f32x2  __attribute__((ext_vector_type(2)));

__device__ __forceinline__ float silu_f(float x){ return x / (1.0f + __expf(-x)); }

__device__ __forceinline__ float wave_reduce_sum(float v){
  #pragma unroll
  for (int s = 1; s < 64; s <<= 1) v += __shfl_xor(v, s);
  return v;
}

// l-of-k with clamp for pad rows 29..31 (their data is zero)
__device__ __forceinline__ constexpr int LOF2(int k){
  return (k<1)?0 : (k<4)?1 : (k<9)?2 : (k<14)?3 : (k<19)?4 : (k<24)?5 : 6;
}

__device__ __forceinline__ f32x4 mfma16(bf16x8 a, bf16x8 b, f32x4 c){
  return __builtin_amdgcn_mfma_f32_16x16x32_bf16(a, b, c, 0, 0, 0);
}

__device__ __forceinline__ float env_f(float d){
  float xx = d*(1.0f/12.0f);
  float x2 = xx*xx, x4 = x2*x2, x5 = x4*xx;
  float env = 1.0f - 21.0f*x5 + 35.0f*x5*xx - 15.0f*x5*x2;
  return (xx < 1.0f) ? env : 0.0f;
}

// ---------------- CSR build ----------------
__global__ void k_count(const int* __restrict__ EI, int* __restrict__ cnt, int E){
  int e = blockIdx.x*256 + threadIdx.x;
  if (e < E) atomicAdd(&cnt[EI[E+e]], 1);
}

__global__ __launch_bounds__(1024) void k_scan(int* __restrict__ cnt, int* __restrict__ rowptr, int N){
  __shared__ int ts[1024];
  int t = threadIdx.x;
  int base = t*8;
  int loc[8]; int sum = 0;
  #pragma unroll
  for (int u = 0; u < 8; u++){ int idx = base+u; int v = (idx < N) ? cnt[idx] : 0; loc[u] = sum; sum += v; }
  ts[t] = sum; __syncthreads();
  for (int off = 1; off < 1024; off <<= 1){
    int v = (t >= off) ? ts[t-off] : 0;
    __syncthreads();
    ts[t] += v;
    __syncthreads();
  }
  int excl = ts[t] - sum;
  #pragma unroll
  for (int u = 0; u < 8; u++){
    int idx = base+u;
    if (idx < N){ int r = excl + loc[u]; rowptr[idx] = r; cnt[idx] = r; }
  }
  if (t == 1023) rowptr[N] = ts[1023];
}

__global__ void k_fill(const int* __restrict__ EI, int* __restrict__ cur, int* __restrict__ order, int E){
  int e = blockIdx.x*256 + threadIdx.x;
  if (e < E){ int pos = atomicAdd(&cur[EI[E+e]], 1); order[pos] = e; }
}

__global__ void k_sort(const int* __restrict__ rowptr, int* __restrict__ order, int N){
  int n = blockIdx.x*256 + threadIdx.x;
  if (n >= N) return;
  int rp = rowptr[n], re = rowptr[n+1];
  for (int a = rp+1; a < re; a++){
    int key = order[a]; int b = a-1;
    while (b >= rp && order[b] > key){ order[b+1] = order[b]; b--; }
    order[b+1] = key;
  }
}

// ---------------- weight transposes ----------------
__global__ void k_tr(const float* __restrict__ src, bf16_t* __restrict__ dst,
                     int L, int R, int C, int Lstr){
  int idx = blockIdx.x*256 + threadIdx.x;
  int total = L*R*C;
  if (idx >= total) return;
  int l = idx / (R*C); int rem = idx - l*(R*C);
  int r = rem / C; int c = rem - r*C;
  dst[((size_t)l*C + c)*R + r] = (bf16_t)src[(size_t)l*Lstr + (size_t)r*C + c];
}

// Wmsg [4][256][64] -> combined [4][128 cols][128 k]; col<64 = P-half, col>=64 = Q-half
__global__ void k_tr2(const float* __restrict__ src, bf16_t* __restrict__ dst){
  int idx = blockIdx.x*256 + threadIdx.x;
  if (idx >= 4*128*128) return;
  int l = idx >> 14; int j = (idx >> 7) & 127; int c = idx & 127;
  float v = (j < 64) ? src[(size_t)l*16384 + c*64 + j]
                     : src[(size_t)l*16384 + 8192 + c*64 + (j-64)];
  dst[idx] = (bf16_t)v;
}

// ---------------- radial MLP table build ----------------
__global__ __launch_bounds__(256) void k_tab_embed(
    const float* __restrict__ We0, const float* __restrict__ be0,
    const float* __restrict__ We1, const float* __restrict__ be1,
    const float* __restrict__ Wr0, const float* __restrict__ Wr1, const float* __restrict__ Wrl,
    float* __restrict__ h2tab, float* __restrict__ radtab)
{
  __shared__ float sb[4][640];
  const int wid = threadIdx.x >> 6, lane = threadIdx.x & 63;
  const int e = blockIdx.x*4 + wid;
  if (e >= GTAB) return;
  const float d = e * (12.0f/(GTAB-1));
  const float DLT = 12.0f/599.0f;
  const float CO  = -0.5f/((2.0f*DLT)*(2.0f*DLT));
  int jc = (int)(d/DLT + 0.5f);
  int j0 = jc - 16; if (j0 < 0) j0 = 0; if (j0 > 600-32) j0 = 600-32;
  float diff = d - (float)(j0+lane)*DLT;
  float gval = __expf(CO*diff*diff);
  float p[10];
  #pragma unroll
  for (int u = 0; u < 10; u++) p[u] = 0.f;
  const int c2 = 2*lane;
  for (int jj = 0; jj < 32; jj++){
    float gj = __shfl(gval, jj);
    int row = j0 + jj;
    const float2 w0 = *(const float2*)(We0 + row*128 + c2);
    p[0] += gj*w0.x; p[1] += gj*w0.y;
    #pragma unroll
    for (int i = 0; i < 4; i++){
      const float2 wr = *(const float2*)(Wr0 + ((size_t)i*600 + row)*128 + c2);
      p[2+2*i] += gj*wr.x; p[3+2*i] += gj*wr.y;
    }
  }
  sb[wid][c2]   = silu_f(p[0] + be0[c2]);
  sb[wid][c2+1] = silu_f(p[1] + be0[c2+1]);
  #pragma unroll
  for (int i = 0; i < 4; i++){
    sb[wid][128 + 128*i + c2]   = silu_f(p[2+2*i]);
    sb[wid][128 + 128*i + c2+1] = silu_f(p[3+2*i]);
  }
  float a0 = 0.f, a1 = 0.f;
  for (int c = 0; c < 128; c++){
    float hv = sb[wid][c];
    const float2 w = *(const float2*)(We1 + c*128 + c2);
    a0 += hv*w.x; a1 += hv*w.y;
  }
  a0 = silu_f(a0 + be1[c2]); a1 = silu_f(a1 + be1[c2+1]);
  h2tab[(size_t)e*128 + c2]     = a0;
  h2tab[(size_t)e*128 + c2 + 1] = a1;
  #pragma unroll
  for (int i = 0; i < 4; i++){
    float r0 = 0.f, r1 = 0.f;
    const float* W1 = Wr1 + (size_t)i*128*128;
    for (int c = 0; c < 128; c++){
      float rv = sb[wid][128 + 128*i + c];
      const float2 w = *(const float2*)(W1 + c*128 + c2);
      r0 += rv*w.x; r1 += rv*w.y;
    }
    r0 = silu_f(r0); r1 = silu_f(r1);
    const float* Wl = Wrl + (size_t)i*128*7;
    float pl[7];
    #pragma unroll
    for (int l = 0; l < 7; l++) pl[l] = r0*Wl[c2*7+l] + r1*Wl[(c2+1)*7+l];
    #pragma unroll
    for (int l = 0; l < 7; l++) pl[l] = wave_reduce_sum(pl[l]);
    if (lane == 0){
      #pragma unroll
      for (int l = 0; l < 7; l++) radtab[(size_t)e*28 + i*7 + l] = pl[l];
    }
  }
}

// ---------------- per-edge h2 interp (edge-parallel) ----------------
__global__ void k_h2e(const float* __restrict__ ed, const float* __restrict__ h2tab,
                      bf16_t* __restrict__ h2e, int E){
  int idx = blockIdx.x*256 + threadIdx.x;
  if (idx >= E*128) return;
  int e = idx >> 7, ch = idx & 127;
  float d = ed[e];
  float u = d * ((GTAB-1)/12.0f);
  int j = (int)u; if (j > GTAB-2) j = GTAB-2;
  float f = u - (float)j;
  float a = h2tab[(size_t)j*128 + ch], b = h2tab[(size_t)(j+1)*128 + ch];
  h2e[idx] = (bf16_t)(a + f*(b-a));
}

// ---------------- x init ----------------
__global__ __launch_bounds__(256) void k_init_x(
    const int* __restrict__ Z, const float* __restrict__ emb,
    const bf16_t* __restrict__ WeprojT, const bf16_t* __restrict__ h2e,
    const int* __restrict__ rowptr, const int* __restrict__ order,
    bf16_t* __restrict__ Xb, int N)
{
  __shared__ bf16_t h2s[32*136];
  __shared__ int Zs[32];
  int n0 = blockIdx.x*32, t = threadIdx.x;
  int half = t >> 7, ch = t & 127;
  for (int pair = 0; pair < 16; pair++){
    int nn = pair*2 + half;
    int n = n0 + nn;
    float acc = 0.f;
    if (n < N){
      int rp = rowptr[n], deg = rowptr[n+1]-rp;
      for (int idx = 0; idx < deg; idx++){
        int e = order[rp+idx];
        acc += (float)h2e[(size_t)e*128 + ch];
      }
    }
    h2s[nn*136 + ch] = (bf16_t)acc;
  }
  if (t < 32) Zs[t] = (n0 + t < N) ? Z[n0+t] : 0;
  __syncthreads();
  int wid = t >> 6, lane = t & 63;
  int mtile = wid & 1;
  int row = mtile*16 + (lane & 15);
  int koff = (lane >> 4)*8;
  bf16x8 afr[4];
  #pragma unroll
  for (int kk = 0; kk < 4; kk++) afr[kk] = *(const bf16x8*)(h2s + row*136 + kk*32 + koff);
  for (int nt = (wid>>1); nt < 232; nt += 2){
    f32x4 acc = {0.f,0.f,0.f,0.f};
    int col = nt*16 + (lane & 15);
    #pragma unroll
    for (int kk = 0; kk < 4; kk++){
      bf16x8 b = *(const bf16x8*)(WeprojT + (size_t)col*128 + kk*32 + koff);
      acc = mfma16(afr[kk], b, acc);
    }
    #pragma unroll
    for (int r = 0; r < 4; r++){
      int r32 = mtile*16 + (lane>>4)*4 + r;
      int n = n0 + r32;
      if (n < N){
        float v = acc[r] * (1.0f/23.395238876342773f);
        if (col < 128) v += emb[(size_t)Zs[r32]*128 + col];
        Xb[(size_t)n*3712 + col] = (bf16_t)v;
      }
    }
  }
}

// ---------------- layer-0 pqv: rms + combined [P|Q] GEMM + PV(fp8) + qm + P0/Q0 ----------------
__global__ __launch_bounds__(512) void k_pqv(
    const bf16_t* __restrict__ Xb, const float* __restrict__ gamma1,
    const bf16_t* __restrict__ WmsgCT, const bf16_t* __restrict__ WvT,
    unsigned char* __restrict__ PV8, bf16_t* __restrict__ qmb,
    float* __restrict__ P0, float* __restrict__ Q0, int layer)
{
  __shared__ bf16_t ys16[32*136];
  __shared__ bf16_t pq16[32*136];
  int n = blockIdx.x, t = threadIdx.x;
  int wid = t >> 6, lane = t & 63;
  const float* g1 = gamma1 + layer*128;
  const bf16_t* xp = Xb + (size_t)n*3712;
  for (int k = wid; k < KM; k += 8){
    float x0 = (float)xp[k*128 + lane], x1 = (float)xp[k*128 + 64 + lane];
    float ss = wave_reduce_sum(x0*x0 + x1*x1);
    float sc = rsqrtf(ss*(1.0f/128.0f) + 1e-6f);
    ys16[k*136 + lane]      = (bf16_t)(x0*sc*g1[lane]);
    ys16[k*136 + 64 + lane] = (bf16_t)(x1*sc*g1[64+lane]);
  }
  for (int idx = t; idx < 3*136; idx += 512) ys16[29*136 + idx] = (bf16_t)0.f;
  __syncthreads();
  int mtile = wid >> 2;
  int row = mtile*16 + (lane & 15);
  int koff = (lane >> 4)*8;
  {
    const bf16_t* Bc = WmsgCT + (size_t)layer*16384;
    f32x4 acc[2] = {{0,0,0,0},{0,0,0,0}};
    #pragma unroll
    for (int kk = 0; kk < 128; kk += 32){
      bf16x8 a = *(const bf16x8*)(ys16 + row*136 + kk + koff);
      #pragma unroll
      for (int u = 0; u < 2; u++){
        int col = ((wid&3)*2+u)*16 + (lane & 15);
        bf16x8 b = *(const bf16x8*)(Bc + (size_t)col*128 + kk + koff);
        acc[u] = mfma16(a, b, acc[u]);
      }
    }
    #pragma unroll
    for (int u = 0; u < 2; u++){
      int col = ((wid&3)*2+u)*16 + (lane & 15);
      #pragma unroll
      for (int r = 0; r < 4; r++){
        int r32 = mtile*16 + (lane>>4)*4 + r;
        pq16[r32*136 + col] = (bf16_t)acc[u][r];
      }
      if (mtile == 0 && (lane>>4) == 0){
        float v = acc[u][0];
        if (col < 64) P0[(size_t)n*64 + col] = v;
        else          Q0[(size_t)n*64 + col - 64] = v;
      }
    }
  }
  __syncthreads();
  {
    const bf16_t* Bt = WvT + (size_t)layer*8192;
    f32x4 acc[2] = {{0,0,0,0},{0,0,0,0}};
    #pragma unroll
    for (int kk = 0; kk < 64; kk += 32){
      bf16x8 a = *(const bf16x8*)(pq16 + row*136 + kk + koff);
      #pragma unroll
      for (int u = 0; u < 2; u++){
        int col = ((wid&3)*2+u)*16 + (lane & 15);
        bf16x8 b = *(const bf16x8*)(Bt + (size_t)col*64 + kk + koff);
        acc[u] = mfma16(a, b, acc[u]);
      }
    }
    unsigned char* pvp = PV8 + (size_t)n*4096;
    int r0i = mtile*16 + (lane>>4)*4;
    #pragma unroll
    for (int u = 0; u < 2; u++){
      int col = ((wid&3)*2+u)*16 + (lane & 15);
      float pk[4];
      #pragma unroll
      for (int r = 0; r < 4; r++){
        int r32 = r0i + r;
        pk[r] = (r32 < KM) ? acc[u][r] : 0.f;
      }
      int dw = __builtin_amdgcn_cvt_pk_fp8_f32(pk[0], pk[1], 0, false);
      dw = __builtin_amdgcn_cvt_pk_fp8_f32(pk[2], pk[3], dw, true);
      *(unsigned int*)(pvp + col*32 + r0i) = (unsigned int)dw;
    }
  }
  for (int idx = t; idx < KM*64; idx += 512){
    int k = idx >> 6, j = idx & 63;
    qmb[(size_t)n*1856 + idx] = pq16[k*136 + 64 + j];
  }
}

// ---------------- per-layer: edge logits + gate (MFMA) ----------------
__global__ __launch_bounds__(256) void k_edge_logits(
    const int* __restrict__ EI, const float* __restrict__ ed,
    const float* __restrict__ P0, const float* __restrict__ Q0,
    const float* __restrict__ radtab, const bf16_t* __restrict__ WapT, const float* __restrict__ wa,
    const bf16_t* __restrict__ WgT, float* __restrict__ logi, bf16_t* __restrict__ gate16,
    int E, int layer)
{
  __shared__ bf16_t m0s[16*72];
  __shared__ int   srcs[16], tgts[16];
  __shared__ float r0s[16];
  int t = threadIdx.x;
  int eb = blockIdx.x*16;
  if (t < 16){
    int e = eb + t;
    if (e < E){
      srcs[t] = EI[e]; tgts[t] = EI[E+e];
      float d = ed[e];
      float u = d * ((GTAB-1)/12.0f);
      int j = (int)u; if (j > GTAB-2) j = GTAB-2;
      float f = u - (float)j;
      float a = radtab[(size_t)j*28 + layer*7], b = radtab[(size_t)(j+1)*28 + layer*7];
      r0s[t] = a + f*(b-a);
    } else { srcs[t] = 0; tgts[t] = 0; r0s[t] = 0.f; }
  }
  __syncthreads();
  #pragma unroll
  for (int u = 0; u < 4; u++){
    int idx = t + u*256;
    int i = idx >> 6, j = idx & 63;
    m0s[i*72 + j] = (bf16_t)((P0[(size_t)srcs[i]*64 + j] + Q0[(size_t)tgts[i]*64 + j]) * r0s[i]);
  }
  __syncthreads();
  int wid = t >> 6, lane = t & 63;
  int l15 = lane & 15, lg = lane >> 4;
  int koff = lg*8;
  bf16x8 a0 = *(const bf16x8*)(m0s + l15*72 + koff);
  bf16x8 a1 = *(const bf16x8*)(m0s + l15*72 + 32 + koff);
  const bf16_t* Ba = WapT + (size_t)layer*16384;
  const bf16_t* Bg = WgT  + (size_t)layer*8192;
  const float* wav = wa + layer*256;
  f32x4 accA[4], accG[2];
  #pragma unroll
  for (int u = 0; u < 4; u++){
    int col = 64*wid + u*16 + l15;
    f32x4 acc = {0,0,0,0};
    acc = mfma16(a0, *(const bf16x8*)(Ba + (size_t)col*64 + koff), acc);
    acc = mfma16(a1, *(const bf16x8*)(Ba + (size_t)col*64 + 32 + koff), acc);
    accA[u] = acc;
  }
  #pragma unroll
  for (int u = 0; u < 2; u++){
    int col = 32*wid + u*16 + l15;
    f32x4 acc = {0,0,0,0};
    acc = mfma16(a0, *(const bf16x8*)(Bg + (size_t)col*64 + koff), acc);
    acc = mfma16(a1, *(const bf16x8*)(Bg + (size_t)col*64 + 32 + koff), acc);
    accG[u] = acc;
  }
  #pragma unroll
  for (int u = 0; u < 2; u++){
    int col = 32*wid + u*16 + l15;
    #pragma unroll
    for (int r = 0; r < 4; r++){
      int e = eb + lg*4 + r;
      if (e < E) gate16[(size_t)e*128 + col] = (bf16_t)silu_f(accG[u][r]);
    }
  }
  #pragma unroll
  for (int hpair = 0; hpair < 2; hpair++){
    int c0 = 64*wid + hpair*32 + l15;
    float w0 = wav[c0], w1 = wav[c0+16];
    float s[4];
    #pragma unroll
    for (int r = 0; r < 4; r++)
      s[r] = silu_f(accA[2*hpair][r])*w0 + silu_f(accA[2*hpair+1][r])*w1;
    #pragma unroll
    for (int r = 0; r < 4; r++){
      s[r] += __shfl_xor(s[r], 1);
      s[r] += __shfl_xor(s[r], 2);
      s[r] += __shfl_xor(s[r], 4);
      s[r] += __shfl_xor(s[r], 8);
    }
    if (l15 == 0){
      #pragma unroll
      for (int r = 0; r < 4; r++){
        int e = eb + lg*4 + r;
        if (e < E) logi[(size_t)e*8 + 2*wid + hpair] = s[r];
      }
    }
  }
}

// fp8 dword -> 4 fp32 FMA into acc
#define FMA_DW(dw, kb) { \
  f32x2 lo_ = __builtin_amdgcn_cvt_pk_f32_fp8((dw), false); \
  f32x2 hi_ = __builtin_amdgcn_cvt_pk_f32_fp8((dw), true); \
  acc[(kb)]   += lo_.x * rw[LOF2((kb))]; \
  acc[(kb)+1] += lo_.y * rw[LOF2((kb)+1)]; \
  acc[(kb)+2] += hi_.x * rw[LOF2((kb)+2)]; \
  acc[(kb)+3] += hi_.y * rw[LOF2((kb)+3)]; }

// ---------------- fused per-layer: attn + FFN + next-layer pqv tail; x in LDS ----------------
__global__ __launch_bounds__(512, 4) void k_attn_ffn(
    const int* __restrict__ EI, const int* __restrict__ rowptr, const int* __restrict__ order,
    const float* __restrict__ ed, const bf16_t* __restrict__ qmb,
    const bf16_t* __restrict__ WvT, const bf16_t* __restrict__ WoT,
    const unsigned char* __restrict__ PV8, const bf16_t* __restrict__ gate16,
    const float* __restrict__ logi, const float* __restrict__ radtab,
    const float* __restrict__ gamma2, const float* __restrict__ Wfg,
    const bf16_t* __restrict__ Wf1T, const bf16_t* __restrict__ Wf2T,
    bf16_t* __restrict__ Xb, int layer,
    const float* __restrict__ gamma1, const bf16_t* __restrict__ WmsgCT,
    unsigned char* __restrict__ PV8o, bf16_t* __restrict__ qmbo,
    float* __restrict__ P0o, float* __restrict__ Q0o, int do_tail)
{
  __shared__ float  xs[3712];        // x residual, fp32, persistent
  __shared__ bf16_t ysag[32*136];    // attn: merge A + Wo input; ffn: ys; tail: ys-next
  __shared__ bf16_t hsqv[32*136];    // attn: qvs, merge B; ffn: hs; tail: pq-next
  __shared__ char   uA[4608];        // qm16 -> {at8, rl7, es, srcs} -> ffn gate partials
  __shared__ float  mh[8], iden[8];

  bf16_t* qm16 = (bf16_t*)uA;
  float*  at8  = (float*)uA;
  float*  rl7  = (float*)(uA + 2048);
  int*    es   = (int*)(uA + 4096);
  int*    srcs = (int*)(uA + 4352);
  float*  pf   = (float*)uA;

  int n = blockIdx.x, t = threadIdx.x;
  int wid = t >> 6, lane = t & 63;
  int rp = rowptr[n], deg = rowptr[n+1] - rp;

  // load x into LDS (bf16x2 vectorized)
  {
    const bf16x2* Xp2 = (const bf16x2*)(Xb + (size_t)n*3712);
    for (int p = t; p < 1856; p += 512){
      bf16x2 v = Xp2[p];
      xs[2*p]   = (float)v.x;
      xs[2*p+1] = (float)v.y;
    }
  }

  if (deg > 0){
    for (int idx = t; idx < KM*64; idx += 512){
      int k = idx >> 6, j = idx & 63;
      qm16[k*72 + j] = qmb[(size_t)n*1856 + idx];
    }
    for (int idx = t; idx < 3*72; idx += 512) qm16[29*72 + idx] = (bf16_t)0.f;
    // softmax stats (8 lanes per head)
    if (t < 64){
      int hh = t & 7, slot = t >> 3;
      float m = -3.0e38f;
      for (int idx = slot; idx < deg; idx += 8){
        int e = order[rp+idx];
        m = fmaxf(m, logi[(size_t)e*8 + hh]);
      }
      m = fmaxf(m, __shfl_xor(m, 8));
      m = fmaxf(m, __shfl_xor(m, 16));
      m = fmaxf(m, __shfl_xor(m, 32));
      float den = 0.f;
      for (int idx = slot; idx < deg; idx += 8){
        int e = order[rp+idx];
        den += env_f(ed[e]) * __expf(logi[(size_t)e*8 + hh] - m);
      }
      den += __shfl_xor(den, 8);
      den += __shfl_xor(den, 16);
      den += __shfl_xor(den, 32);
      if (t < 8){ mh[t] = m; iden[t] = 1.0f/(den + 1e-16f); }
    }
    __syncthreads();
    // QV GEMM: hsqv = qm16 @ WvT (K=64, 8 waves)
    {
      const bf16_t* Bt = WvT + (size_t)layer*8192;
      int mtile = wid >> 2, colt = (wid & 3)*2;
      int row = mtile*16 + (lane & 15);
      int koff = (lane >> 4)*8;
      f32x4 a2[2] = {{0,0,0,0},{0,0,0,0}};
      #pragma unroll
      for (int kk = 0; kk < 64; kk += 32){
        bf16x8 a = *(const bf16x8*)(qm16 + row*72 + kk + koff);
        #pragma unroll
        for (int u = 0; u < 2; u++){
          int col = (colt+u)*16 + (lane & 15);
          bf16x8 b = *(const bf16x8*)(Bt + (size_t)col*64 + kk + koff);
          a2[u] = mfma16(a, b, a2[u]);
        }
      }
      #pragma unroll
      for (int u = 0; u < 2; u++){
        int col = (colt+u)*16 + (lane & 15);
        #pragma unroll
        for (int r = 0; r < 4; r++){
          int r32 = mtile*16 + (lane>>4)*4 + r;
          hsqv[r32*136 + col] = (bf16_t)a2[u][r];
        }
      }
    }
    __syncthreads();
    // gather: eg x hv; fp8 PV, 3-deep prefetch
    int eg = t >> 7, hv = t & 127, h = hv >> 4;
    float acc[32];
    #pragma unroll
    for (int j = 0; j < 32; j++) acc[j] = 0.f;
    float S[7];
    #pragma unroll
    for (int l = 0; l < 7; l++) S[l] = 0.f;
    for (int base = 0; base < deg; base += 64){
      int ne = min(64, deg - base);
      if (t < ne){ int e = order[rp + base + t]; es[t] = e; srcs[t] = EI[e]; }
      __syncthreads();
      if (t < ne*8){
        int i = t >> 3, q = t & 7;
        int e = es[i];
        float d = ed[e];
        at8[t] = env_f(d) * __expf(logi[(size_t)e*8 + q] - mh[q]) * iden[q];
        if (q < 7){
          float u = d * ((GTAB-1)/12.0f);
          int j = (int)u; if (j > GTAB-2) j = GTAB-2;
          float f = u - (float)j;
          float a = radtab[(size_t)j*28 + layer*7 + q], b = radtab[(size_t)(j+1)*28 + layer*7 + q];
          rl7[t] = a + f*(b-a);
        }
      }
      __syncthreads();
      uint4 A0 = {0,0,0,0}, A1 = {0,0,0,0}, B0 = {0,0,0,0}, B1 = {0,0,0,0};
      float gA = 0.f, gB = 0.f;
      int i = eg;
      if (i < ne){
        const uint4* p = (const uint4*)(PV8 + (size_t)srcs[i]*4096 + hv*32);
        A0 = p[0]; A1 = p[1];
        gA = (float)gate16[(size_t)es[i]*128 + hv];
      }
      if (i + 4 < ne){
        const uint4* p = (const uint4*)(PV8 + (size_t)srcs[i+4]*4096 + hv*32);
        B0 = p[0]; B1 = p[1];
        gB = (float)gate16[(size_t)es[i+4]*128 + hv];
      }
      while (i < ne){
        int i2 = i + 8;
        uint4 C0 = {0,0,0,0}, C1 = {0,0,0,0}; float gC = 0.f;
        if (i2 < ne){
          const uint4* p = (const uint4*)(PV8 + (size_t)srcs[i2]*4096 + hv*32);
          C0 = p[0]; C1 = p[1];
          gC = (float)gate16[(size_t)es[i2]*128 + hv];
        }
        float w = gA * at8[i*8 + h];
        float rw[7];
        #pragma unroll
        for (int l = 0; l < 7; l++){ rw[l] = rl7[i*8 + l]*w; S[l] += rw[l]; }
        FMA_DW(A0.x, 0)  FMA_DW(A0.y, 4)  FMA_DW(A0.z, 8)  FMA_DW(A0.w, 12)
        FMA_DW(A1.x, 16) FMA_DW(A1.y, 20) FMA_DW(A1.z, 24) FMA_DW(A1.w, 28)
        A0 = B0; A1 = B1; gA = gB;
        B0 = C0; B1 = C1; gB = gC;
        i += 4;
      }
      __syncthreads();
    }
    #pragma unroll
    for (int j = 0; j < 32; j++)
      acc[j] += (float)hsqv[j*136 + hv] * S[LOF2(j)];
    __syncthreads();
    if (eg == 0){
      #pragma unroll
      for (int j = 0; j < 32; j++) ysag[j*136 + hv] = (bf16_t)acc[j];
    } else if (eg == 1){
      #pragma unroll
      for (int j = 0; j < 32; j++) hsqv[j*136 + hv] = (bf16_t)acc[j];
    }
    __syncthreads();
    if (eg == 2){
      #pragma unroll
      for (int j = 0; j < 32; j++) ysag[j*136 + hv] = (bf16_t)((float)ysag[j*136 + hv] + acc[j]);
    } else if (eg == 3){
      #pragma unroll
      for (int j = 0; j < 32; j++) hsqv[j*136 + hv] = (bf16_t)((float)hsqv[j*136 + hv] + acc[j]);
    }
    __syncthreads();
    for (int idx = t; idx < 32*128; idx += 512){
      int k = idx >> 7, c = idx & 127;
      ysag[k*136 + c] = (bf16_t)((float)ysag[k*136 + c] + (float)hsqv[k*136 + c]);
    }
    __syncthreads();
    // Wo GEMM: xs += ag @ WoT
    {
      const bf16_t* Bt = WoT + (size_t)layer*16384;
      int mtile = wid >> 2, colt = (wid & 3)*2;
      int row = mtile*16 + (lane & 15);
      int koff = (lane >> 4)*8;
      f32x4 a2[2] = {{0,0,0,0},{0,0,0,0}};
      #pragma unroll
      for (int kk = 0; kk < 128; kk += 32){
        bf16x8 a = *(const bf16x8*)(ysag + row*136 + kk + koff);
        #pragma unroll
        for (int u = 0; u < 2; u++){
          int col = (colt+u)*16 + (lane & 15);
          bf16x8 b = *(const bf16x8*)(Bt + (size_t)col*128 + kk + koff);
          a2[u] = mfma16(a, b, a2[u]);
        }
      }
      #pragma unroll
      for (int u = 0; u < 2; u++){
        int col = (colt+u)*16 + (lane & 15);
        #pragma unroll
        for (int r = 0; r < 4; r++){
          int r32 = mtile*16 + (lane>>4)*4 + r;
          if (r32 < KM) xs[r32*128 + col] += a2[u][r];
        }
      }
    }
  }
  __syncthreads();
  // ---------- FFN phase ----------
  const float* g2 = gamma2 + layer*128;
  for (int k = wid; k < KM; k += 8){
    float x0 = xs[k*128 + lane], x1 = xs[k*128 + 64 + lane];
    float ss = wave_reduce_sum(x0*x0 + x1*x1);
    float sc = rsqrtf(ss*(1.0f/128.0f) + 1e-6f);
    ysag[k*136 + lane]      = (bf16_t)(x0*sc*g2[lane]);
    ysag[k*136 + 64 + lane] = (bf16_t)(x1*sc*g2[64+lane]);
  }
  for (int idx = t; idx < 3*136; idx += 512) ysag[29*136 + idx] = (bf16_t)0.f;
  __syncthreads();
  {
    int part = t >> 7, f = t & 127;
    const float* Wfgp = Wfg + (size_t)layer*16384;
    float p = 0.f;
    for (int c = part*32; c < part*32 + 32; c++) p += (float)ysag[c] * Wfgp[c*128 + f];
    pf[part*128 + f] = p;
  }
  __syncthreads();
  if (t < 128) pf[512 + t] = silu_f(pf[t] + pf[128+t] + pf[256+t] + pf[384+t]);
  __syncthreads();
  {
    const bf16_t* Bt = Wf1T + (size_t)layer*16384;
    int mtile = wid >> 2, colt = (wid & 3)*2;
    int row = mtile*16 + (lane & 15);
    int koff = (lane >> 4)*8;
    f32x4 a2[2] = {{0,0,0,0},{0,0,0,0}};
    #pragma unroll
    for (int kk = 0; kk < 128; kk += 32){
      bf16x8 a = *(const bf16x8*)(ysag + row*136 + kk + koff);
      #pragma unroll
      for (int u = 0; u < 2; u++){
        int col = (colt+u)*16 + (lane & 15);
        bf16x8 b = *(const bf16x8*)(Bt + (size_t)col*128 + kk + koff);
        a2[u] = mfma16(a, b, a2[u]);
      }
    }
    #pragma unroll
    for (int u = 0; u < 2; u++){
      int col = (colt+u)*16 + (lane & 15);
      float gfc = pf[512 + col];
      #pragma unroll
      for (int r = 0; r < 4; r++){
        int r32 = mtile*16 + (lane>>4)*4 + r;
        hsqv[r32*136 + col] = (bf16_t)(a2[u][r]*gfc);
      }
    }
  }
  __syncthreads();
  {
    const bf16_t* Bt = Wf2T + (size_t)layer*16384;
    int mtile = wid >> 2, colt = (wid & 3)*2;
    int row = mtile*16 + (lane & 15);
    int koff = (lane >> 4)*8;
    f32x4 a2[2] = {{0,0,0,0},{0,0,0,0}};
    #pragma unroll
    for (int kk = 0; kk < 128; kk += 32){
      bf16x8 a = *(const bf16x8*)(hsqv + row*136 + kk + koff);
      #pragma unroll
      for (int u = 0; u < 2; u++){
        int col = (colt+u)*16 + (lane & 15);
        bf16x8 b = *(const bf16x8*)(Bt + (size_t)col*128 + kk + koff);
        a2[u] = mfma16(a, b, a2[u]);
      }
    }
    #pragma unroll
    for (int u = 0; u < 2; u++){
      int col = (colt+u)*16 + (lane & 15);
      #pragma unroll
      for (int r = 0; r < 4; r++){
        int r32 = mtile*16 + (lane>>4)*4 + r;
        if (r32 < KM) xs[r32*128 + col] += a2[u][r];
      }
    }
  }
  __syncthreads();
  // store x back (bf16x2 vectorized)
  {
    bf16x2* Xp2 = (bf16x2*)(Xb + (size_t)n*3712);
    for (int p = t; p < 1856; p += 512){
      bf16x2 v;
      v.x = (bf16_t)xs[2*p];
      v.y = (bf16_t)xs[2*p+1];
      Xp2[p] = v;
    }
  }
  // ---------- tail: next-layer pqv (node-local, from xs) ----------
  if (do_tail){
    const float* g1n = gamma1 + (size_t)(layer+1)*128;
    for (int k = wid; k < KM; k += 8){
      float x0 = xs[k*128 + lane], x1 = xs[k*128 + 64 + lane];
      float ss = wave_reduce_sum(x0*x0 + x1*x1);
      float sc = rsqrtf(ss*(1.0f/128.0f) + 1e-6f);
      ysag[k*136 + lane]      = (bf16_t)(x0*sc*g1n[lane]);
      ysag[k*136 + 64 + lane] = (bf16_t)(x1*sc*g1n[64+lane]);
    }
    // pads of ysag still zero from FFN phase
    __syncthreads();
    int mtile = wid >> 2;
    int row = mtile*16 + (lane & 15);
    int koff = (lane >> 4)*8;
    // GEMM-C next: pq = ys @ WmsgCT[layer+1]; into hsqv
    {
      const bf16_t* Bc = WmsgCT + (size_t)(layer+1)*16384;
      f32x4 acc[2] = {{0,0,0,0},{0,0,0,0}};
      #pragma unroll
      for (int kk = 0; kk < 128; kk += 32){
        bf16x8 a = *(const bf16x8*)(ysag + row*136 + kk + koff);
        #pragma unroll
        for (int u = 0; u < 2; u++){
          int col = ((wid&3)*2+u)*16 + (lane & 15);
          bf16x8 b = *(const bf16x8*)(Bc + (size_t)col*128 + kk + koff);
          acc[u] = mfma16(a, b, acc[u]);
        }
      }
      #pragma unroll
      for (int u = 0; u < 2; u++){
        int col = ((wid&3)*2+u)*16 + (lane & 15);
        #pragma unroll
        for (int r = 0; r < 4; r++){
          int r32 = mtile*16 + (lane>>4)*4 + r;
          hsqv[r32*136 + col] = (bf16_t)acc[u][r];
        }
        if (mtile == 0 && (lane>>4) == 0){
          float v = acc[u][0];
          if (col < 64) P0o[(size_t)n*64 + col] = v;
          else          Q0o[(size_t)n*64 + col - 64] = v;
        }
      }
    }
    __syncthreads();
    // PV GEMM next: pq[:,0:64] @ WvT[layer+1] -> PV8o fp8
    {
      const bf16_t* Bt = WvT + (size_t)(layer+1)*8192;
      f32x4 acc[2] = {{0,0,0,0},{0,0,0,0}};
      #pragma unroll
      for (int kk = 0; kk < 64; kk += 32){
        bf16x8 a = *(const bf16x8*)(hsqv + row*136 + kk + koff);
        #pragma unroll
        for (int u = 0; u < 2; u++){
          int col = ((wid&3)*2+u)*16 + (lane & 15);
          bf16x8 b = *(const bf16x8*)(Bt + (size_t)col*64 + kk + koff);
          acc[u] = mfma16(a, b, acc[u]);
        }
      }
      unsigned char* pvp = PV8o + (size_t)n*4096;
      int r0i = mtile*16 + (lane>>4)*4;
      #pragma unroll
      for (int u = 0; u < 2; u++){
        int col = ((wid&3)*2+u)*16 + (lane & 15);
        float pk[4];
        #pragma unroll
        for (int r = 0; r < 4; r++){
          int r32 = r0i + r;
          pk[r] = (r32 < KM) ? acc[u][r] : 0.f;
        }
        int dw = __builtin_amdgcn_cvt_pk_fp8_f32(pk[0], pk[1], 0, false);
        dw = __builtin_amdgcn_cvt_pk_fp8_f32(pk[2], pk[3], dw, true);
        *(unsigned int*)(pvp + col*32 + r0i) = (unsigned int)dw;
      }
    }
    // qm store next
    for (int idx = t; idx < KM*64; idx += 512){
      int k = idx >> 6, j = idx & 63;
      qmbo[(size_t)n*1856 + idx] = hsqv[k*136 + 64 + j];
    }
  }
}

// ---------------- output head ----------------
__global__ __launch_bounds__(256) void k_head(
    const bf16_t* __restrict__ Xb, const float* __restrict__ Wh1, const float* __restrict__ Wh2,
    float* __restrict__ partial, int N)
{
  __shared__ float wsum[4];
  int t = threadIdx.x;
  int half = t >> 7;
  int n = blockIdx.x*2 + half;
  int f = t & 127;
  float sv = 0.f;
  if (n < N){
    const bf16_t* xp = Xb + (size_t)n*3712;
    float acc = 0.f;
    for (int c = 0; c < 128; c++) acc += (float)xp[c]*Wh1[c*128 + f];
    sv = silu_f(acc)*Wh2[f];
  }
  sv = wave_reduce_sum(sv);
  if ((t & 63) == 0) wsum[t >> 6] = sv;
  __syncthreads();
  if (t == 0) partial[blockIdx.x] = wsum[0] + wsum[1] + wsum[2] + wsum[3];
}

__global__ __launch_bounds__(256) void k_reduce(const float* __restrict__ partial, float* __restrict__ out, int P){
  __shared__ float sh[256];
  int t = threadIdx.x;
  float s = 0.f;
  for (int i = t; i < P; i += 256) s += partial[i];
  sh[t] = s; __syncthreads();
  for (int off = 128; off > 0; off >>= 1){
    if (t < off) sh[t] += sh[t+off];
    __syncthreads();
  }
  if (t == 0) out[0] = sh[0] / 77.81317f;
}

extern "C" void kernel_launch(void* const* d_in, const int* in_sizes, int n_in,
                              void* d_out, int out_size, void* d_ws, size_t ws_size,
                              hipStream_t stream)
{
  const int*   Z      = (const int*)d_in[0];
  const int*   EI     = (const int*)d_in[1];
  const float* ed     = (const float*)d_in[2];
  const float* emb    = (const float*)d_in[3];
  const float* We0    = (const float*)d_in[4];
  const float* be0    = (const float*)d_in[5];
  const float* We1    = (const float*)d_in[6];
  const float* be1    = (const float*)d_in[7];
  const float* Weproj = (const float*)d_in[8];
  const float* gamma1 = (const float*)d_in[9];
  const float* gamma2 = (const float*)d_in[10];
  const float* Wr0    = (const float*)d_in[11];
  const float* Wr1    = (const float*)d_in[12];
  const float* Wrl    = (const float*)d_in[13];
  const float* Wmsg   = (const float*)d_in[14];
  const float* Wap    = (const float*)d_in[15];
  const float* wa     = (const float*)d_in[16];
  const float* Wg     = (const float*)d_in[17];
  const float* Wv     = (const float*)d_in[18];
  const float* Wo     = (const float*)d_in[19];
  const float* Wf1    = (const float*)d_in[20];
  const float* Wfg    = (const float*)d_in[21];
  const float* Wf2    = (const float*)d_in[22];
  const float* Wh1    = (const float*)d_in[23];
  const float* Wh2    = (const float*)d_in[24];

  const int N = in_sizes[0];
  const int E = in_sizes[2];

  float* ws = (float*)d_ws;
  size_t o = 0;
  auto alloc = [&](size_t nf){ float* p = ws + o; o += (nf + 7) & ~(size_t)7; return p; };

  bf16_t* Xb    = (bf16_t*)alloc((size_t)N*1856);      // N*3712 bf16
  float* P0     = alloc((size_t)N*128);                 // 2 x N*64 (ping-pong)
  float* Q0     = alloc((size_t)N*128);
  float* logi   = alloc((size_t)E*8);
  float* part   = alloc((size_t)((N+1)/2) + 8);
  float* radtab = alloc((size_t)GTAB*28);
  bf16_t* qmb   = (bf16_t*)alloc((size_t)N*1856);      // 2 x N*1856 bf16; h2tab aliases buf0
  float* h2tab  = (float*)qmb;                          // GTAB*128 f32 = 1MB; disjoint lifetime
  unsigned char* PV8 = (unsigned char*)alloc((size_t)N*2048);  // 2 x N*4096 fp8
  bf16_t* gate16= (bf16_t*)alloc((size_t)E*64);        // E*128 bf16; h2e aliases pre-layers
  bf16_t* arena = (bf16_t*)alloc(434176);              // 868352 bf16
  int* rowptr = (int*)alloc((size_t)N+8);
  int* curs   = (int*)alloc((size_t)N);
  int* order  = (int*)alloc((size_t)E);
  // total ~182 MB for N=6000, E=120000

  bf16_t* WmsgCT  = arena;            // [4][128][128]
  bf16_t* WvT     = arena + 65536;    // [4][128][64]
  bf16_t* WoT     = arena + 98304;    // [4][128][128]
  bf16_t* Wf1T    = arena + 163840;   // [4][128][128]
  bf16_t* Wf2T    = arena + 229376;   // [4][128][128]
  bf16_t* WapT    = arena + 294912;   // [4][256][64]
  bf16_t* WgT     = arena + 360448;   // [4][128][64]
  bf16_t* WeprojT = arena + 393216;   // [3712][128]

  bf16_t* h2e = gate16;   // alias: dead before layer-0 logits writes gate16

  // CSR by target
  hipMemsetAsync(curs, 0, sizeof(int)*N, stream);
  k_count<<<(E+255)/256, 256, 0, stream>>>(EI, curs, E);
  k_scan<<<1, 1024, 0, stream>>>(curs, rowptr, N);
  k_fill<<<(E+255)/256, 256, 0, stream>>>(EI, curs, order, E);
  k_sort<<<(N+255)/256, 256, 0, stream>>>(rowptr, order, N);

  // weight transposes -> bf16 arenas
  k_tr2<<<256, 256, 0, stream>>>(Wmsg, WmsgCT);
  k_tr<<<128, 256, 0, stream>>>(Wv,   WvT,  4, 64, 128, 8192);
  k_tr<<<256, 256, 0, stream>>>(Wo,   WoT,  4, 128, 128, 16384);
  k_tr<<<256, 256, 0, stream>>>(Wf1,  Wf1T, 4, 128, 128, 16384);
  k_tr<<<256, 256, 0, stream>>>(Wf2,  Wf2T, 4, 128, 128, 16384);
  k_tr<<<256, 256, 0, stream>>>(Wap,  WapT, 4, 64, 256, 16384);
  k_tr<<<128, 256, 0, stream>>>(Wg,   WgT,  4, 64, 128, 8192);
  k_tr<<<1856, 256, 0, stream>>>(Weproj, WeprojT, 1, 128, 3712, 0);

  // radial tables + per-edge h2 + x init
  k_tab_embed<<<GTAB/4, 256, 0, stream>>>(We0, be0, We1, be1, Wr0, Wr1, Wrl, h2tab, radtab);
  k_h2e<<<(E*128+255)/256, 256, 0, stream>>>(ed, h2tab, h2e, E);
  k_init_x<<<(N+31)/32, 256, 0, stream>>>(Z, emb, WeprojT, h2e, rowptr, order, Xb, N);

  // layer-0 pqv (subsequent layers' pqv fused into k_attn_ffn tail)
  k_pqv<<<N, 512, 0, stream>>>(Xb, gamma1, WmsgCT, WvT, PV8, qmb, P0, Q0, 0);

  for (int i = 0; i < 4; i++){
    int cur = i & 1, nxt = (i+1) & 1;
    unsigned char* PV8i = PV8 + (size_t)cur*N*4096;
    unsigned char* PV8o = PV8 + (size_t)nxt*N*4096;
    bf16_t* qmbi = qmb + (size_t)cur*N*1856;
    bf16_t* qmbo = qmb + (size_t)nxt*N*1856;
    float* P0i = P0 + (size_t)cur*N*64, *P0o = P0 + (size_t)nxt*N*64;
    float* Q0i = Q0 + (size_t)cur*N*64, *Q0o = Q0 + (size_t)nxt*N*64;
    k_edge_logits<<<(E+15)/16, 256, 0, stream>>>(EI, ed, P0i, Q0i, radtab, WapT, wa, WgT, logi, gate16, E, i);
    k_attn_ffn<<<N, 512, 0, stream>>>(EI, rowptr, order, ed, qmbi, WvT, WoT, PV8i, gate16,
                                      logi, radtab, gamma2, Wfg, Wf1T, Wf2T, Xb, i,
                                      gamma1, WmsgCT, PV8o, qmbo, P0o, Q0o, (i < 3) ? 1 : 0);
  }

  int PB = (N+1)/2;
  k_head<<<PB, 256, 0, stream>>>(Xb, Wh1, Wh2, part, N);
  k_reduce<<<1, 256, 0, stream>>>(part, (float*)d_out, PB);
}

// Round 9
// 2210.862 us; speedup vs baseline: 1.4955x; 1.0584x over previous
//
#include <hip/hip_runtime.h>

#define KM 29
#define GTAB 2048

typedef __bf16 bf16_t;
typedef __bf16 bf16x8 __attribute__((ext_vector_type(8)));
typedef __bf16 bf16x4 __attribute__((ext_vector_type(4)));
typedef __bf16 bf16x2 __attribute__((ext_vector_type(2)));
typedef float  f32x4  __attribute__((ext_vector_type(4)));
typedef float  f32x2  __attribute__((ext_vector_type(2)));

__device__ __forceinline__ float silu_f(float x){ return x / (1.0f + __expf(-x)); }

__device__ __forceinline__ float wave_reduce_sum(float v){
  #pragma unroll
  for (int s = 1; s < 64; s <<= 1) v += __shfl_xor(v, s);
  return v;
}

// l-of-k with clamp for pad rows 29..31 (their data is zero)
__device__ __forceinline__ constexpr int LOF2(int k){
  return (k<1)?0 : (k<4)?1 : (k<9)?2 : (k<14)?3 : (k<19)?4 : (k<24)?5 : 6;
}

__device__ __forceinline__ f32x4 mfma16(bf16x8 a, bf16x8 b, f32x4 c){
  return __builtin_amdgcn_mfma_f32_16x16x32_bf16(a, b, c, 0, 0, 0);
}

__device__ __forceinline__ float env_f(float d){
  float xx = d*(1.0f/12.0f);
  float x2 = xx*xx, x4 = x2*x2, x5 = x4*xx;
  float env = 1.0f - 21.0f*x5 + 35.0f*x5*xx - 15.0f*x5*x2;
  return (xx < 1.0f) ? env : 0.0f;
}

// ---------------- CSR build ----------------
__global__ void k_count(const int* __restrict__ EI, int* __restrict__ cnt, int E){
  int e = blockIdx.x*256 + threadIdx.x;
  if (e < E) atomicAdd(&cnt[EI[E+e]], 1);
}

__global__ __launch_bounds__(1024) void k_scan(int* __restrict__ cnt, int* __restrict__ rowptr, int N){
  __shared__ int ts[1024];
  int t = threadIdx.x;
  int base = t*8;
  int loc[8]; int sum = 0;
  #pragma unroll
  for (int u = 0; u < 8; u++){ int idx = base+u; int v = (idx < N) ? cnt[idx] : 0; loc[u] = sum; sum += v; }
  ts[t] = sum; __syncthreads();
  for (int off = 1; off < 1024; off <<= 1){
    int v = (t >= off) ? ts[t-off] : 0;
    __syncthreads();
    ts[t] += v;
    __syncthreads();
  }
  int excl = ts[t] - sum;
  #pragma unroll
  for (int u = 0; u < 8; u++){
    int idx = base+u;
    if (idx < N){ int r = excl + loc[u]; rowptr[idx] = r; cnt[idx] = r; }
  }
  if (t == 1023) rowptr[N] = ts[1023];
}

__global__ void k_fill(const int* __restrict__ EI, int* __restrict__ cur, int* __restrict__ order, int E){
  int e = blockIdx.x*256 + threadIdx.x;
  if (e < E){ int pos = atomicAdd(&cur[EI[E+e]], 1); order[pos] = e; }
}

__global__ void k_sort(const int* __restrict__ rowptr, int* __restrict__ order, int N){
  int n = blockIdx.x*256 + threadIdx.x;
  if (n >= N) return;
  int rp = rowptr[n], re = rowptr[n+1];
  for (int a = rp+1; a < re; a++){
    int key = order[a]; int b = a-1;
    while (b >= rp && order[b] > key){ order[b+1] = order[b]; b--; }
    order[b+1] = key;
  }
}

// ---------------- weight transposes ----------------
__global__ void k_tr(const float* __restrict__ src, bf16_t* __restrict__ dst,
                     int L, int R, int C, int Lstr){
  int idx = blockIdx.x*256 + threadIdx.x;
  int total = L*R*C;
  if (idx >= total) return;
  int l = idx / (R*C); int rem = idx - l*(R*C);
  int r = rem / C; int c = rem - r*C;
  dst[((size_t)l*C + c)*R + r] = (bf16_t)src[(size_t)l*Lstr + (size_t)r*C + c];
}

// Wmsg [4][256][64] -> combined [4][128 cols][128 k]; col<64 = P-half, col>=64 = Q-half
__global__ void k_tr2(const float* __restrict__ src, bf16_t* __restrict__ dst){
  int idx = blockIdx.x*256 + threadIdx.x;
  if (idx >= 4*128*128) return;
  int l = idx >> 14; int j = (idx >> 7) & 127; int c = idx & 127;
  float v = (j < 64) ? src[(size_t)l*16384 + c*64 + j]
                     : src[(size_t)l*16384 + 8192 + c*64 + (j-64)];
  dst[idx] = (bf16_t)v;
}

// ---------------- radial MLP table build ----------------
__global__ __launch_bounds__(256) void k_tab_embed(
    const float* __restrict__ We0, const float* __restrict__ be0,
    const float* __restrict__ We1, const float* __restrict__ be1,
    const float* __restrict__ Wr0, const float* __restrict__ Wr1, const float* __restrict__ Wrl,
    float* __restrict__ h2tab, float* __restrict__ radtab)
{
  __shared__ float sb[4][640];
  const int wid = threadIdx.x >> 6, lane = threadIdx.x & 63;
  const int e = blockIdx.x*4 + wid;
  if (e >= GTAB) return;
  const float d = e * (12.0f/(GTAB-1));
  const float DLT = 12.0f/599.0f;
  const float CO  = -0.5f/((2.0f*DLT)*(2.0f*DLT));
  int jc = (int)(d/DLT + 0.5f);
  int j0 = jc - 16; if (j0 < 0) j0 = 0; if (j0 > 600-32) j0 = 600-32;
  float diff = d - (float)(j0+lane)*DLT;
  float gval = __expf(CO*diff*diff);
  float p[10];
  #pragma unroll
  for (int u = 0; u < 10; u++) p[u] = 0.f;
  const int c2 = 2*lane;
  for (int jj = 0; jj < 32; jj++){
    float gj = __shfl(gval, jj);
    int row = j0 + jj;
    const float2 w0 = *(const float2*)(We0 + row*128 + c2);
    p[0] += gj*w0.x; p[1] += gj*w0.y;
    #pragma unroll
    for (int i = 0; i < 4; i++){
      const float2 wr = *(const float2*)(Wr0 + ((size_t)i*600 + row)*128 + c2);
      p[2+2*i] += gj*wr.x; p[3+2*i] += gj*wr.y;
    }
  }
  sb[wid][c2]   = silu_f(p[0] + be0[c2]);
  sb[wid][c2+1] = silu_f(p[1] + be0[c2+1]);
  #pragma unroll
  for (int i = 0; i < 4; i++){
    sb[wid][128 + 128*i + c2]   = silu_f(p[2+2*i]);
    sb[wid][128 + 128*i + c2+1] = silu_f(p[3+2*i]);
  }
  float a0 = 0.f, a1 = 0.f;
  for (int c = 0; c < 128; c++){
    float hv = sb[wid][c];
    const float2 w = *(const float2*)(We1 + c*128 + c2);
    a0 += hv*w.x; a1 += hv*w.y;
  }
  a0 = silu_f(a0 + be1[c2]); a1 = silu_f(a1 + be1[c2+1]);
  h2tab[(size_t)e*128 + c2]     = a0;
  h2tab[(size_t)e*128 + c2 + 1] = a1;
  #pragma unroll
  for (int i = 0; i < 4; i++){
    float r0 = 0.f, r1 = 0.f;
    const float* W1 = Wr1 + (size_t)i*128*128;
    for (int c = 0; c < 128; c++){
      float rv = sb[wid][128 + 128*i + c];
      const float2 w = *(const float2*)(W1 + c*128 + c2);
      r0 += rv*w.x; r1 += rv*w.y;
    }
    r0 = silu_f(r0); r1 = silu_f(r1);
    const float* Wl = Wrl + (size_t)i*128*7;
    float pl[7];
    #pragma unroll
    for (int l = 0; l < 7; l++) pl[l] = r0*Wl[c2*7+l] + r1*Wl[(c2+1)*7+l];
    #pragma unroll
    for (int l = 0; l < 7; l++) pl[l] = wave_reduce_sum(pl[l]);
    if (lane == 0){
      #pragma unroll
      for (int l = 0; l < 7; l++) radtab[(size_t)e*28 + i*7 + l] = pl[l];
    }
  }
}

// ---------------- per-edge h2 interp (edge-parallel) ----------------
__global__ void k_h2e(const float* __restrict__ ed, const float* __restrict__ h2tab,
                      bf16_t* __restrict__ h2e, int E){
  int idx = blockIdx.x*256 + threadIdx.x;
  if (idx >= E*128) return;
  int e = idx >> 7, ch = idx & 127;
  float d = ed[e];
  float u = d * ((GTAB-1)/12.0f);
  int j = (int)u; if (j > GTAB-2) j = GTAB-2;
  float f = u - (float)j;
  float a = h2tab[(size_t)j*128 + ch], b = h2tab[(size_t)(j+1)*128 + ch];
  h2e[idx] = (bf16_t)(a + f*(b-a));
}

// ---------------- per-node h2 sum (node*ch parallel) ----------------
__global__ __launch_bounds__(256) void k_h2sum(
    const bf16_t* __restrict__ h2e, const int* __restrict__ rowptr, const int* __restrict__ order,
    bf16_t* __restrict__ h2sum, int N)
{
  int n = blockIdx.x*2 + (threadIdx.x >> 7);
  int ch = threadIdx.x & 127;
  if (n >= N) return;
  int rp = rowptr[n], deg = rowptr[n+1] - rp;
  float acc = 0.f;
  for (int idx = 0; idx < deg; idx++){
    int e = order[rp+idx];
    acc += (float)h2e[(size_t)e*128 + ch];
  }
  h2sum[(size_t)n*128 + ch] = (bf16_t)acc;
}

// ---------------- x init (MFMA from h2sum) ----------------
__global__ __launch_bounds__(256) void k_init_x(
    const int* __restrict__ Z, const float* __restrict__ emb,
    const bf16_t* __restrict__ WeprojT, const bf16_t* __restrict__ h2sum,
    bf16_t* __restrict__ Xb, int N)
{
  __shared__ bf16_t h2s[32*136];
  __shared__ int Zs[32];
  int n0 = blockIdx.x*32, t = threadIdx.x;
  for (int idx = t; idx < 32*128; idx += 256){
    int nn = idx >> 7, ch = idx & 127;
    int n = n0 + nn;
    h2s[nn*136 + ch] = (n < N) ? h2sum[(size_t)n*128 + ch] : (bf16_t)0.f;
  }
  if (t < 32) Zs[t] = (n0 + t < N) ? Z[n0+t] : 0;
  __syncthreads();
  int wid = t >> 6, lane = t & 63;
  int mtile = wid & 1;
  int row = mtile*16 + (lane & 15);
  int koff = (lane >> 4)*8;
  bf16x8 afr[4];
  #pragma unroll
  for (int kk = 0; kk < 4; kk++) afr[kk] = *(const bf16x8*)(h2s + row*136 + kk*32 + koff);
  for (int nt = (wid>>1); nt < 232; nt += 2){
    f32x4 acc = {0.f,0.f,0.f,0.f};
    int col = nt*16 + (lane & 15);
    #pragma unroll
    for (int kk = 0; kk < 4; kk++){
      bf16x8 b = *(const bf16x8*)(WeprojT + (size_t)col*128 + kk*32 + koff);
      acc = mfma16(afr[kk], b, acc);
    }
    #pragma unroll
    for (int r = 0; r < 4; r++){
      int r32 = mtile*16 + (lane>>4)*4 + r;
      int n = n0 + r32;
      if (n < N){
        float v = acc[r] * (1.0f/23.395238876342773f);
        if (col < 128) v += emb[(size_t)Zs[r32]*128 + col];
        Xb[(size_t)n*3712 + col] = (bf16_t)v;
      }
    }
  }
}

// ---------------- layer-0 pqv: rms + combined [P|Q] GEMM + PV(fp8) + P0/Q0 ----------------
__global__ __launch_bounds__(512) void k_pqv(
    const bf16_t* __restrict__ Xb, const float* __restrict__ gamma1,
    const bf16_t* __restrict__ WmsgCT, const bf16_t* __restrict__ WvT,
    unsigned char* __restrict__ PV8,
    float* __restrict__ P0, float* __restrict__ Q0, int layer)
{
  __shared__ bf16_t ys16[32*136];
  __shared__ bf16_t pq16[32*136];
  int n = blockIdx.x, t = threadIdx.x;
  int wid = t >> 6, lane = t & 63;
  const float* g1 = gamma1 + layer*128;
  const bf16_t* xp = Xb + (size_t)n*3712;
  for (int k = wid; k < KM; k += 8){
    float x0 = (float)xp[k*128 + lane], x1 = (float)xp[k*128 + 64 + lane];
    float ss = wave_reduce_sum(x0*x0 + x1*x1);
    float sc = rsqrtf(ss*(1.0f/128.0f) + 1e-6f);
    ys16[k*136 + lane]      = (bf16_t)(x0*sc*g1[lane]);
    ys16[k*136 + 64 + lane] = (bf16_t)(x1*sc*g1[64+lane]);
  }
  for (int idx = t; idx < 3*136; idx += 512) ys16[29*136 + idx] = (bf16_t)0.f;
  __syncthreads();
  int mtile = wid >> 2;
  int row = mtile*16 + (lane & 15);
  int koff = (lane >> 4)*8;
  {
    const bf16_t* Bc = WmsgCT + (size_t)layer*16384;
    f32x4 acc[2] = {{0,0,0,0},{0,0,0,0}};
    #pragma unroll
    for (int kk = 0; kk < 128; kk += 32){
      bf16x8 a = *(const bf16x8*)(ys16 + row*136 + kk + koff);
      #pragma unroll
      for (int u = 0; u < 2; u++){
        int col = ((wid&3)*2+u)*16 + (lane & 15);
        bf16x8 b = *(const bf16x8*)(Bc + (size_t)col*128 + kk + koff);
        acc[u] = mfma16(a, b, acc[u]);
      }
    }
    #pragma unroll
    for (int u = 0; u < 2; u++){
      int col = ((wid&3)*2+u)*16 + (lane & 15);
      #pragma unroll
      for (int r = 0; r < 4; r++){
        int r32 = mtile*16 + (lane>>4)*4 + r;
        pq16[r32*136 + col] = (bf16_t)acc[u][r];
      }
      if (mtile == 0 && (lane>>4) == 0){
        float v = acc[u][0];
        if (col < 64) P0[(size_t)n*64 + col] = v;
        else          Q0[(size_t)n*64 + col - 64] = v;
      }
    }
  }
  __syncthreads();
  {
    const bf16_t* Bt = WvT + (size_t)layer*8192;
    f32x4 acc[2] = {{0,0,0,0},{0,0,0,0}};
    #pragma unroll
    for (int kk = 0; kk < 64; kk += 32){
      bf16x8 a = *(const bf16x8*)(pq16 + row*136 + kk + koff);
      #pragma unroll
      for (int u = 0; u < 2; u++){
        int col = ((wid&3)*2+u)*16 + (lane & 15);
        bf16x8 b = *(const bf16x8*)(Bt + (size_t)col*64 + kk + koff);
        acc[u] = mfma16(a, b, acc[u]);
      }
    }
    unsigned char* pvp = PV8 + (size_t)n*4096;
    int r0i = mtile*16 + (lane>>4)*4;
    #pragma unroll
    for (int u = 0; u < 2; u++){
      int col = ((wid&3)*2+u)*16 + (lane & 15);
      float pk[4];
      #pragma unroll
      for (int r = 0; r < 4; r++){
        int r32 = r0i + r;
        pk[r] = (r32 < KM) ? acc[u][r] : 0.f;
      }
      int dw = __builtin_amdgcn_cvt_pk_fp8_f32(pk[0], pk[1], 0, false);
      dw = __builtin_amdgcn_cvt_pk_fp8_f32(pk[2], pk[3], dw, true);
      *(unsigned int*)(pvp + col*32 + r0i) = (unsigned int)dw;
    }
  }
}

// ---------------- per-layer: edge logits + gate (MFMA) ----------------
__global__ __launch_bounds__(256) void k_edge_logits(
    const int* __restrict__ EI, const float* __restrict__ ed,
    const float* __restrict__ P0, const float* __restrict__ Q0,
    const float* __restrict__ radtab, const bf16_t* __restrict__ WapT, const float* __restrict__ wa,
    const bf16_t* __restrict__ WgT, float* __restrict__ logi, bf16_t* __restrict__ gate16,
    int E, int layer)
{
  __shared__ bf16_t m0s[16*72];
  __shared__ int   srcs[16], tgts[16];
  __shared__ float r0s[16];
  int t = threadIdx.x;
  int eb = blockIdx.x*16;
  if (t < 16){
    int e = eb + t;
    if (e < E){
      srcs[t] = EI[e]; tgts[t] = EI[E+e];
      float d = ed[e];
      float u = d * ((GTAB-1)/12.0f);
      int j = (int)u; if (j > GTAB-2) j = GTAB-2;
      float f = u - (float)j;
      float a = radtab[(size_t)j*28 + layer*7], b = radtab[(size_t)(j+1)*28 + layer*7];
      r0s[t] = a + f*(b-a);
    } else { srcs[t] = 0; tgts[t] = 0; r0s[t] = 0.f; }
  }
  __syncthreads();
  #pragma unroll
  for (int u = 0; u < 4; u++){
    int idx = t + u*256;
    int i = idx >> 6, j = idx & 63;
    m0s[i*72 + j] = (bf16_t)((P0[(size_t)srcs[i]*64 + j] + Q0[(size_t)tgts[i]*64 + j]) * r0s[i]);
  }
  __syncthreads();
  int wid = t >> 6, lane = t & 63;
  int l15 = lane & 15, lg = lane >> 4;
  int koff = lg*8;
  bf16x8 a0 = *(const bf16x8*)(m0s + l15*72 + koff);
  bf16x8 a1 = *(const bf16x8*)(m0s + l15*72 + 32 + koff);
  const bf16_t* Ba = WapT + (size_t)layer*16384;
  const bf16_t* Bg = WgT  + (size_t)layer*8192;
  const float* wav = wa + layer*256;
  f32x4 accA[4], accG[2];
  #pragma unroll
  for (int u = 0; u < 4; u++){
    int col = 64*wid + u*16 + l15;
    f32x4 acc = {0,0,0,0};
    acc = mfma16(a0, *(const bf16x8*)(Ba + (size_t)col*64 + koff), acc);
    acc = mfma16(a1, *(const bf16x8*)(Ba + (size_t)col*64 + 32 + koff), acc);
    accA[u] = acc;
  }
  #pragma unroll
  for (int u = 0; u < 2; u++){
    int col = 32*wid + u*16 + l15;
    f32x4 acc = {0,0,0,0};
    acc = mfma16(a0, *(const bf16x8*)(Bg + (size_t)col*64 + koff), acc);
    acc = mfma16(a1, *(const bf16x8*)(Bg + (size_t)col*64 + 32 + koff), acc);
    accG[u] = acc;
  }
  #pragma unroll
  for (int u = 0; u < 2; u++){
    int col = 32*wid + u*16 + l15;
    #pragma unroll
    for (int r = 0; r < 4; r++){
      int e = eb + lg*4 + r;
      if (e < E) gate16[(size_t)e*128 + col] = (bf16_t)silu_f(accG[u][r]);
    }
  }
  #pragma unroll
  for (int hpair = 0; hpair < 2; hpair++){
    int c0 = 64*wid + hpair*32 + l15;
    float w0 = wav[c0], w1 = wav[c0+16];
    float s[4];
    #pragma unroll
    for (int r = 0; r < 4; r++)
      s[r] = silu_f(accA[2*hpair][r])*w0 + silu_f(accA[2*hpair+1][r])*w1;
    #pragma unroll
    for (int r = 0; r < 4; r++){
      s[r] += __shfl_xor(s[r], 1);
      s[r] += __shfl_xor(s[r], 2);
      s[r] += __shfl_xor(s[r], 4);
      s[r] += __shfl_xor(s[r], 8);
    }
    if (l15 == 0){
      #pragma unroll
      for (int r = 0; r < 4; r++){
        int e = eb + lg*4 + r;
        if (e < E) logi[(size_t)e*8 + 2*wid + hpair] = s[r];
      }
    }
  }
}

// fp8 dword -> 4 fp32 FMA into acc
#define FMA_DW(dw, kb) { \
  f32x2 lo_ = __builtin_amdgcn_cvt_pk_f32_fp8((dw), false); \
  f32x2 hi_ = __builtin_amdgcn_cvt_pk_f32_fp8((dw), true); \
  acc[(kb)]   += lo_.x * rw[LOF2((kb))]; \
  acc[(kb)+1] += lo_.y * rw[LOF2((kb)+1)]; \
  acc[(kb)+2] += hi_.x * rw[LOF2((kb)+2)]; \
  acc[(kb)+3] += hi_.y * rw[LOF2((kb)+3)]; }

// ---------------- fused per-layer: attn (deferred-norm) + FFN + next-layer pqv tail ----------------
__global__ __launch_bounds__(512, 4) void k_attn_ffn(
    const int* __restrict__ EI, const int* __restrict__ rowptr, const int* __restrict__ order,
    const float* __restrict__ ed,
    const bf16_t* __restrict__ WvT, const bf16_t* __restrict__ WoT,
    const unsigned char* __restrict__ PV8, const bf16_t* __restrict__ gate16,
    const float* __restrict__ logi, const float* __restrict__ radtab,
    const float* __restrict__ gamma1, const float* __restrict__ gamma2,
    const float* __restrict__ Wfg,
    const bf16_t* __restrict__ Wf1T, const bf16_t* __restrict__ Wf2T,
    const bf16_t* __restrict__ WmsgCT,
    bf16_t* __restrict__ Xb, int layer,
    unsigned char* __restrict__ PV8o, float* __restrict__ P0o, float* __restrict__ Q0o,
    int do_tail)
{
  __shared__ float  xs[3712];        // x residual, fp32, persistent
  __shared__ bf16_t ysag[32*136];    // ys1 -> merge A + Wo input; ffn: ys; tail: ys-next
  __shared__ bf16_t hsqv[32*136];    // qvs, merge B; ffn: hs; tail: pq-next
  __shared__ char   uA[4608];        // qm16 -> {at8, rl7} -> ffn gate partials
  __shared__ int    esb[64], srcs[64];
  __shared__ float  denl[32];

  bf16_t* qm16 = (bf16_t*)uA;
  float*  at8  = (float*)uA;
  float*  rl7  = (float*)(uA + 2048);
  float*  pf   = (float*)uA;

  int n = blockIdx.x, t = threadIdx.x;
  int wid = t >> 6, lane = t & 63;
  int rp = rowptr[n], deg = rowptr[n+1] - rp;

  // P0: load x into LDS + prefetch chunk-0 edge metadata
  {
    const bf16x2* Xp2 = (const bf16x2*)(Xb + (size_t)n*3712);
    for (int p = t; p < 1856; p += 512){
      bf16x2 v = Xp2[p];
      xs[2*p]   = (float)v.x;
      xs[2*p+1] = (float)v.y;
    }
  }
  {
    int m0 = (deg < 64) ? deg : 64;
    if (t < m0){ int e = order[rp + t]; esb[t] = e; srcs[t] = EI[e]; }
  }
  __syncthreads();

  if (deg > 0){
    // P1: ys1 = rms(xs)*gamma1[layer] -> ysag
    {
      const float* g1 = gamma1 + layer*128;
      for (int k = wid; k < KM; k += 8){
        float x0 = xs[k*128 + lane], x1 = xs[k*128 + 64 + lane];
        float ss = wave_reduce_sum(x0*x0 + x1*x1);
        float sc = rsqrtf(ss*(1.0f/128.0f) + 1e-6f);
        ysag[k*136 + lane]      = (bf16_t)(x0*sc*g1[lane]);
        ysag[k*136 + 64 + lane] = (bf16_t)(x1*sc*g1[64+lane]);
      }
      for (int idx = t; idx < 3*136; idx += 512) ysag[29*136 + idx] = (bf16_t)0.f;
    }
    __syncthreads();
    // P2: qm16 = ys1 @ WmsgCT[layer] cols 64..127 (32x64, K=128, 8 waves x 1 tile)
    {
      const bf16_t* Bc = WmsgCT + (size_t)layer*16384 + (size_t)64*128;
      int mtile = wid >> 2;
      int col = (wid & 3)*16 + (lane & 15);
      int row = mtile*16 + (lane & 15);
      int koff = (lane >> 4)*8;
      f32x4 a2 = {0,0,0,0};
      #pragma unroll
      for (int kk = 0; kk < 128; kk += 32){
        bf16x8 a = *(const bf16x8*)(ysag + row*136 + kk + koff);
        bf16x8 b = *(const bf16x8*)(Bc + (size_t)col*128 + kk + koff);
        a2 = mfma16(a, b, a2);
      }
      #pragma unroll
      for (int r = 0; r < 4; r++){
        int r32 = mtile*16 + (lane>>4)*4 + r;
        qm16[r32*72 + col] = (bf16_t)a2[r];
      }
    }
    __syncthreads();
    // P3: QV GEMM: hsqv = qm16 @ WvT (K=64, 8 waves)
    {
      const bf16_t* Bt = WvT + (size_t)layer*8192;
      int mtile = wid >> 2, colt = (wid & 3)*2;
      int row = mtile*16 + (lane & 15);
      int koff = (lane >> 4)*8;
      f32x4 a2[2] = {{0,0,0,0},{0,0,0,0}};
      #pragma unroll
      for (int kk = 0; kk < 64; kk += 32){
        bf16x8 a = *(const bf16x8*)(qm16 + row*72 + kk + koff);
        #pragma unroll
        for (int u = 0; u < 2; u++){
          int col = (colt+u)*16 + (lane & 15);
          bf16x8 b = *(const bf16x8*)(Bt + (size_t)col*64 + kk + koff);
          a2[u] = mfma16(a, b, a2[u]);
        }
      }
      #pragma unroll
      for (int u = 0; u < 2; u++){
        int col = (colt+u)*16 + (lane & 15);
        #pragma unroll
        for (int r = 0; r < 4; r++){
          int r32 = mtile*16 + (lane>>4)*4 + r;
          hsqv[r32*136 + col] = (bf16_t)a2[u][r];
        }
      }
    }
    __syncthreads();   // qm dead -> uA reused by at8/rl7
    // P4: gather chunks; UNNORMALIZED weights env*exp(logit); per-(eg,h) den partials
    int eg = t >> 7, hv = t & 127, h = hv >> 4;
    float acc[32];
    #pragma unroll
    for (int j = 0; j < 32; j++) acc[j] = 0.f;
    float S[7];
    #pragma unroll
    for (int l = 0; l < 7; l++) S[l] = 0.f;
    float dpart = 0.f;
    for (int base = 0; base < deg; base += 64){
      int ne = min(64, deg - base);
      if (base > 0){
        __syncthreads();   // prev gather done before metadata/at8 overwrite
        if (t < ne){ int e = order[rp + base + t]; esb[t] = e; srcs[t] = EI[e]; }
        __syncthreads();
      }
      if (t < ne*8){
        int i = t >> 3, q = t & 7;
        int e = esb[i];
        float d = ed[e];
        at8[t] = env_f(d) * __expf(logi[(size_t)e*8 + q]);   // unnormalized
        if (q < 7){
          float u = d * ((GTAB-1)/12.0f);
          int j = (int)u; if (j > GTAB-2) j = GTAB-2;
          float f = u - (float)j;
          float a = radtab[(size_t)j*28 + layer*7 + q], b = radtab[(size_t)(j+1)*28 + layer*7 + q];
          rl7[t] = a + f*(b-a);
        }
      }
      __syncthreads();
      uint4 A0 = {0,0,0,0}, A1 = {0,0,0,0}, B0 = {0,0,0,0}, B1 = {0,0,0,0};
      float gA = 0.f, gB = 0.f;
      int i = eg;
      if (i < ne){
        const uint4* p = (const uint4*)(PV8 + (size_t)srcs[i]*4096 + hv*32);
        A0 = p[0]; A1 = p[1];
        gA = (float)gate16[(size_t)esb[i]*128 + hv];
      }
      if (i + 4 < ne){
        const uint4* p = (const uint4*)(PV8 + (size_t)srcs[i+4]*4096 + hv*32);
        B0 = p[0]; B1 = p[1];
        gB = (float)gate16[(size_t)esb[i+4]*128 + hv];
      }
      while (i < ne){
        int i2 = i + 8;
        uint4 C0 = {0,0,0,0}, C1 = {0,0,0,0}; float gC = 0.f;
        if (i2 < ne){
          const uint4* p = (const uint4*)(PV8 + (size_t)srcs[i2]*4096 + hv*32);
          C0 = p[0]; C1 = p[1];
          gC = (float)gate16[(size_t)esb[i2]*128 + hv];
        }
        float ae = at8[i*8 + h];
        dpart += ae;
        float w = gA * ae;
        float rw[7];
        #pragma unroll
        for (int l = 0; l < 7; l++){ rw[l] = rl7[i*8 + l]*w; S[l] += rw[l]; }
        FMA_DW(A0.x, 0)  FMA_DW(A0.y, 4)  FMA_DW(A0.z, 8)  FMA_DW(A0.w, 12)
        FMA_DW(A1.x, 16) FMA_DW(A1.y, 20) FMA_DW(A1.z, 24) FMA_DW(A1.w, 28)
        A0 = B0; A1 = B1; gA = gB;
        B0 = C0; B1 = C1; gB = gC;
        i += 4;
      }
    }
    // P5: QV*S (unnormalized), den merge, normalize
    #pragma unroll
    for (int j = 0; j < 32; j++)
      acc[j] += (float)hsqv[j*136 + hv] * S[LOF2(j)];
    if ((hv & 15) == 0) denl[eg*8 + h] = dpart;
    __syncthreads();   // qvs reads done + denl visible
    {
      float dsum = denl[h] + denl[8 + h] + denl[16 + h] + denl[24 + h];
      float inv = 1.0f/(dsum + 1e-30f);
      #pragma unroll
      for (int j = 0; j < 32; j++) acc[j] *= inv;
    }
    // bf16 merge: g0->ysag, g1->hsqv; g2+=ysag, g3+=hsqv; combine
    if (eg == 0){
      #pragma unroll
      for (int j = 0; j < 32; j++) ysag[j*136 + hv] = (bf16_t)acc[j];
    } else if (eg == 1){
      #pragma unroll
      for (int j = 0; j < 32; j++) hsqv[j*136 + hv] = (bf16_t)acc[j];
    }
    __syncthreads();
    if (eg == 2){
      #pragma unroll
      for (int j = 0; j < 32; j++) ysag[j*136 + hv] = (bf16_t)((float)ysag[j*136 + hv] + acc[j]);
    } else if (eg == 3){
      #pragma unroll
      for (int j = 0; j < 32; j++) hsqv[j*136 + hv] = (bf16_t)((float)hsqv[j*136 + hv] + acc[j]);
    }
    __syncthreads();
    for (int idx = t; idx < 32*128; idx += 512){
      int k = idx >> 7, c = idx & 127;
      ysag[k*136 + c] = (bf16_t)((float)ysag[k*136 + c] + (float)hsqv[k*136 + c]);
    }
    __syncthreads();
    // Wo GEMM: xs += ag @ WoT (K=128, 8 waves)
    {
      const bf16_t* Bt = WoT + (size_t)layer*16384;
      int mtile = wid >> 2, colt = (wid & 3)*2;
      int row = mtile*16 + (lane & 15);
      int koff = (lane >> 4)*8;
      f32x4 a2[2] = {{0,0,0,0},{0,0,0,0}};
      #pragma unroll
      for (int kk = 0; kk < 128; kk += 32){
        bf16x8 a = *(const bf16x8*)(ysag + row*136 + kk + koff);
        #pragma unroll
        for (int u = 0; u < 2; u++){
          int col = (colt+u)*16 + (lane & 15);
          bf16x8 b = *(const bf16x8*)(Bt + (size_t)col*128 + kk + koff);
          a2[u] = mfma16(a, b, a2[u]);
        }
      }
      #pragma unroll
      for (int u = 0; u < 2; u++){
        int col = (colt+u)*16 + (lane & 15);
        #pragma unroll
        for (int r = 0; r < 4; r++){
          int r32 = mtile*16 + (lane>>4)*4 + r;
          if (r32 < KM) xs[r32*128 + col] += a2[u][r];
        }
      }
    }
  }
  __syncthreads();
  // ---------- FFN phase ----------
  const float* g2 = gamma2 + layer*128;
  for (int k = wid; k < KM; k += 8){
    float x0 = xs[k*128 + lane], x1 = xs[k*128 + 64 + lane];
    float ss = wave_reduce_sum(x0*x0 + x1*x1);
    float sc = rsqrtf(ss*(1.0f/128.0f) + 1e-6f);
    ysag[k*136 + lane]      = (bf16_t)(x0*sc*g2[lane]);
    ysag[k*136 + 64 + lane] = (bf16_t)(x1*sc*g2[64+lane]);
  }
  for (int idx = t; idx < 3*136; idx += 512) ysag[29*136 + idx] = (bf16_t)0.f;
  __syncthreads();
  {
    int part = t >> 7, f = t & 127;
    const float* Wfgp = Wfg + (size_t)layer*16384;
    float p = 0.f;
    for (int c = part*32; c < part*32 + 32; c++) p += (float)ysag[c] * Wfgp[c*128 + f];
    pf[part*128 + f] = p;
  }
  __syncthreads();
  if (t < 128) pf[512 + t] = silu_f(pf[t] + pf[128+t] + pf[256+t] + pf[384+t]);
  __syncthreads();
  {
    const bf16_t* Bt = Wf1T + (size_t)layer*16384;
    int mtile = wid >> 2, colt = (wid & 3)*2;
    int row = mtile*16 + (lane & 15);
    int koff = (lane >> 4)*8;
    f32x4 a2[2] = {{0,0,0,0},{0,0,0,0}};
    #pragma unroll
    for (int kk = 0; kk < 128; kk += 32){
      bf16x8 a = *(const bf16x8*)(ysag + row*136 + kk + koff);
      #pragma unroll
      for (int u = 0; u < 2; u++){
        int col = (colt+u)*16 + (lane & 15);
        bf16x8 b = *(const bf16x8*)(Bt + (size_t)col*128 + kk + koff);
        a2[u] = mfma16(a, b, a2[u]);
      }
    }
    #pragma unroll
    for (int u = 0; u < 2; u++){
      int col = (colt+u)*16 + (lane & 15);
      float gfc = pf[512 + col];
      #pragma unroll
      for (int r = 0; r < 4; r++){
        int r32 = mtile*16 + (lane>>4)*4 + r;
        hsqv[r32*136 + col] = (bf16_t)(a2[u][r]*gfc);
      }
    }
  }
  __syncthreads();
  {
    const bf16_t* Bt = Wf2T + (size_t)layer*16384;
    int mtile = wid >> 2, colt = (wid & 3)*2;
    int row = mtile*16 + (lane & 15);
    int koff = (lane >> 4)*8;
    f32x4 a2[2] = {{0,0,0,0},{0,0,0,0}};
    #pragma unroll
    for (int kk = 0; kk < 128; kk += 32){
      bf16x8 a = *(const bf16x8*)(hsqv + row*136 + kk + koff);
      #pragma unroll
      for (int u = 0; u < 2; u++){
        int col = (colt+u)*16 + (lane & 15);
        bf16x8 b = *(const bf16x8*)(Bt + (size_t)col*128 + kk + koff);
        a2[u] = mfma16(a, b, a2[u]);
      }
    }
    #pragma unroll
    for (int u = 0; u < 2; u++){
      int col = (colt+u)*16 + (lane & 15);
      #pragma unroll
      for (int r = 0; r < 4; r++){
        int r32 = mtile*16 + (lane>>4)*4 + r;
        if (r32 < KM) xs[r32*128 + col] += a2[u][r];
      }
    }
  }
  __syncthreads();
  // store x back (bf16x2 vectorized)
  {
    bf16x2* Xp2 = (bf16x2*)(Xb + (size_t)n*3712);
    for (int p = t; p < 1856; p += 512){
      bf16x2 v;
      v.x = (bf16_t)xs[2*p];
      v.y = (bf16_t)xs[2*p+1];
      Xp2[p] = v;
    }
  }
  // ---------- tail: next-layer pqv (PV8o + P0o/Q0o only; qm recomputed next layer) ----------
  if (do_tail){
    const float* g1n = gamma1 + (size_t)(layer+1)*128;
    for (int k = wid; k < KM; k += 8){
      float x0 = xs[k*128 + lane], x1 = xs[k*128 + 64 + lane];
      float ss = wave_reduce_sum(x0*x0 + x1*x1);
      float sc = rsqrtf(ss*(1.0f/128.0f) + 1e-6f);
      ysag[k*136 + lane]      = (bf16_t)(x0*sc*g1n[lane]);
      ysag[k*136 + 64 + lane] = (bf16_t)(x1*sc*g1n[64+lane]);
    }
    // pads of ysag still zero from FFN phase
    __syncthreads();
    int mtile = wid >> 2;
    int row = mtile*16 + (lane & 15);
    int koff = (lane >> 4)*8;
    // GEMM-C next: pq = ys @ WmsgCT[layer+1]; into hsqv; P0o/Q0o from row 0
    {
      const bf16_t* Bc = WmsgCT + (size_t)(layer+1)*16384;
      f32x4 acc[2] = {{0,0,0,0},{0,0,0,0}};
      #pragma unroll
      for (int kk = 0; kk < 128; kk += 32){
        bf16x8 a = *(const bf16x8*)(ysag + row*136 + kk + koff);
        #pragma unroll
        for (int u = 0; u < 2; u++){
          int col = ((wid&3)*2+u)*16 + (lane & 15);
          bf16x8 b = *(const bf16x8*)(Bc + (size_t)col*128 + kk + koff);
          acc[u] = mfma16(a, b, acc[u]);
        }
      }
      #pragma unroll
      for (int u = 0; u < 2; u++){
        int col = ((wid&3)*2+u)*16 + (lane & 15);
        #pragma unroll
        for (int r = 0; r < 4; r++){
          int r32 = mtile*16 + (lane>>4)*4 + r;
          hsqv[r32*136 + col] = (bf16_t)acc[u][r];
        }
        if (mtile == 0 && (lane>>4) == 0){
          float v = acc[u][0];
          if (col < 64) P0o[(size_t)n*64 + col] = v;
          else          Q0o[(size_t)n*64 + col - 64] = v;
        }
      }
    }
    __syncthreads();
    // PV GEMM next: pq[:,0:64] @ WvT[layer+1] -> PV8o fp8
    {
      const bf16_t* Bt = WvT + (size_t)(layer+1)*8192;
      f32x4 acc[2] = {{0,0,0,0},{0,0,0,0}};
      #pragma unroll
      for (int kk = 0; kk < 64; kk += 32){
        bf16x8 a = *(const bf16x8*)(hsqv + row*136 + kk + koff);
        #pragma unroll
        for (int u = 0; u < 2; u++){
          int col = ((wid&3)*2+u)*16 + (lane & 15);
          bf16x8 b = *(const bf16x8*)(Bt + (size_t)col*64 + kk + koff);
          acc[u] = mfma16(a, b, acc[u]);
        }
      }
      unsigned char* pvp = PV8o + (size_t)n*4096;
      int r0i = mtile*16 + (lane>>4)*4;
      #pragma unroll
      for (int u = 0; u < 2; u++){
        int col = ((wid&3)*2+u)*16 + (lane & 15);
        float pk[4];
        #pragma unroll
        for (int r = 0; r < 4; r++){
          int r32 = r0i + r;
          pk[r] = (r32 < KM) ? acc[u][r] : 0.f;
        }
        int dw = __builtin_amdgcn_cvt_pk_fp8_f32(pk[0], pk[1], 0, false);
        dw = __builtin_amdgcn_cvt_pk_fp8_f32(pk[2], pk[3], dw, true);
        *(unsigned int*)(pvp + col*32 + r0i) = (unsigned int)dw;
      }
    }
  }
}

// ---------------- output head ----------------
__global__ __launch_bounds__(256) void k_head(
    const bf16_t* __restrict__ Xb, const float* __restrict__ Wh1, const float* __restrict__ Wh2,
    float* __restrict__ partial, int N)
{
  __shared__ float wsum[4];
  int t = threadIdx.x;
  int half = t >> 7;
  int n = blockIdx.x*2 + half;
  int f = t & 127;
  float sv = 0.f;
  if (n < N){
    const bf16_t* xp = Xb + (size_t)n*3712;
    float acc = 0.f;
    for (int c = 0; c < 128; c++) acc += (float)xp[c]*Wh1[c*128 + f];
    sv = silu_f(acc)*Wh2[f];
  }
  sv = wave_reduce_sum(sv);
  if ((t & 63) == 0) wsum[t >> 6] = sv;
  __syncthreads();
  if (t == 0) partial[blockIdx.x] = wsum[0] + wsum[1] + wsum[2] + wsum[3];
}

__global__ __launch_bounds__(256) void k_reduce(const float* __restrict__ partial, float* __restrict__ out, int P){
  __shared__ float sh[256];
  int t = threadIdx.x;
  float s = 0.f;
  for (int i = t; i < P; i += 256) s += partial[i];
  sh[t] = s; __syncthreads();
  for (int off = 128; off > 0; off >>= 1){
    if (t < off) sh[t] += sh[t+off];
    __syncthreads();
  }
  if (t == 0) out[0] = sh[0] / 77.81317f;
}

extern "C" void kernel_launch(void* const* d_in, const int* in_sizes, int n_in,
                              void* d_out, int out_size, void* d_ws, size_t ws_size,
                              hipStream_t stream)
{
  const int*   Z      = (const int*)d_in[0];
  const int*   EI     = (const int*)d_in[1];
  const float* ed     = (const float*)d_in[2];
  const float* emb    = (const float*)d_in[3];
  const float* We0    = (const float*)d_in[4];
  const float* be0    = (const float*)d_in[5];
  const float* We1    = (const float*)d_in[6];
  const float* be1    = (const float*)d_in[7];
  const float* Weproj = (const float*)d_in[8];
  const float* gamma1 = (const float*)d_in[9];
  const float* gamma2 = (const float*)d_in[10];
  const float* Wr0    = (const float*)d_in[11];
  const float* Wr1    = (const float*)d_in[12];
  const float* Wrl    = (const float*)d_in[13];
  const float* Wmsg   = (const float*)d_in[14];
  const float* Wap    = (const float*)d_in[15];
  const float* wa     = (const float*)d_in[16];
  const float* Wg     = (const float*)d_in[17];
  const float* Wv     = (const float*)d_in[18];
  const float* Wo     = (const float*)d_in[19];
  const float* Wf1    = (const float*)d_in[20];
  const float* Wfg    = (const float*)d_in[21];
  const float* Wf2    = (const float*)d_in[22];
  const float* Wh1    = (const float*)d_in[23];
  const float* Wh2    = (const float*)d_in[24];

  const int N = in_sizes[0];
  const int E = in_sizes[2];

  float* ws = (float*)d_ws;
  size_t o = 0;
  auto alloc = [&](size_t nf){ float* p = ws + o; o += (nf + 7) & ~(size_t)7; return p; };

  bf16_t* Xb    = (bf16_t*)alloc((size_t)N*1856);      // N*3712 bf16
  float* P0     = alloc((size_t)N*128);                 // 2 x N*64 (ping-pong)
  float* Q0     = alloc((size_t)N*128);
  float* logi   = alloc((size_t)E*8);
  float* part   = alloc((size_t)((N+1)/2) + 8);
  float* radtab = alloc((size_t)GTAB*28);
  float* h2tab  = alloc((size_t)GTAB*128);
  bf16_t* h2sum = (bf16_t*)alloc((size_t)N*64);        // N*128 bf16
  unsigned char* PV8 = (unsigned char*)alloc((size_t)N*2048);  // 2 x N*4096 fp8
  bf16_t* gate16= (bf16_t*)alloc((size_t)E*64);        // E*128 bf16; h2e aliases pre-layers
  bf16_t* arena = (bf16_t*)alloc(434176);              // 868352 bf16
  int* rowptr = (int*)alloc((size_t)N+8);
  int* curs   = (int*)alloc((size_t)N);
  int* order  = (int*)alloc((size_t)E);
  // total ~138 MB for N=6000, E=120000

  bf16_t* WmsgCT  = arena;            // [4][128][128]
  bf16_t* WvT     = arena + 65536;    // [4][128][64]
  bf16_t* WoT     = arena + 98304;    // [4][128][128]
  bf16_t* Wf1T    = arena + 163840;   // [4][128][128]
  bf16_t* Wf2T    = arena + 229376;   // [4][128][128]
  bf16_t* WapT    = arena + 294912;   // [4][256][64]
  bf16_t* WgT     = arena + 360448;   // [4][128][64]
  bf16_t* WeprojT = arena + 393216;   // [3712][128]

  bf16_t* h2e = gate16;   // alias: dead before layer-0 logits writes gate16

  // CSR by target
  hipMemsetAsync(curs, 0, sizeof(int)*N, stream);
  k_count<<<(E+255)/256, 256, 0, stream>>>(EI, curs, E);
  k_scan<<<1, 1024, 0, stream>>>(curs, rowptr, N);
  k_fill<<<(E+255)/256, 256, 0, stream>>>(EI, curs, order, E);
  k_sort<<<(N+255)/256, 256, 0, stream>>>(rowptr, order, N);

  // weight transposes -> bf16 arenas
  k_tr2<<<256, 256, 0, stream>>>(Wmsg, WmsgCT);
  k_tr<<<128, 256, 0, stream>>>(Wv,   WvT,  4, 64, 128, 8192);
  k_tr<<<256, 256, 0, stream>>>(Wo,   WoT,  4, 128, 128, 16384);
  k_tr<<<256, 256, 0, stream>>>(Wf1,  Wf1T, 4, 128, 128, 16384);
  k_tr<<<256, 256, 0, stream>>>(Wf2,  Wf2T, 4, 128, 128, 16384);
  k_tr<<<256, 256, 0, stream>>>(Wap,  WapT, 4, 64, 256, 16384);
  k_tr<<<128, 256, 0, stream>>>(Wg,   WgT,  4, 64, 128, 8192);
  k_tr<<<1856, 256, 0, stream>>>(Weproj, WeprojT, 1, 128, 3712, 0);

  // radial tables + per-edge h2 + per-node h2 sum + x init
  k_tab_embed<<<GTAB/4, 256, 0, stream>>>(We0, be0, We1, be1, Wr0, Wr1, Wrl, h2tab, radtab);
  k_h2e<<<(E*128+255)/256, 256, 0, stream>>>(ed, h2tab, h2e, E);
  k_h2sum<<<(N+1)/2, 256, 0, stream>>>(h2e, rowptr, order, h2sum, N);
  k_init_x<<<(N+31)/32, 256, 0, stream>>>(Z, emb, WeprojT, h2sum, Xb, N);

  // layer-0 pqv (subsequent layers' pqv fused into k_attn_ffn tail)
  k_pqv<<<N, 512, 0, stream>>>(Xb, gamma1, WmsgCT, WvT, PV8, P0, Q0, 0);

  for (int i = 0; i < 4; i++){
    int cur = i & 1, nxt = (i+1) & 1;
    unsigned char* PV8i = PV8 + (size_t)cur*N*4096;
    unsigned char* PV8o = PV8 + (size_t)nxt*N*4096;
    float* P0i = P0 + (size_t)cur*N*64, *P0o = P0 + (size_t)nxt*N*64;
    float* Q0i = Q0 + (size_t)cur*N*64, *Q0o = Q0 + (size_t)nxt*N*64;
    k_edge_logits<<<(E+15)/16, 256, 0, stream>>>(EI, ed, P0i, Q0i, radtab, WapT, wa, WgT, logi, gate16, E, i);
    k_attn_ffn<<<N, 512, 0, stream>>>(EI, rowptr, order, ed, WvT, WoT, PV8i, gate16,
                                      logi, radtab, gamma1, gamma2, Wfg, Wf1T, Wf2T, WmsgCT,
                                      Xb, i, PV8o, P0o, Q0o, (i < 3) ? 1 : 0);
  }

  int PB = (N+1)/2;
  k_head<<<PB, 256, 0, stream>>>(Xb, Wh1, Wh2, part, N);
  k_reduce<<<1, 256, 0, stream>>>(part, (float*)d_out, PB);
}

// Round 10
// 2078.165 us; speedup vs baseline: 1.5910x; 1.0639x over previous
//
#include <hip/hip_runtime.h>

#define KM 29
#define GTAB 2048

typedef __bf16 bf16_t;
typedef __bf16 bf16x8 __attribute__((ext_vector_type(8)));
typedef __bf16 bf16x4 __attribute__((ext_vector_type(4)));
typedef __bf16 bf16x2 __attribute__((ext_vector_type(2)));
typedef float  f32x4  __attribute__((ext_vector_type(4)));
typedef float  f32x2  __attribute__((ext_vector_type(2)));

__device__ __forceinline__ float silu_f(float x){ return x / (1.0f + __expf(-x)); }

__device__ __forceinline__ float wave_reduce_sum(float v){
  #pragma unroll
  for (int s = 1; s < 64; s <<= 1) v += __shfl_xor(v, s);
  return v;
}

// l-of-k with clamp for pad rows 29..31 (their data is zero)
__device__ __forceinline__ constexpr int LOF2(int k){
  return (k<1)?0 : (k<4)?1 : (k<9)?2 : (k<14)?3 : (k<19)?4 : (k<24)?5 : 6;
}

__device__ __forceinline__ f32x4 mfma16(bf16x8 a, bf16x8 b, f32x4 c){
  return __builtin_amdgcn_mfma_f32_16x16x32_bf16(a, b, c, 0, 0, 0);
}

__device__ __forceinline__ float env_f(float d){
  float xx = d*(1.0f/12.0f);
  float x2 = xx*xx, x4 = x2*x2, x5 = x4*xx;
  float env = 1.0f - 21.0f*x5 + 35.0f*x5*xx - 15.0f*x5*x2;
  return (xx < 1.0f) ? env : 0.0f;
}

// ---------------- CSR build ----------------
__global__ void k_count(const int* __restrict__ EI, int* __restrict__ cnt, int E){
  int e = blockIdx.x*256 + threadIdx.x;
  if (e < E) atomicAdd(&cnt[EI[E+e]], 1);
}

__global__ __launch_bounds__(1024) void k_scan(int* __restrict__ cnt, int* __restrict__ rowptr, int N){
  __shared__ int ts[1024];
  int t = threadIdx.x;
  int base = t*8;
  int loc[8]; int sum = 0;
  #pragma unroll
  for (int u = 0; u < 8; u++){ int idx = base+u; int v = (idx < N) ? cnt[idx] : 0; loc[u] = sum; sum += v; }
  ts[t] = sum; __syncthreads();
  for (int off = 1; off < 1024; off <<= 1){
    int v = (t >= off) ? ts[t-off] : 0;
    __syncthreads();
    ts[t] += v;
    __syncthreads();
  }
  int excl = ts[t] - sum;
  #pragma unroll
  for (int u = 0; u < 8; u++){
    int idx = base+u;
    if (idx < N){ int r = excl + loc[u]; rowptr[idx] = r; cnt[idx] = r; }
  }
  if (t == 1023) rowptr[N] = ts[1023];
}

__global__ void k_fill(const int* __restrict__ EI, int* __restrict__ cur, int* __restrict__ order, int E){
  int e = blockIdx.x*256 + threadIdx.x;
  if (e < E){ int pos = atomicAdd(&cur[EI[E+e]], 1); order[pos] = e; }
}

__global__ void k_sort(const int* __restrict__ rowptr, int* __restrict__ order, int N){
  int n = blockIdx.x*256 + threadIdx.x;
  if (n >= N) return;
  int rp = rowptr[n], re = rowptr[n+1];
  for (int a = rp+1; a < re; a++){
    int key = order[a]; int b = a-1;
    while (b >= rp && order[b] > key){ order[b+1] = order[b]; b--; }
    order[b+1] = key;
  }
}

// ---------------- weight transposes ----------------
__global__ void k_tr(const float* __restrict__ src, bf16_t* __restrict__ dst,
                     int L, int R, int C, int Lstr){
  int idx = blockIdx.x*256 + threadIdx.x;
  int total = L*R*C;
  if (idx >= total) return;
  int l = idx / (R*C); int rem = idx - l*(R*C);
  int r = rem / C; int c = rem - r*C;
  dst[((size_t)l*C + c)*R + r] = (bf16_t)src[(size_t)l*Lstr + (size_t)r*C + c];
}

// Wmsg [4][256][64] -> combined [4][128 cols][128 k]; col<64 = P-half, col>=64 = Q-half
__global__ void k_tr2(const float* __restrict__ src, bf16_t* __restrict__ dst){
  int idx = blockIdx.x*256 + threadIdx.x;
  if (idx >= 4*128*128) return;
  int l = idx >> 14; int j = (idx >> 7) & 127; int c = idx & 127;
  float v = (j < 64) ? src[(size_t)l*16384 + c*64 + j]
                     : src[(size_t)l*16384 + 8192 + c*64 + (j-64)];
  dst[idx] = (bf16_t)v;
}

// ---------------- radial MLP table build ----------------
__global__ __launch_bounds__(256) void k_tab_embed(
    const float* __restrict__ We0, const float* __restrict__ be0,
    const float* __restrict__ We1, const float* __restrict__ be1,
    const float* __restrict__ Wr0, const float* __restrict__ Wr1, const float* __restrict__ Wrl,
    float* __restrict__ h2tab, float* __restrict__ radtab)
{
  __shared__ float sb[4][640];
  const int wid = threadIdx.x >> 6, lane = threadIdx.x & 63;
  const int e = blockIdx.x*4 + wid;
  if (e >= GTAB) return;
  const float d = e * (12.0f/(GTAB-1));
  const float DLT = 12.0f/599.0f;
  const float CO  = -0.5f/((2.0f*DLT)*(2.0f*DLT));
  int jc = (int)(d/DLT + 0.5f);
  int j0 = jc - 16; if (j0 < 0) j0 = 0; if (j0 > 600-32) j0 = 600-32;
  float diff = d - (float)(j0+lane)*DLT;
  float gval = __expf(CO*diff*diff);
  float p[10];
  #pragma unroll
  for (int u = 0; u < 10; u++) p[u] = 0.f;
  const int c2 = 2*lane;
  for (int jj = 0; jj < 32; jj++){
    float gj = __shfl(gval, jj);
    int row = j0 + jj;
    const float2 w0 = *(const float2*)(We0 + row*128 + c2);
    p[0] += gj*w0.x; p[1] += gj*w0.y;
    #pragma unroll
    for (int i = 0; i < 4; i++){
      const float2 wr = *(const float2*)(Wr0 + ((size_t)i*600 + row)*128 + c2);
      p[2+2*i] += gj*wr.x; p[3+2*i] += gj*wr.y;
    }
  }
  sb[wid][c2]   = silu_f(p[0] + be0[c2]);
  sb[wid][c2+1] = silu_f(p[1] + be0[c2+1]);
  #pragma unroll
  for (int i = 0; i < 4; i++){
    sb[wid][128 + 128*i + c2]   = silu_f(p[2+2*i]);
    sb[wid][128 + 128*i + c2+1] = silu_f(p[3+2*i]);
  }
  float a0 = 0.f, a1 = 0.f;
  for (int c = 0; c < 128; c++){
    float hv = sb[wid][c];
    const float2 w = *(const float2*)(We1 + c*128 + c2);
    a0 += hv*w.x; a1 += hv*w.y;
  }
  a0 = silu_f(a0 + be1[c2]); a1 = silu_f(a1 + be1[c2+1]);
  h2tab[(size_t)e*128 + c2]     = a0;
  h2tab[(size_t)e*128 + c2 + 1] = a1;
  #pragma unroll
  for (int i = 0; i < 4; i++){
    float r0 = 0.f, r1 = 0.f;
    const float* W1 = Wr1 + (size_t)i*128*128;
    for (int c = 0; c < 128; c++){
      float rv = sb[wid][128 + 128*i + c];
      const float2 w = *(const float2*)(W1 + c*128 + c2);
      r0 += rv*w.x; r1 += rv*w.y;
    }
    r0 = silu_f(r0); r1 = silu_f(r1);
    const float* Wl = Wrl + (size_t)i*128*7;
    float pl[7];
    #pragma unroll
    for (int l = 0; l < 7; l++) pl[l] = r0*Wl[c2*7+l] + r1*Wl[(c2+1)*7+l];
    #pragma unroll
    for (int l = 0; l < 7; l++) pl[l] = wave_reduce_sum(pl[l]);
    if (lane == 0){
      #pragma unroll
      for (int l = 0; l < 7; l++) radtab[(size_t)e*28 + i*7 + l] = pl[l];
    }
  }
}

// ---------------- per-edge h2 interp (edge-parallel) ----------------
__global__ void k_h2e(const float* __restrict__ ed, const float* __restrict__ h2tab,
                      bf16_t* __restrict__ h2e, int E){
  int idx = blockIdx.x*256 + threadIdx.x;
  if (idx >= E*128) return;
  int e = idx >> 7, ch = idx & 127;
  float d = ed[e];
  float u = d * ((GTAB-1)/12.0f);
  int j = (int)u; if (j > GTAB-2) j = GTAB-2;
  float f = u - (float)j;
  float a = h2tab[(size_t)j*128 + ch], b = h2tab[(size_t)(j+1)*128 + ch];
  h2e[idx] = (bf16_t)(a + f*(b-a));
}

// ---------------- per-node h2 sum ----------------
__global__ __launch_bounds__(256) void k_h2sum(
    const bf16_t* __restrict__ h2e, const int* __restrict__ rowptr, const int* __restrict__ order,
    bf16_t* __restrict__ h2sum, int N)
{
  int n = blockIdx.x*2 + (threadIdx.x >> 7);
  int ch = threadIdx.x & 127;
  if (n >= N) return;
  int rp = rowptr[n], deg = rowptr[n+1] - rp;
  float acc = 0.f;
  for (int idx = 0; idx < deg; idx++){
    int e = order[rp+idx];
    acc += (float)h2e[(size_t)e*128 + ch];
  }
  h2sum[(size_t)n*128 + ch] = (bf16_t)acc;
}

// ---------------- x init (MFMA from h2sum) ----------------
__global__ __launch_bounds__(256) void k_init_x(
    const int* __restrict__ Z, const float* __restrict__ emb,
    const bf16_t* __restrict__ WeprojT, const bf16_t* __restrict__ h2sum,
    bf16_t* __restrict__ Xb, int N)
{
  __shared__ bf16_t h2s[32*136];
  __shared__ int Zs[32];
  int n0 = blockIdx.x*32, t = threadIdx.x;
  for (int idx = t; idx < 32*128; idx += 256){
    int nn = idx >> 7, ch = idx & 127;
    int n = n0 + nn;
    h2s[nn*136 + ch] = (n < N) ? h2sum[(size_t)n*128 + ch] : (bf16_t)0.f;
  }
  if (t < 32) Zs[t] = (n0 + t < N) ? Z[n0+t] : 0;
  __syncthreads();
  int wid = t >> 6, lane = t & 63;
  int mtile = wid & 1;
  int row = mtile*16 + (lane & 15);
  int koff = (lane >> 4)*8;
  bf16x8 afr[4];
  #pragma unroll
  for (int kk = 0; kk < 4; kk++) afr[kk] = *(const bf16x8*)(h2s + row*136 + kk*32 + koff);
  for (int nt = (wid>>1); nt < 232; nt += 2){
    f32x4 acc = {0.f,0.f,0.f,0.f};
    int col = nt*16 + (lane & 15);
    #pragma unroll
    for (int kk = 0; kk < 4; kk++){
      bf16x8 b = *(const bf16x8*)(WeprojT + (size_t)col*128 + kk*32 + koff);
      acc = mfma16(afr[kk], b, acc);
    }
    #pragma unroll
    for (int r = 0; r < 4; r++){
      int r32 = mtile*16 + (lane>>4)*4 + r;
      int n = n0 + r32;
      if (n < N){
        float v = acc[r] * (1.0f/23.395238876342773f);
        if (col < 128) v += emb[(size_t)Zs[r32]*128 + col];
        Xb[(size_t)n*3712 + col] = (bf16_t)v;
      }
    }
  }
}

// ---------------- layer-0 pqv: rms + combined [P|Q] GEMM + PV8/QV8 + P0/Q0 ----------------
__global__ __launch_bounds__(512) void k_pqv(
    const bf16_t* __restrict__ Xb, const float* __restrict__ gamma1,
    const bf16_t* __restrict__ WmsgCT, const bf16_t* __restrict__ WvT,
    unsigned char* __restrict__ PV8, unsigned char* __restrict__ QV8,
    float* __restrict__ P0, float* __restrict__ Q0, int layer)
{
  __shared__ bf16_t ys16[32*136];
  __shared__ bf16_t pq16[32*136];
  int n = blockIdx.x, t = threadIdx.x;
  int wid = t >> 6, lane = t & 63;
  const float* g1 = gamma1 + layer*128;
  const bf16_t* xp = Xb + (size_t)n*3712;
  for (int k = wid; k < KM; k += 8){
    float x0 = (float)xp[k*128 + lane], x1 = (float)xp[k*128 + 64 + lane];
    float ss = wave_reduce_sum(x0*x0 + x1*x1);
    float sc = rsqrtf(ss*(1.0f/128.0f) + 1e-6f);
    ys16[k*136 + lane]      = (bf16_t)(x0*sc*g1[lane]);
    ys16[k*136 + 64 + lane] = (bf16_t)(x1*sc*g1[64+lane]);
  }
  for (int idx = t; idx < 3*136; idx += 512) ys16[29*136 + idx] = (bf16_t)0.f;
  __syncthreads();
  int mtile = wid >> 2;
  int row = mtile*16 + (lane & 15);
  int koff = (lane >> 4)*8;
  {
    const bf16_t* Bc = WmsgCT + (size_t)layer*16384;
    f32x4 acc[2] = {{0,0,0,0},{0,0,0,0}};
    #pragma unroll
    for (int kk = 0; kk < 128; kk += 32){
      bf16x8 a = *(const bf16x8*)(ys16 + row*136 + kk + koff);
      #pragma unroll
      for (int u = 0; u < 2; u++){
        int col = ((wid&3)*2+u)*16 + (lane & 15);
        bf16x8 b = *(const bf16x8*)(Bc + (size_t)col*128 + kk + koff);
        acc[u] = mfma16(a, b, acc[u]);
      }
    }
    #pragma unroll
    for (int u = 0; u < 2; u++){
      int col = ((wid&3)*2+u)*16 + (lane & 15);
      #pragma unroll
      for (int r = 0; r < 4; r++){
        int r32 = mtile*16 + (lane>>4)*4 + r;
        pq16[r32*136 + col] = (bf16_t)acc[u][r];
      }
      if (mtile == 0 && (lane>>4) == 0){
        float v = acc[u][0];
        if (col < 64) P0[(size_t)n*64 + col] = v;
        else          Q0[(size_t)n*64 + col - 64] = v;
      }
    }
  }
  __syncthreads();
  // PV GEMM: pq[:,0:64] @ WvT -> PV8
  {
    const bf16_t* Bt = WvT + (size_t)layer*8192;
    f32x4 acc[2] = {{0,0,0,0},{0,0,0,0}};
    #pragma unroll
    for (int kk = 0; kk < 64; kk += 32){
      bf16x8 a = *(const bf16x8*)(pq16 + row*136 + kk + koff);
      #pragma unroll
      for (int u = 0; u < 2; u++){
        int col = ((wid&3)*2+u)*16 + (lane & 15);
        bf16x8 b = *(const bf16x8*)(Bt + (size_t)col*64 + kk + koff);
        acc[u] = mfma16(a, b, acc[u]);
      }
    }
    unsigned char* pvp = PV8 + (size_t)n*4096;
    int r0i = mtile*16 + (lane>>4)*4;
    #pragma unroll
    for (int u = 0; u < 2; u++){
      int col = ((wid&3)*2+u)*16 + (lane & 15);
      float pk[4];
      #pragma unroll
      for (int r = 0; r < 4; r++){
        int r32 = r0i + r;
        pk[r] = (r32 < KM) ? acc[u][r] : 0.f;
      }
      int dw = __builtin_amdgcn_cvt_pk_fp8_f32(pk[0], pk[1], 0, false);
      dw = __builtin_amdgcn_cvt_pk_fp8_f32(pk[2], pk[3], dw, true);
      *(unsigned int*)(pvp + col*32 + r0i) = (unsigned int)dw;
    }
  }
  // QV GEMM: pq[:,64:128] @ WvT -> QV8
  {
    const bf16_t* Bt = WvT + (size_t)layer*8192;
    f32x4 acc[2] = {{0,0,0,0},{0,0,0,0}};
    #pragma unroll
    for (int kk = 0; kk < 64; kk += 32){
      bf16x8 a = *(const bf16x8*)(pq16 + row*136 + 64 + kk + koff);
      #pragma unroll
      for (int u = 0; u < 2; u++){
        int col = ((wid&3)*2+u)*16 + (lane & 15);
        bf16x8 b = *(const bf16x8*)(Bt + (size_t)col*64 + kk + koff);
        acc[u] = mfma16(a, b, acc[u]);
      }
    }
    unsigned char* qvp = QV8 + (size_t)n*4096;
    int r0i = mtile*16 + (lane>>4)*4;
    #pragma unroll
    for (int u = 0; u < 2; u++){
      int col = ((wid&3)*2+u)*16 + (lane & 15);
      float pk[4];
      #pragma unroll
      for (int r = 0; r < 4; r++){
        int r32 = r0i + r;
        pk[r] = (r32 < KM) ? acc[u][r] : 0.f;
      }
      int dw = __builtin_amdgcn_cvt_pk_fp8_f32(pk[0], pk[1], 0, false);
      dw = __builtin_amdgcn_cvt_pk_fp8_f32(pk[2], pk[3], dw, true);
      *(unsigned int*)(qvp + col*32 + r0i) = (unsigned int)dw;
    }
  }
}

// ---------------- per-layer: edge logits + gate (MFMA) ----------------
__global__ __launch_bounds__(256) void k_edge_logits(
    const int* __restrict__ EI, const float* __restrict__ ed,
    const float* __restrict__ P0, const float* __restrict__ Q0,
    const float* __restrict__ radtab, const bf16_t* __restrict__ WapT, const float* __restrict__ wa,
    const bf16_t* __restrict__ WgT, float* __restrict__ logi, bf16_t* __restrict__ gate16,
    int E, int layer)
{
  __shared__ bf16_t m0s[16*72];
  __shared__ int   srcs[16], tgts[16];
  __shared__ float r0s[16];
  int t = threadIdx.x;
  int eb = blockIdx.x*16;
  if (t < 16){
    int e = eb + t;
    if (e < E){
      srcs[t] = EI[e]; tgts[t] = EI[E+e];
      float d = ed[e];
      float u = d * ((GTAB-1)/12.0f);
      int j = (int)u; if (j > GTAB-2) j = GTAB-2;
      float f = u - (float)j;
      float a = radtab[(size_t)j*28 + layer*7], b = radtab[(size_t)(j+1)*28 + layer*7];
      r0s[t] = a + f*(b-a);
    } else { srcs[t] = 0; tgts[t] = 0; r0s[t] = 0.f; }
  }
  __syncthreads();
  #pragma unroll
  for (int u = 0; u < 4; u++){
    int idx = t + u*256;
    int i = idx >> 6, j = idx & 63;
    m0s[i*72 + j] = (bf16_t)((P0[(size_t)srcs[i]*64 + j] + Q0[(size_t)tgts[i]*64 + j]) * r0s[i]);
  }
  __syncthreads();
  int wid = t >> 6, lane = t & 63;
  int l15 = lane & 15, lg = lane >> 4;
  int koff = lg*8;
  bf16x8 a0 = *(const bf16x8*)(m0s + l15*72 + koff);
  bf16x8 a1 = *(const bf16x8*)(m0s + l15*72 + 32 + koff);
  const bf16_t* Ba = WapT + (size_t)layer*16384;
  const bf16_t* Bg = WgT  + (size_t)layer*8192;
  const float* wav = wa + layer*256;
  f32x4 accA[4], accG[2];
  #pragma unroll
  for (int u = 0; u < 4; u++){
    int col = 64*wid + u*16 + l15;
    f32x4 acc = {0,0,0,0};
    acc = mfma16(a0, *(const bf16x8*)(Ba + (size_t)col*64 + koff), acc);
    acc = mfma16(a1, *(const bf16x8*)(Ba + (size_t)col*64 + 32 + koff), acc);
    accA[u] = acc;
  }
  #pragma unroll
  for (int u = 0; u < 2; u++){
    int col = 32*wid + u*16 + l15;
    f32x4 acc = {0,0,0,0};
    acc = mfma16(a0, *(const bf16x8*)(Bg + (size_t)col*64 + koff), acc);
    acc = mfma16(a1, *(const bf16x8*)(Bg + (size_t)col*64 + 32 + koff), acc);
    accG[u] = acc;
  }
  #pragma unroll
  for (int u = 0; u < 2; u++){
    int col = 32*wid + u*16 + l15;
    #pragma unroll
    for (int r = 0; r < 4; r++){
      int e = eb + lg*4 + r;
      if (e < E) gate16[(size_t)e*128 + col] = (bf16_t)silu_f(accG[u][r]);
    }
  }
  #pragma unroll
  for (int hpair = 0; hpair < 2; hpair++){
    int c0 = 64*wid + hpair*32 + l15;
    float w0 = wav[c0], w1 = wav[c0+16];
    float s[4];
    #pragma unroll
    for (int r = 0; r < 4; r++)
      s[r] = silu_f(accA[2*hpair][r])*w0 + silu_f(accA[2*hpair+1][r])*w1;
    #pragma unroll
    for (int r = 0; r < 4; r++){
      s[r] += __shfl_xor(s[r], 1);
      s[r] += __shfl_xor(s[r], 2);
      s[r] += __shfl_xor(s[r], 4);
      s[r] += __shfl_xor(s[r], 8);
    }
    if (l15 == 0){
      #pragma unroll
      for (int r = 0; r < 4; r++){
        int e = eb + lg*4 + r;
        if (e < E) logi[(size_t)e*8 + 2*wid + hpair] = s[r];
      }
    }
  }
}

// fp8 dword -> 4 fp32 FMA into acc
#define FMA_DW(dw, kb) { \
  f32x2 lo_ = __builtin_amdgcn_cvt_pk_f32_fp8((dw), false); \
  f32x2 hi_ = __builtin_amdgcn_cvt_pk_f32_fp8((dw), true); \
  acc[(kb)]   += lo_.x * rw[LOF2((kb))]; \
  acc[(kb)+1] += lo_.y * rw[LOF2((kb)+1)]; \
  acc[(kb)+2] += hi_.x * rw[LOF2((kb)+2)]; \
  acc[(kb)+3] += hi_.y * rw[LOF2((kb)+3)]; }

// ---------------- per-layer: gather-only kernel ----------------
__global__ __launch_bounds__(512, 4) void k_gather(
    const int* __restrict__ EI, const int* __restrict__ rowptr, const int* __restrict__ order,
    const float* __restrict__ ed,
    const unsigned char* __restrict__ PV8, const unsigned char* __restrict__ QV8,
    const bf16_t* __restrict__ gate16, const float* __restrict__ logi,
    const float* __restrict__ radtab,
    bf16_t* __restrict__ agg, int layer)
{
  __shared__ bf16_t mA[32*136];
  __shared__ bf16_t mB[32*136];
  __shared__ float at8[512];
  __shared__ float rl7[512];
  __shared__ int   esb[64], srcs[64];
  __shared__ float denl[32];

  int n = blockIdx.x, t = threadIdx.x;
  int rp = rowptr[n], deg = rowptr[n+1] - rp;
  if (deg == 0){
    for (int idx = t; idx < 3712; idx += 512) agg[(size_t)n*3712 + idx] = (bf16_t)0.f;
    return;
  }
  int eg = t >> 7, hv = t & 127, h = hv >> 4;
  float acc[32];
  #pragma unroll
  for (int j = 0; j < 32; j++) acc[j] = 0.f;
  float S[7];
  #pragma unroll
  for (int l = 0; l < 7; l++) S[l] = 0.f;
  float dpart = 0.f;
  for (int base = 0; base < deg; base += 64){
    int ne = min(64, deg - base);
    if (base > 0) __syncthreads();
    if (t < ne){ int e = order[rp + base + t]; esb[t] = e; srcs[t] = EI[e]; }
    __syncthreads();
    if (t < ne*8){
      int i = t >> 3, q = t & 7;
      int e = esb[i];
      float d = ed[e];
      at8[t] = env_f(d) * __expf(logi[(size_t)e*8 + q]);   // unnormalized
      if (q < 7){
        float u = d * ((GTAB-1)/12.0f);
        int j = (int)u; if (j > GTAB-2) j = GTAB-2;
        float f = u - (float)j;
        float a = radtab[(size_t)j*28 + layer*7 + q], b = radtab[(size_t)(j+1)*28 + layer*7 + q];
        rl7[t] = a + f*(b-a);
      }
    }
    __syncthreads();
    uint4 A0 = {0,0,0,0}, A1 = {0,0,0,0}, B0 = {0,0,0,0}, B1 = {0,0,0,0};
    float gA = 0.f, gB = 0.f;
    int i = eg;
    if (i < ne){
      const uint4* p = (const uint4*)(PV8 + (size_t)srcs[i]*4096 + hv*32);
      A0 = p[0]; A1 = p[1];
      gA = (float)gate16[(size_t)esb[i]*128 + hv];
    }
    if (i + 4 < ne){
      const uint4* p = (const uint4*)(PV8 + (size_t)srcs[i+4]*4096 + hv*32);
      B0 = p[0]; B1 = p[1];
      gB = (float)gate16[(size_t)esb[i+4]*128 + hv];
    }
    while (i < ne){
      int i2 = i + 8;
      uint4 C0 = {0,0,0,0}, C1 = {0,0,0,0}; float gC = 0.f;
      if (i2 < ne){
        const uint4* p = (const uint4*)(PV8 + (size_t)srcs[i2]*4096 + hv*32);
        C0 = p[0]; C1 = p[1];
        gC = (float)gate16[(size_t)esb[i2]*128 + hv];
      }
      float ae = at8[i*8 + h];
      dpart += ae;
      float w = gA * ae;
      float rw[7];
      #pragma unroll
      for (int l = 0; l < 7; l++){ rw[l] = rl7[i*8 + l]*w; S[l] += rw[l]; }
      FMA_DW(A0.x, 0)  FMA_DW(A0.y, 4)  FMA_DW(A0.z, 8)  FMA_DW(A0.w, 12)
      FMA_DW(A1.x, 16) FMA_DW(A1.y, 20) FMA_DW(A1.z, 24) FMA_DW(A1.w, 28)
      A0 = B0; A1 = B1; gA = gB;
      B0 = C0; B1 = C1; gB = gC;
      i += 4;
    }
  }
  // QV*S partial per eg group (fp8 QV, contiguous per node)
  {
    const unsigned char* qvp = QV8 + (size_t)n*4096 + hv*32;
    uint4 q0 = *(const uint4*)qvp;
    uint4 q1 = *(const uint4*)(qvp + 16);
    float rw[7];
    #pragma unroll
    for (int l = 0; l < 7; l++) rw[l] = S[l];
    FMA_DW(q0.x, 0)  FMA_DW(q0.y, 4)  FMA_DW(q0.z, 8)  FMA_DW(q0.w, 12)
    FMA_DW(q1.x, 16) FMA_DW(q1.y, 20) FMA_DW(q1.z, 24) FMA_DW(q1.w, 28)
  }
  if ((hv & 15) == 0) denl[eg*8 + h] = dpart;
  __syncthreads();
  {
    float dsum = denl[h] + denl[8 + h] + denl[16 + h] + denl[24 + h];
    float inv = 1.0f/(dsum + 1e-30f);
    #pragma unroll
    for (int j = 0; j < 32; j++) acc[j] *= inv;
  }
  // pairwise bf16 merge
  if (eg == 0){
    #pragma unroll
    for (int j = 0; j < 32; j++) mA[j*136 + hv] = (bf16_t)acc[j];
  } else if (eg == 1){
    #pragma unroll
    for (int j = 0; j < 32; j++) mB[j*136 + hv] = (bf16_t)acc[j];
  }
  __syncthreads();
  if (eg == 2){
    #pragma unroll
    for (int j = 0; j < 32; j++) mA[j*136 + hv] = (bf16_t)((float)mA[j*136 + hv] + acc[j]);
  } else if (eg == 3){
    #pragma unroll
    for (int j = 0; j < 32; j++) mB[j*136 + hv] = (bf16_t)((float)mB[j*136 + hv] + acc[j]);
  }
  __syncthreads();
  for (int idx = t; idx < 3712; idx += 512){
    int k = idx >> 7, c = idx & 127;
    agg[(size_t)n*3712 + idx] = (bf16_t)((float)mA[k*136 + c] + (float)mB[k*136 + c]);
  }
}

// ---------------- per-layer: x update (Wo + FFN + next-layer pqv tail) ----------------
__global__ __launch_bounds__(512, 4) void k_xupdate(
    const bf16_t* __restrict__ agg,
    const float* __restrict__ gamma1, const float* __restrict__ gamma2,
    const float* __restrict__ Wfg,
    const bf16_t* __restrict__ Wf1T, const bf16_t* __restrict__ Wf2T,
    const bf16_t* __restrict__ WoT, const bf16_t* __restrict__ WmsgCT, const bf16_t* __restrict__ WvT,
    bf16_t* __restrict__ Xb, int layer,
    unsigned char* __restrict__ PV8o, unsigned char* __restrict__ QV8o,
    float* __restrict__ P0o, float* __restrict__ Q0o, int do_tail)
{
  __shared__ float  xs[3712];
  __shared__ bf16_t ysag[32*136];
  __shared__ bf16_t hsqv[32*136];
  __shared__ float  pf[640];

  int n = blockIdx.x, t = threadIdx.x;
  int wid = t >> 6, lane = t & 63;

  // load x + agg into LDS
  {
    const bf16x2* Xp2 = (const bf16x2*)(Xb + (size_t)n*3712);
    for (int p = t; p < 1856; p += 512){
      bf16x2 v = Xp2[p];
      xs[2*p]   = (float)v.x;
      xs[2*p+1] = (float)v.y;
    }
  }
  for (int idx = t; idx < 3712; idx += 512){
    int k = idx >> 7, c = idx & 127;
    ysag[k*136 + c] = agg[(size_t)n*3712 + idx];
  }
  for (int idx = t; idx < 3*136; idx += 512) ysag[29*136 + idx] = (bf16_t)0.f;
  __syncthreads();
  // Wo GEMM: xs += agg @ WoT (K=128, 8 waves)
  {
    const bf16_t* Bt = WoT + (size_t)layer*16384;
    int mtile = wid >> 2, colt = (wid & 3)*2;
    int row = mtile*16 + (lane & 15);
    int koff = (lane >> 4)*8;
    f32x4 a2[2] = {{0,0,0,0},{0,0,0,0}};
    #pragma unroll
    for (int kk = 0; kk < 128; kk += 32){
      bf16x8 a = *(const bf16x8*)(ysag + row*136 + kk + koff);
      #pragma unroll
      for (int u = 0; u < 2; u++){
        int col = (colt+u)*16 + (lane & 15);
        bf16x8 b = *(const bf16x8*)(Bt + (size_t)col*128 + kk + koff);
        a2[u] = mfma16(a, b, a2[u]);
      }
    }
    #pragma unroll
    for (int u = 0; u < 2; u++){
      int col = (colt+u)*16 + (lane & 15);
      #pragma unroll
      for (int r = 0; r < 4; r++){
        int r32 = mtile*16 + (lane>>4)*4 + r;
        if (r32 < KM) xs[r32*128 + col] += a2[u][r];
      }
    }
  }
  __syncthreads();
  // ---------- FFN ----------
  const float* g2 = gamma2 + layer*128;
  for (int k = wid; k < KM; k += 8){
    float x0 = xs[k*128 + lane], x1 = xs[k*128 + 64 + lane];
    float ss = wave_reduce_sum(x0*x0 + x1*x1);
    float sc = rsqrtf(ss*(1.0f/128.0f) + 1e-6f);
    ysag[k*136 + lane]      = (bf16_t)(x0*sc*g2[lane]);
    ysag[k*136 + 64 + lane] = (bf16_t)(x1*sc*g2[64+lane]);
  }
  for (int idx = t; idx < 3*136; idx += 512) ysag[29*136 + idx] = (bf16_t)0.f;
  __syncthreads();
  {
    int part = t >> 7, f = t & 127;
    const float* Wfgp = Wfg + (size_t)layer*16384;
    float p = 0.f;
    for (int c = part*32; c < part*32 + 32; c++) p += (float)ysag[c] * Wfgp[c*128 + f];
    pf[part*128 + f] = p;
  }
  __syncthreads();
  if (t < 128) pf[512 + t] = silu_f(pf[t] + pf[128+t] + pf[256+t] + pf[384+t]);
  __syncthreads();
  {
    const bf16_t* Bt = Wf1T + (size_t)layer*16384;
    int mtile = wid >> 2, colt = (wid & 3)*2;
    int row = mtile*16 + (lane & 15);
    int koff = (lane >> 4)*8;
    f32x4 a2[2] = {{0,0,0,0},{0,0,0,0}};
    #pragma unroll
    for (int kk = 0; kk < 128; kk += 32){
      bf16x8 a = *(const bf16x8*)(ysag + row*136 + kk + koff);
      #pragma unroll
      for (int u = 0; u < 2; u++){
        int col = (colt+u)*16 + (lane & 15);
        bf16x8 b = *(const bf16x8*)(Bt + (size_t)col*128 + kk + koff);
        a2[u] = mfma16(a, b, a2[u]);
      }
    }
    #pragma unroll
    for (int u = 0; u < 2; u++){
      int col = (colt+u)*16 + (lane & 15);
      float gfc = pf[512 + col];
      #pragma unroll
      for (int r = 0; r < 4; r++){
        int r32 = mtile*16 + (lane>>4)*4 + r;
        hsqv[r32*136 + col] = (bf16_t)(a2[u][r]*gfc);
      }
    }
  }
  __syncthreads();
  {
    const bf16_t* Bt = Wf2T + (size_t)layer*16384;
    int mtile = wid >> 2, colt = (wid & 3)*2;
    int row = mtile*16 + (lane & 15);
    int koff = (lane >> 4)*8;
    f32x4 a2[2] = {{0,0,0,0},{0,0,0,0}};
    #pragma unroll
    for (int kk = 0; kk < 128; kk += 32){
      bf16x8 a = *(const bf16x8*)(hsqv + row*136 + kk + koff);
      #pragma unroll
      for (int u = 0; u < 2; u++){
        int col = (colt+u)*16 + (lane & 15);
        bf16x8 b = *(const bf16x8*)(Bt + (size_t)col*128 + kk + koff);
        a2[u] = mfma16(a, b, a2[u]);
      }
    }
    #pragma unroll
    for (int u = 0; u < 2; u++){
      int col = (colt+u)*16 + (lane & 15);
      #pragma unroll
      for (int r = 0; r < 4; r++){
        int r32 = mtile*16 + (lane>>4)*4 + r;
        if (r32 < KM) xs[r32*128 + col] += a2[u][r];
      }
    }
  }
  __syncthreads();
  // store x back
  {
    bf16x2* Xp2 = (bf16x2*)(Xb + (size_t)n*3712);
    for (int p = t; p < 1856; p += 512){
      bf16x2 v;
      v.x = (bf16_t)xs[2*p];
      v.y = (bf16_t)xs[2*p+1];
      Xp2[p] = v;
    }
  }
  // ---------- tail: next-layer pqv ----------
  if (do_tail){
    const float* g1n = gamma1 + (size_t)(layer+1)*128;
    for (int k = wid; k < KM; k += 8){
      float x0 = xs[k*128 + lane], x1 = xs[k*128 + 64 + lane];
      float ss = wave_reduce_sum(x0*x0 + x1*x1);
      float sc = rsqrtf(ss*(1.0f/128.0f) + 1e-6f);
      ysag[k*136 + lane]      = (bf16_t)(x0*sc*g1n[lane]);
      ysag[k*136 + 64 + lane] = (bf16_t)(x1*sc*g1n[64+lane]);
    }
    __syncthreads();
    int mtile = wid >> 2;
    int row = mtile*16 + (lane & 15);
    int koff = (lane >> 4)*8;
    // pq = ys @ WmsgCT[layer+1] -> hsqv; P0o/Q0o from row 0
    {
      const bf16_t* Bc = WmsgCT + (size_t)(layer+1)*16384;
      f32x4 acc[2] = {{0,0,0,0},{0,0,0,0}};
      #pragma unroll
      for (int kk = 0; kk < 128; kk += 32){
        bf16x8 a = *(const bf16x8*)(ysag + row*136 + kk + koff);
        #pragma unroll
        for (int u = 0; u < 2; u++){
          int col = ((wid&3)*2+u)*16 + (lane & 15);
          bf16x8 b = *(const bf16x8*)(Bc + (size_t)col*128 + kk + koff);
          acc[u] = mfma16(a, b, acc[u]);
        }
      }
      #pragma unroll
      for (int u = 0; u < 2; u++){
        int col = ((wid&3)*2+u)*16 + (lane & 15);
        #pragma unroll
        for (int r = 0; r < 4; r++){
          int r32 = mtile*16 + (lane>>4)*4 + r;
          hsqv[r32*136 + col] = (bf16_t)acc[u][r];
        }
        if (mtile == 0 && (lane>>4) == 0){
          float v = acc[u][0];
          if (col < 64) P0o[(size_t)n*64 + col] = v;
          else          Q0o[(size_t)n*64 + col - 64] = v;
        }
      }
    }
    __syncthreads();
    // PV8o = pq[:,0:64] @ WvT[layer+1]
    {
      const bf16_t* Bt = WvT + (size_t)(layer+1)*8192;
      f32x4 acc[2] = {{0,0,0,0},{0,0,0,0}};
      #pragma unroll
      for (int kk = 0; kk < 64; kk += 32){
        bf16x8 a = *(const bf16x8*)(hsqv + row*136 + kk + koff);
        #pragma unroll
        for (int u = 0; u < 2; u++){
          int col = ((wid&3)*2+u)*16 + (lane & 15);
          bf16x8 b = *(const bf16x8*)(Bt + (size_t)col*64 + kk + koff);
          acc[u] = mfma16(a, b, acc[u]);
        }
      }
      unsigned char* pvp = PV8o + (size_t)n*4096;
      int r0i = mtile*16 + (lane>>4)*4;
      #pragma unroll
      for (int u = 0; u < 2; u++){
        int col = ((wid&3)*2+u)*16 + (lane & 15);
        float pk[4];
        #pragma unroll
        for (int r = 0; r < 4; r++){
          int r32 = r0i + r;
          pk[r] = (r32 < KM) ? acc[u][r] : 0.f;
        }
        int dw = __builtin_amdgcn_cvt_pk_fp8_f32(pk[0], pk[1], 0, false);
        dw = __builtin_amdgcn_cvt_pk_fp8_f32(pk[2], pk[3], dw, true);
        *(unsigned int*)(pvp + col*32 + r0i) = (unsigned int)dw;
      }
    }
    // QV8o = pq[:,64:128] @ WvT[layer+1]
    {
      const bf16_t* Bt = WvT + (size_t)(layer+1)*8192;
      f32x4 acc[2] = {{0,0,0,0},{0,0,0,0}};
      #pragma unroll
      for (int kk = 0; kk < 64; kk += 32){
        bf16x8 a = *(const bf16x8*)(hsqv + row*136 + 64 + kk + koff);
        #pragma unroll
        for (int u = 0; u < 2; u++){
          int col = ((wid&3)*2+u)*16 + (lane & 15);
          bf16x8 b = *(const bf16x8*)(Bt + (size_t)col*64 + kk + koff);
          acc[u] = mfma16(a, b, acc[u]);
        }
      }
      unsigned char* qvp = QV8o + (size_t)n*4096;
      int r0i = mtile*16 + (lane>>4)*4;
      #pragma unroll
      for (int u = 0; u < 2; u++){
        int col = ((wid&3)*2+u)*16 + (lane & 15);
        float pk[4];
        #pragma unroll
        for (int r = 0; r < 4; r++){
          int r32 = r0i + r;
          pk[r] = (r32 < KM) ? acc[u][r] : 0.f;
        }
        int dw = __builtin_amdgcn_cvt_pk_fp8_f32(pk[0], pk[1], 0, false);
        dw = __builtin_amdgcn_cvt_pk_fp8_f32(pk[2], pk[3], dw, true);
        *(unsigned int*)(qvp + col*32 + r0i) = (unsigned int)dw;
      }
    }
  }
}

// ---------------- output head ----------------
__global__ __launch_bounds__(256) void k_head(
    const bf16_t* __restrict__ Xb, const float* __restrict__ Wh1, const float* __restrict__ Wh2,
    float* __restrict__ partial, int N)
{
  __shared__ float wsum[4];
  int t = threadIdx.x;
  int half = t >> 7;
  int n = blockIdx.x*2 + half;
  int f = t & 127;
  float sv = 0.f;
  if (n < N){
    const bf16_t* xp = Xb + (size_t)n*3712;
    float acc = 0.f;
    for (int c = 0; c < 128; c++) acc += (float)xp[c]*Wh1[c*128 + f];
    sv = silu_f(acc)*Wh2[f];
  }
  sv = wave_reduce_sum(sv);
  if ((t & 63) == 0) wsum[t >> 6] = sv;
  __syncthreads();
  if (t == 0) partial[blockIdx.x] = wsum[0] + wsum[1] + wsum[2] + wsum[3];
}

__global__ __launch_bounds__(256) void k_reduce(const float* __restrict__ partial, float* __restrict__ out, int P){
  __shared__ float sh[256];
  int t = threadIdx.x;
  float s = 0.f;
  for (int i = t; i < P; i += 256) s += partial[i];
  sh[t] = s; __syncthreads();
  for (int off = 128; off > 0; off >>= 1){
    if (t < off) sh[t] += sh[t+off];
    __syncthreads();
  }
  if (t == 0) out[0] = sh[0] / 77.81317f;
}

extern "C" void kernel_launch(void* const* d_in, const int* in_sizes, int n_in,
                              void* d_out, int out_size, void* d_ws, size_t ws_size,
                              hipStream_t stream)
{
  const int*   Z      = (const int*)d_in[0];
  const int*   EI     = (const int*)d_in[1];
  const float* ed     = (const float*)d_in[2];
  const float* emb    = (const float*)d_in[3];
  const float* We0    = (const float*)d_in[4];
  const float* be0    = (const float*)d_in[5];
  const float* We1    = (const float*)d_in[6];
  const float* be1    = (const float*)d_in[7];
  const float* Weproj = (const float*)d_in[8];
  const float* gamma1 = (const float*)d_in[9];
  const float* gamma2 = (const float*)d_in[10];
  const float* Wr0    = (const float*)d_in[11];
  const float* Wr1    = (const float*)d_in[12];
  const float* Wrl    = (const float*)d_in[13];
  const float* Wmsg   = (const float*)d_in[14];
  const float* Wap    = (const float*)d_in[15];
  const float* wa     = (const float*)d_in[16];
  const float* Wg     = (const float*)d_in[17];
  const float* Wv     = (const float*)d_in[18];
  const float* Wo     = (const float*)d_in[19];
  const float* Wf1    = (const float*)d_in[20];
  const float* Wfg    = (const float*)d_in[21];
  const float* Wf2    = (const float*)d_in[22];
  const float* Wh1    = (const float*)d_in[23];
  const float* Wh2    = (const float*)d_in[24];

  const int N = in_sizes[0];
  const int E = in_sizes[2];

  float* ws = (float*)d_ws;
  size_t o = 0;
  auto alloc = [&](size_t nf){ float* p = ws + o; o += (nf + 7) & ~(size_t)7; return p; };

  bf16_t* Xb    = (bf16_t*)alloc((size_t)N*1856);      // N*3712 bf16
  float* P0     = alloc((size_t)N*64);
  float* Q0     = alloc((size_t)N*64);
  float* logi   = alloc((size_t)E*8);
  float* part   = alloc((size_t)((N+1)/2) + 8);
  float* radtab = alloc((size_t)GTAB*28);
  float* h2tab  = alloc((size_t)GTAB*128);
  bf16_t* h2sum = (bf16_t*)alloc((size_t)N*64);        // N*128 bf16
  unsigned char* PV8 = (unsigned char*)alloc((size_t)N*1024);  // N*4096 fp8
  unsigned char* QV8 = (unsigned char*)alloc((size_t)N*1024);  // N*4096 fp8
  bf16_t* agg   = (bf16_t*)alloc((size_t)N*1856);      // N*3712 bf16
  bf16_t* gate16= (bf16_t*)alloc((size_t)E*64);        // E*128 bf16; h2e aliases pre-layers
  bf16_t* arena = (bf16_t*)alloc(434176);              // 868352 bf16
  int* rowptr = (int*)alloc((size_t)N+8);
  int* curs   = (int*)alloc((size_t)N);
  int* order  = (int*)alloc((size_t)E);
  // total ~178 MB for N=6000, E=120000 (known-good <= 199.5 MB)

  bf16_t* WmsgCT  = arena;            // [4][128][128]
  bf16_t* WvT     = arena + 65536;    // [4][128][64]
  bf16_t* WoT     = arena + 98304;    // [4][128][128]
  bf16_t* Wf1T    = arena + 163840;   // [4][128][128]
  bf16_t* Wf2T    = arena + 229376;   // [4][128][128]
  bf16_t* WapT    = arena + 294912;   // [4][256][64]
  bf16_t* WgT     = arena + 360448;   // [4][128][64]
  bf16_t* WeprojT = arena + 393216;   // [3712][128]

  bf16_t* h2e = gate16;   // alias: dead before layer-0 logits writes gate16

  // CSR by target
  hipMemsetAsync(curs, 0, sizeof(int)*N, stream);
  k_count<<<(E+255)/256, 256, 0, stream>>>(EI, curs, E);
  k_scan<<<1, 1024, 0, stream>>>(curs, rowptr, N);
  k_fill<<<(E+255)/256, 256, 0, stream>>>(EI, curs, order, E);
  k_sort<<<(N+255)/256, 256, 0, stream>>>(rowptr, order, N);

  // weight transposes -> bf16 arenas
  k_tr2<<<256, 256, 0, stream>>>(Wmsg, WmsgCT);
  k_tr<<<128, 256, 0, stream>>>(Wv,   WvT,  4, 64, 128, 8192);
  k_tr<<<256, 256, 0, stream>>>(Wo,   WoT,  4, 128, 128, 16384);
  k_tr<<<256, 256, 0, stream>>>(Wf1,  Wf1T, 4, 128, 128, 16384);
  k_tr<<<256, 256, 0, stream>>>(Wf2,  Wf2T, 4, 128, 128, 16384);
  k_tr<<<256, 256, 0, stream>>>(Wap,  WapT, 4, 64, 256, 16384);
  k_tr<<<128, 256, 0, stream>>>(Wg,   WgT,  4, 64, 128, 8192);
  k_tr<<<1856, 256, 0, stream>>>(Weproj, WeprojT, 1, 128, 3712, 0);

  // radial tables + per-edge h2 + per-node h2 sum + x init
  k_tab_embed<<<GTAB/4, 256, 0, stream>>>(We0, be0, We1, be1, Wr0, Wr1, Wrl, h2tab, radtab);
  k_h2e<<<(E*128+255)/256, 256, 0, stream>>>(ed, h2tab, h2e, E);
  k_h2sum<<<(N+1)/2, 256, 0, stream>>>(h2e, rowptr, order, h2sum, N);
  k_init_x<<<(N+31)/32, 256, 0, stream>>>(Z, emb, WeprojT, h2sum, Xb, N);

  // layer-0 pqv (later layers' pqv fused into k_xupdate tail)
  k_pqv<<<N, 512, 0, stream>>>(Xb, gamma1, WmsgCT, WvT, PV8, QV8, P0, Q0, 0);

  for (int i = 0; i < 4; i++){
    k_edge_logits<<<(E+15)/16, 256, 0, stream>>>(EI, ed, P0, Q0, radtab, WapT, wa, WgT, logi, gate16, E, i);
    k_gather<<<N, 512, 0, stream>>>(EI, rowptr, order, ed, PV8, QV8, gate16, logi, radtab, agg, i);
    k_xupdate<<<N, 512, 0, stream>>>(agg, gamma1, gamma2, Wfg, Wf1T, Wf2T, WoT, WmsgCT, WvT,
                                     Xb, i, PV8, QV8, P0, Q0, (i < 3) ? 1 : 0);
  }

  int PB = (N+1)/2;
  k_head<<<PB, 256, 0, stream>>>(Xb, Wh1, Wh2, part, N);
  k_reduce<<<1, 256, 0, stream>>>(part, (float*)d_out, PB);
}